// Round 7
// baseline (385.912 us; speedup 1.0000x reference)
//
#include <hip/hip_runtime.h>
#include <math.h>

#define N_NODES 50000
#define N_EDGES 800000

typedef short short8 __attribute__((ext_vector_type(8)));
typedef float f32x4 __attribute__((ext_vector_type(4)));

// ---------------- bf16 helpers ----------------
__device__ inline unsigned short f2bf(float v) {
  unsigned u = __float_as_uint(v);
  u += 0x7FFFu + ((u >> 16) & 1u);  // round-to-nearest-even
  return (unsigned short)(u >> 16);
}
__device__ inline float bf2f(unsigned short b) {
  return __uint_as_float(((unsigned)b) << 16);
}

// ---------------- cast x -> bf16 ----------------
__global__ void cast_bf16(const float* __restrict__ in, unsigned short* __restrict__ out, int n4) {
  int i = blockIdx.x * blockDim.x + threadIdx.x;
  if (i >= n4) return;
  float4 v = ((const float4*)in)[i];
  ushort4 o;
  o.x = f2bf(v.x); o.y = f2bf(v.y); o.z = f2bf(v.z); o.w = f2bf(v.w);
  ((ushort4*)out)[i] = o;
}

// ---------------- weight concat + transpose + bf16: Wt[c][k] ----------------
__global__ void concat_wt(const float* __restrict__ W0, const float* __restrict__ W1,
                          const float* __restrict__ W2, const float* __restrict__ W3,
                          const float* __restrict__ b0, const float* __restrict__ b1,
                          const float* __restrict__ b2, const float* __restrict__ b3,
                          unsigned short* __restrict__ Wt, float* __restrict__ bcat,
                          int K, int segN) {
  int i = blockIdx.x * blockDim.x + threadIdx.x;
  int Ncat = 4 * segN;
  if (i < Ncat * K) {
    int c = i / K, k = i % K;
    int mi = c / segN, lc = c % segN;
    const float* W = (mi == 0) ? W0 : (mi == 1) ? W1 : (mi == 2) ? W2 : W3;
    Wt[i] = f2bf(W[(size_t)k * segN + lc]);
  }
  if (i < Ncat) {
    int mi = i / segN, lc = i % segN;
    const float* b = (mi == 0) ? b0 : (mi == 1) ? b1 : (mi == 2) ? b2 : b3;
    bcat[i] = b[lc];
  }
}

// ================= GEMMs: no LDS staging (fragments direct from global/L2), =================
// ================= LDS-repack epilogue for coalesced bf16 row stores.       =================
// A is [M][128] bf16, Wt is [Ncat][128] bf16 (pre-transposed). BM=64, 256 thr = 4 waves.
// MFMA fragment addressing (verified R4..R6): A row = bm+i*16+lr, k = ks*32+q*8;
// C/D: col=lr, row=q*4+r.

// ---- gemm_bf16: 128-col strip -> identity-layout bf16 output (Q1b / SK1 via blockIdx.y) ----
__global__ __launch_bounds__(256) void gemm_bf16(
    const unsigned short* __restrict__ Ab, const unsigned short* __restrict__ Wt,
    const float* __restrict__ bcat, unsigned short* __restrict__ outA,
    unsigned short* __restrict__ outB, int coloffB, int M) {
  __shared__ unsigned short Ls[64 * 132];  // stride 132 shorts (pad kills bank conflicts)
  const int coloff = blockIdx.y ? coloffB : 0;
  unsigned short* out = blockIdx.y ? outB : outA;
  const int bm = blockIdx.x * 64;
  const int tid = threadIdx.x, wave = tid >> 6, lane = tid & 63;
  const int lr = lane & 15, q = lane >> 4;

  f32x4 acc[4][2];
#pragma unroll
  for (int i = 0; i < 4; ++i)
#pragma unroll
    for (int j = 0; j < 2; ++j) acc[i][j] = (f32x4){0.f, 0.f, 0.f, 0.f};

#pragma unroll
  for (int ks = 0; ks < 4; ++ks) {
    short8 af[4], bf[2];
#pragma unroll
    for (int i = 0; i < 4; ++i) {
      int gm = bm + i * 16 + lr; if (gm >= M) gm = 0;
      af[i] = *(const short8*)(Ab + (size_t)gm * 128 + ks * 32 + q * 8);
    }
#pragma unroll
    for (int j = 0; j < 2; ++j)
      bf[j] = *(const short8*)(Wt + (size_t)(coloff + wave * 32 + j * 16 + lr) * 128 + ks * 32 + q * 8);
#pragma unroll
    for (int i = 0; i < 4; ++i)
#pragma unroll
      for (int j = 0; j < 2; ++j)
        acc[i][j] = __builtin_amdgcn_mfma_f32_16x16x32_bf16(af[i], bf[j], acc[i][j], 0, 0, 0);
  }

  float bj[2];
#pragma unroll
  for (int j = 0; j < 2; ++j) bj[j] = bcat[coloff + wave * 32 + j * 16 + lr];
#pragma unroll
  for (int i = 0; i < 4; ++i)
#pragma unroll
    for (int r = 0; r < 4; ++r) {
      int row = i * 16 + q * 4 + r;
#pragma unroll
      for (int j = 0; j < 2; ++j) {
        int c = wave * 32 + j * 16 + lr;
        Ls[row * 132 + c] = f2bf(acc[i][j][r] + bj[j]);
      }
    }
  __syncthreads();
  // readout: 64 rows x 32 uint2 = 2048, 8 per thread, coalesced
#pragma unroll
  for (int p = 0; p < 8; ++p) {
    int idx = tid + p * 256;
    int row = idx >> 5, u = idx & 31;
    int gr = bm + row;
    if (gr < M) *(uint2*)(out + (size_t)gr * 128 + u * 4) = *(const uint2*)&Ls[row * 132 + u * 4];
  }
}

// ---- gemm_kv1: cols 128..383 of Wcat1 -> KV1 interleaved rows (256 shorts/row) ----
__global__ __launch_bounds__(256) void gemm_kv1(
    const unsigned short* __restrict__ Ab, const unsigned short* __restrict__ Wt,
    const float* __restrict__ bcat, unsigned short* __restrict__ KV, int M) {
  __shared__ unsigned short Ls[64 * 268];  // stride 268 (data 256)
  const int bm = blockIdx.x * 64;
  const int tid = threadIdx.x, wave = tid >> 6, lane = tid & 63;
  const int lr = lane & 15, q = lane >> 4;

  f32x4 acc[4][4];
#pragma unroll
  for (int i = 0; i < 4; ++i)
#pragma unroll
    for (int j = 0; j < 4; ++j) acc[i][j] = (f32x4){0.f, 0.f, 0.f, 0.f};

#pragma unroll
  for (int ks = 0; ks < 4; ++ks) {
    short8 af[4], bf[4];
#pragma unroll
    for (int i = 0; i < 4; ++i) {
      int gm = bm + i * 16 + lr; if (gm >= M) gm = 0;
      af[i] = *(const short8*)(Ab + (size_t)gm * 128 + ks * 32 + q * 8);
    }
#pragma unroll
    for (int j = 0; j < 4; ++j)
      bf[j] = *(const short8*)(Wt + (size_t)(128 + wave * 64 + j * 16 + lr) * 128 + ks * 32 + q * 8);
#pragma unroll
    for (int i = 0; i < 4; ++i)
#pragma unroll
      for (int j = 0; j < 4; ++j)
        acc[i][j] = __builtin_amdgcn_mfma_f32_16x16x32_bf16(af[i], bf[j], acc[i][j], 0, 0, 0);
  }

  float bj[4];
#pragma unroll
  for (int j = 0; j < 4; ++j) bj[j] = bcat[128 + wave * 64 + j * 16 + lr];
#pragma unroll
  for (int i = 0; i < 4; ++i)
#pragma unroll
    for (int r = 0; r < 4; ++r) {
      int row = i * 16 + q * 4 + r;
#pragma unroll
      for (int j = 0; j < 4; ++j) {
        int c = wave * 64 + j * 16 + lr;  // 0..255 over K|V
        int slot = (c < 128) ? ((c >> 1) * 4 + (c & 1))
                             : (((c - 128) >> 1) * 4 + 2 + ((c - 128) & 1));
        Ls[row * 268 + slot] = f2bf(acc[i][j][r] + bj[j]);
      }
    }
  __syncthreads();
  // readout: 64 rows x 64 uint2 = 4096, 16 per thread
#pragma unroll
  for (int p = 0; p < 16; ++p) {
    int idx = tid + p * 256;
    int row = idx >> 6, u = idx & 63;
    int gr = bm + row;
    if (gr < M) *(uint2*)(KV + (size_t)gr * 256 + u * 4) = *(const uint2*)&Ls[row * 268 + u * 4];
  }
}

// ---- gemm2: all 128 cols of Wcat2 -> C2 rows [Q(32) | KVinterleave(64) | H(32)] bf16 ----
__global__ __launch_bounds__(256) void gemm2(
    const unsigned short* __restrict__ Ab, const unsigned short* __restrict__ Wt,
    const float* __restrict__ bcat, unsigned short* __restrict__ C2, int M) {
  __shared__ unsigned short Ls[64 * 132];
  const int bm = blockIdx.x * 64;
  const int tid = threadIdx.x, wave = tid >> 6, lane = tid & 63;
  const int lr = lane & 15, q = lane >> 4;

  f32x4 acc[4][2];
#pragma unroll
  for (int i = 0; i < 4; ++i)
#pragma unroll
    for (int j = 0; j < 2; ++j) acc[i][j] = (f32x4){0.f, 0.f, 0.f, 0.f};

#pragma unroll
  for (int ks = 0; ks < 4; ++ks) {
    short8 af[4], bf[2];
#pragma unroll
    for (int i = 0; i < 4; ++i) {
      int gm = bm + i * 16 + lr; if (gm >= M) gm = 0;
      af[i] = *(const short8*)(Ab + (size_t)gm * 128 + ks * 32 + q * 8);
    }
#pragma unroll
    for (int j = 0; j < 2; ++j)
      bf[j] = *(const short8*)(Wt + (size_t)(wave * 32 + j * 16 + lr) * 128 + ks * 32 + q * 8);
#pragma unroll
    for (int i = 0; i < 4; ++i)
#pragma unroll
      for (int j = 0; j < 2; ++j)
        acc[i][j] = __builtin_amdgcn_mfma_f32_16x16x32_bf16(af[i], bf[j], acc[i][j], 0, 0, 0);
  }

  float bj[2];
#pragma unroll
  for (int j = 0; j < 2; ++j) bj[j] = bcat[wave * 32 + j * 16 + lr];
#pragma unroll
  for (int i = 0; i < 4; ++i)
#pragma unroll
    for (int r = 0; r < 4; ++r) {
      int row = i * 16 + q * 4 + r;
#pragma unroll
      for (int j = 0; j < 2; ++j) {
        int c = wave * 32 + j * 16 + lr;  // 0..127 = Q|K|V|H
        int slot = (c < 32) ? c
                 : (c < 64) ? (32 + (c - 32) * 2)
                 : (c < 96) ? (33 + (c - 64) * 2)
                 : c;
        Ls[row * 132 + slot] = f2bf(acc[i][j][r] + bj[j]);
      }
    }
  __syncthreads();
#pragma unroll
  for (int p = 0; p < 8; ++p) {
    int idx = tid + p * 256;
    int row = idx >> 5, u = idx & 31;
    int gr = bm + row;
    if (gr < M) *(uint2*)(C2 + (size_t)gr * 128 + u * 4) = *(const uint2*)&Ls[row * 132 + u * 4];
  }
}

// ---------------- CSR build ----------------
__global__ void deg_count(const int* __restrict__ ei, int* __restrict__ deg, int E) {
  int e = blockIdx.x * blockDim.x + threadIdx.x;
  if (e < E) atomicAdd(&deg[ei[E + e]], 1);
}

__global__ void scan_part(const int* __restrict__ deg, int* __restrict__ bsum, int n) {
  int i = blockIdx.x * 256 + threadIdx.x;
  int v = (i < n) ? deg[i] : 0;
#pragma unroll
  for (int off = 1; off < 64; off <<= 1) v += __shfl_xor(v, off);
  __shared__ int s[4];
  if ((threadIdx.x & 63) == 0) s[threadIdx.x >> 6] = v;
  __syncthreads();
  if (threadIdx.x == 0) bsum[blockIdx.x] = s[0] + s[1] + s[2] + s[3];
}

__global__ void scan_tops(const int* __restrict__ bsum, int* __restrict__ boff,
                          int* __restrict__ rowptr, int nb, int n) {
  __shared__ int s[256];
  int t = threadIdx.x;
  int v = (t < nb) ? bsum[t] : 0;
  s[t] = v;
  __syncthreads();
#pragma unroll
  for (int off = 1; off < 256; off <<= 1) {
    int u = (t >= off) ? s[t - off] : 0;
    __syncthreads();
    s[t] += u;
    __syncthreads();
  }
  if (t < nb) boff[t] = (t == 0) ? 0 : s[t - 1];
  if (t == 255) rowptr[n] = s[255];
}

__global__ void scan_final(const int* __restrict__ deg, const int* __restrict__ boff,
                           int* __restrict__ rowptr, int* __restrict__ cur, int n) {
  __shared__ int s[256];
  int i = blockIdx.x * 256 + threadIdx.x;
  int t = threadIdx.x;
  int v = (i < n) ? deg[i] : 0;
  s[t] = v;
  __syncthreads();
#pragma unroll
  for (int off = 1; off < 256; off <<= 1) {
    int u = (t >= off) ? s[t - off] : 0;
    __syncthreads();
    s[t] += u;
    __syncthreads();
  }
  if (i < n) {
    int excl = boff[blockIdx.x] + s[t] - v;
    rowptr[i] = excl;
    cur[i] = excl;
  }
}

__global__ void scatter_edges(const int* __restrict__ ei, int* __restrict__ cur,
                              int* __restrict__ esrc, int E) {
  int e = blockIdx.x * blockDim.x + threadIdx.x;
  if (e >= E) return;
  int src = ei[e];
  int dst = ei[E + e];
  int pos = atomicAdd(&cur[dst], 1);
  esrc[pos] = src;
}

// ---------------- fused online-softmax aggregation ----------------
// conv1: one wave per node; lane owns 2 dims; x4 unrolled edge loop.
__global__ void node_attn1(const int* __restrict__ rowptr, const int* __restrict__ esrc,
                           const unsigned short* __restrict__ Qb,
                           const unsigned short* __restrict__ KV,
                           const unsigned short* __restrict__ SK, unsigned short* __restrict__ Hb,
                           int n) {
  int node = (blockIdx.x * blockDim.x + threadIdx.x) >> 6;
  int lane = threadIdx.x & 63;
  if (node >= n) return;
  const int r0 = rowptr[node], r1 = rowptr[node + 1];
  unsigned qu = *(const unsigned*)(Qb + (size_t)node * 128 + lane * 2);
  float2 q;
  q.x = __uint_as_float((qu & 0xFFFFu) << 16);
  q.y = __uint_as_float(qu & 0xFFFF0000u);
  float m = -INFINITY, l = 0.f;
  float2 acc = {0.f, 0.f};
  const float SCL = 0.17677669529663687f;  // 1/sqrt(32)
  int j = r0;
  for (; j + 4 <= r1; j += 4) {
    int s0 = esrc[j], s1 = esrc[j + 1], s2 = esrc[j + 2], s3 = esrc[j + 3];
    ushort4 kv0 = *(const ushort4*)(KV + (size_t)s0 * 256 + lane * 4);
    ushort4 kv1 = *(const ushort4*)(KV + (size_t)s1 * 256 + lane * 4);
    ushort4 kv2 = *(const ushort4*)(KV + (size_t)s2 * 256 + lane * 4);
    ushort4 kv3 = *(const ushort4*)(KV + (size_t)s3 * 256 + lane * 4);
    float d0 = q.x * bf2f(kv0.x) + q.y * bf2f(kv0.y);
    float d1 = q.x * bf2f(kv1.x) + q.y * bf2f(kv1.y);
    float d2 = q.x * bf2f(kv2.x) + q.y * bf2f(kv2.y);
    float d3 = q.x * bf2f(kv3.x) + q.y * bf2f(kv3.y);
#pragma unroll
    for (int msk = 1; msk <= 8; msk <<= 1) {
      d0 += __shfl_xor(d0, msk);
      d1 += __shfl_xor(d1, msk);
      d2 += __shfl_xor(d2, msk);
      d3 += __shfl_xor(d3, msk);
    }
    float lg0 = d0 * SCL, lg1 = d1 * SCL, lg2 = d2 * SCL, lg3 = d3 * SCL;
    float mnew = fmaxf(fmaxf(m, fmaxf(lg0, lg1)), fmaxf(lg2, lg3));
    float sc = __expf(m - mnew);
    float p0 = __expf(lg0 - mnew), p1 = __expf(lg1 - mnew);
    float p2 = __expf(lg2 - mnew), p3 = __expf(lg3 - mnew);
    l = l * sc + (p0 + p1) + (p2 + p3);
    acc.x = acc.x * sc + p0 * bf2f(kv0.z) + p1 * bf2f(kv1.z) + p2 * bf2f(kv2.z) + p3 * bf2f(kv3.z);
    acc.y = acc.y * sc + p0 * bf2f(kv0.w) + p1 * bf2f(kv1.w) + p2 * bf2f(kv2.w) + p3 * bf2f(kv3.w);
    m = mnew;
  }
  for (; j < r1; ++j) {
    int src = esrc[j];
    ushort4 kv = *(const ushort4*)(KV + (size_t)src * 256 + lane * 4);
    float d = q.x * bf2f(kv.x) + q.y * bf2f(kv.y);
    d += __shfl_xor(d, 1);
    d += __shfl_xor(d, 2);
    d += __shfl_xor(d, 4);
    d += __shfl_xor(d, 8);
    float lg = d * SCL;
    float mnew = fmaxf(m, lg);
    float sc = __expf(m - mnew);
    float p = __expf(lg - mnew);
    l = l * sc + p;
    acc.x = acc.x * sc + p * bf2f(kv.z);
    acc.y = acc.y * sc + p * bf2f(kv.w);
    m = mnew;
  }
  float inv = (l > 0.f) ? 1.f / l : 0.f;
  unsigned sku = *(const unsigned*)(SK + (size_t)node * 128 + lane * 2);
  float skx = __uint_as_float((sku & 0xFFFFu) << 16);
  float sky = __uint_as_float(sku & 0xFFFF0000u);
  float ox = fmaxf(skx + acc.x * inv, 0.f);
  float oy = fmaxf(sky + acc.y * inv, 0.f);
  unsigned hb = ((unsigned)f2bf(oy) << 16) | (unsigned)f2bf(ox);
  *(unsigned*)(Hb + (size_t)node * 128 + lane * 2) = hb;
}

// conv2: 32 lanes per node; C2 row = [Q(32) | KV(64) | H(32)] bf16.
__global__ void node_attn2(const int* __restrict__ rowptr, const int* __restrict__ esrc,
                           unsigned short* __restrict__ C2, int n) {
  int t = blockIdx.x * blockDim.x + threadIdx.x;
  int node = t >> 5;
  int lane = threadIdx.x & 31;
  if (node >= n) return;
  const int r0 = rowptr[node], r1 = rowptr[node + 1];
  const float q = bf2f(C2[(size_t)node * 128 + lane]);
  float m = -INFINITY, l = 0.f, acc = 0.f;
  const float SCL = 0.17677669529663687f;
  int j = r0;
  for (; j + 4 <= r1; j += 4) {
    int s0 = esrc[j], s1 = esrc[j + 1], s2 = esrc[j + 2], s3 = esrc[j + 3];
    unsigned u0 = *(const unsigned*)(C2 + (size_t)s0 * 128 + 32 + lane * 2);
    unsigned u1 = *(const unsigned*)(C2 + (size_t)s1 * 128 + 32 + lane * 2);
    unsigned u2 = *(const unsigned*)(C2 + (size_t)s2 * 128 + 32 + lane * 2);
    unsigned u3 = *(const unsigned*)(C2 + (size_t)s3 * 128 + 32 + lane * 2);
    float d0 = q * __uint_as_float((u0 & 0xFFFFu) << 16);
    float d1 = q * __uint_as_float((u1 & 0xFFFFu) << 16);
    float d2 = q * __uint_as_float((u2 & 0xFFFFu) << 16);
    float d3 = q * __uint_as_float((u3 & 0xFFFFu) << 16);
#pragma unroll
    for (int msk = 1; msk <= 16; msk <<= 1) {
      d0 += __shfl_xor(d0, msk);
      d1 += __shfl_xor(d1, msk);
      d2 += __shfl_xor(d2, msk);
      d3 += __shfl_xor(d3, msk);
    }
    float lg0 = d0 * SCL, lg1 = d1 * SCL, lg2 = d2 * SCL, lg3 = d3 * SCL;
    float mnew = fmaxf(fmaxf(m, fmaxf(lg0, lg1)), fmaxf(lg2, lg3));
    float sc = __expf(m - mnew);
    float p0 = __expf(lg0 - mnew), p1 = __expf(lg1 - mnew);
    float p2 = __expf(lg2 - mnew), p3 = __expf(lg3 - mnew);
    l = l * sc + (p0 + p1) + (p2 + p3);
    acc = acc * sc + p0 * __uint_as_float(u0 & 0xFFFF0000u) + p1 * __uint_as_float(u1 & 0xFFFF0000u)
                   + p2 * __uint_as_float(u2 & 0xFFFF0000u) + p3 * __uint_as_float(u3 & 0xFFFF0000u);
    m = mnew;
  }
  for (; j < r1; ++j) {
    int src = esrc[j];
    unsigned kvu = *(const unsigned*)(C2 + (size_t)src * 128 + 32 + lane * 2);
    float k = __uint_as_float((kvu & 0xFFFFu) << 16);
    float v = __uint_as_float(kvu & 0xFFFF0000u);
    float d = q * k;
    d += __shfl_xor(d, 1);
    d += __shfl_xor(d, 2);
    d += __shfl_xor(d, 4);
    d += __shfl_xor(d, 8);
    d += __shfl_xor(d, 16);
    float lg = d * SCL;
    float mnew = fmaxf(m, lg);
    float sc = __expf(m - mnew);
    float p = __expf(lg - mnew);
    l = l * sc + p;
    acc = acc * sc + p * v;
    m = mnew;
  }
  float inv = (l > 0.f) ? 1.f / l : 0.f;
  unsigned short* h = C2 + (size_t)node * 128 + 96 + lane;
  *h = f2bf(bf2f(*h) + acc * inv);
}

// ---------------- epilogue ----------------
__global__ void mean_reduce(const unsigned short* __restrict__ C2, float* __restrict__ ACC, int n) {
  __shared__ float s[256];
  float acc = 0.f;
  int stride = gridDim.x * blockDim.x;
  int total = n * 32;
  for (int i = blockIdx.x * blockDim.x + threadIdx.x; i < total; i += stride) {
    int node = i >> 5, c = i & 31;
    acc += fmaxf(bf2f(C2[(size_t)node * 128 + 96 + c]), 0.f);  // relu fused
  }
  s[threadIdx.x] = acc;
  __syncthreads();
  for (int off = 128; off >= 32; off >>= 1) {
    if (threadIdx.x < off) s[threadIdx.x] += s[threadIdx.x + off];
    __syncthreads();
  }
  if (threadIdx.x < 32) atomicAdd(&ACC[threadIdx.x], s[threadIdx.x]);
}

__global__ void final_out(const float* __restrict__ ACC, const float* __restrict__ Wo,
                          const float* __restrict__ bo, float* __restrict__ out, float invN) {
  int lane = threadIdx.x;
  float v = 0.f;
  if (lane < 32) v = ACC[lane] * invN * Wo[lane];
  v += __shfl_xor(v, 1);
  v += __shfl_xor(v, 2);
  v += __shfl_xor(v, 4);
  v += __shfl_xor(v, 8);
  v += __shfl_xor(v, 16);
  v += __shfl_xor(v, 32);
  if (lane == 0) out[0] = v + bo[0];
}

extern "C" void kernel_launch(void* const* d_in, const int* in_sizes, int n_in,
                              void* d_out, int out_size, void* d_ws, size_t ws_size,
                              hipStream_t stream) {
  const float* x   = (const float*)d_in[0];
  const int*   ei  = (const int*)d_in[1];  // [2, E]: row 0 = src, row 1 = dst
  const float* Wq1 = (const float*)d_in[2];  const float* bq1 = (const float*)d_in[3];
  const float* Wk1 = (const float*)d_in[4];  const float* bk1 = (const float*)d_in[5];
  const float* Wv1 = (const float*)d_in[6];  const float* bv1 = (const float*)d_in[7];
  const float* Ws1 = (const float*)d_in[8];  const float* bs1 = (const float*)d_in[9];
  const float* Wq2 = (const float*)d_in[10]; const float* bq2 = (const float*)d_in[11];
  const float* Wk2 = (const float*)d_in[12]; const float* bk2 = (const float*)d_in[13];
  const float* Wv2 = (const float*)d_in[14]; const float* bv2 = (const float*)d_in[15];
  const float* Ws2 = (const float*)d_in[16]; const float* bs2 = (const float*)d_in[17];
  const float* Wo  = (const float*)d_in[18]; const float* bo  = (const float*)d_in[19];

  char* ws = (char*)d_ws;
  const int N = N_NODES, E = N_EDGES;
  const int NB = (N + 255) / 256;
  const int GB = (N + 63) / 64;  // 782 GEMM row-blocks

  // buffers (all bf16 intermediates)
  unsigned short* xb  = (unsigned short*)(ws + 0);          // N*128
  unsigned short* Q1b = (unsigned short*)(ws + 12800000);   // N*128
  unsigned short* SK1 = (unsigned short*)(ws + 25600000);   // N*128
  unsigned short* KV1 = (unsigned short*)(ws + 38400000);   // N*256 interleaved
  unsigned short* H1b = (unsigned short*)(ws + 64000000);   // N*128
  unsigned short* C2  = (unsigned short*)(ws + 76800000);   // N*128 [Q|KV|H]
  // CSR + weights + misc
  int* rowptr = (int*)(ws + 102400000);
  int* cur    = (int*)(ws + 102600064);
  int* esrc   = (int*)(ws + 102800128);
  int* deg    = (int*)(ws + 106000128);
  int* bsum   = (int*)(ws + 106200192);
  int* boff   = (int*)(ws + 106201216);
  unsigned short* Wt1   = (unsigned short*)(ws + 106202240);  // 512x128
  unsigned short* Wt2   = (unsigned short*)(ws + 106333312);  // 128x128
  float*          bcat1 = (float*)(ws + 106366080);
  float*          bcat2 = (float*)(ws + 106368128);
  float*          ACC   = (float*)(ws + 106368640);

  float* out = (float*)d_out;

  hipMemsetAsync(deg, 0, (size_t)N * sizeof(int), stream);
  hipMemsetAsync(ACC, 0, 32 * sizeof(float), stream);

  dim3 blk(256);

  // ---- CSR build ----
  deg_count<<<dim3((E + 255) / 256), blk, 0, stream>>>(ei, deg, E);
  scan_part<<<dim3(NB), blk, 0, stream>>>(deg, bsum, N);
  scan_tops<<<dim3(1), blk, 0, stream>>>(bsum, boff, rowptr, NB, N);
  scan_final<<<dim3(NB), blk, 0, stream>>>(deg, boff, rowptr, cur, N);
  scatter_edges<<<dim3((E + 255) / 256), blk, 0, stream>>>(ei, cur, esrc, E);

  // ---- prep ----
  cast_bf16<<<dim3((N * 128 / 4 + 255) / 256), blk, 0, stream>>>(x, xb, N * 128 / 4);
  concat_wt<<<dim3((512 * 128 + 255) / 256), blk, 0, stream>>>(
      Wq1, Wk1, Wv1, Ws1, bq1, bk1, bv1, bs1, Wt1, bcat1, 128, 128);
  concat_wt<<<dim3((128 * 128 + 255) / 256), blk, 0, stream>>>(
      Wq2, Wk2, Wv2, Ws2, bq2, bk2, bv2, bs2, Wt2, bcat2, 128, 32);

  // ---- conv1 GEMMs ----
  gemm_bf16<<<dim3(GB, 2), blk, 0, stream>>>(xb, Wt1, bcat1, Q1b, SK1, 384, N);
  gemm_kv1<<<dim3(GB), blk, 0, stream>>>(xb, Wt1, bcat1, KV1, N);

  // ---- conv1 fused attention + skip + relu -> bf16 ----
  node_attn1<<<dim3((N * 64 + 255) / 256), blk, 0, stream>>>(rowptr, esrc, Q1b, KV1, SK1, H1b, N);

  // ---- conv2 GEMM (fused Q|KV|H rows) ----
  gemm2<<<dim3(GB), blk, 0, stream>>>(H1b, Wt2, bcat2, C2, N);

  // ---- conv2 fused attention ----
  node_attn2<<<dim3((N * 32 + 255) / 256), blk, 0, stream>>>(rowptr, esrc, C2, N);

  // ---- relu + mean + final linear ----
  mean_reduce<<<dim3(1024), blk, 0, stream>>>(C2, ACC, N);
  final_out<<<dim3(1), dim3(64), 0, stream>>>(ACC, Wo, bo, out, 1.0f / (float)N);
}

// Round 8
// 327.383 us; speedup vs baseline: 1.1788x; 1.1788x over previous
//
#include <hip/hip_runtime.h>
#include <math.h>

#define N_NODES 50000
#define N_EDGES 800000
#define NBK 196          // dst buckets of 256 nodes: bucket = dst >> 8
#define BCAP 6144        // max edges per bucket handled in LDS (mean 4082, sigma 64)

typedef short short8 __attribute__((ext_vector_type(8)));
typedef float f32x4 __attribute__((ext_vector_type(4)));

// ---------------- bf16 helpers ----------------
__device__ inline unsigned short f2bf(float v) {
  unsigned u = __float_as_uint(v);
  u += 0x7FFFu + ((u >> 16) & 1u);  // round-to-nearest-even
  return (unsigned short)(u >> 16);
}
__device__ inline float bf2f(unsigned short b) {
  return __uint_as_float(((unsigned)b) << 16);
}

// ---------------- cast x -> bf16 ----------------
__global__ void cast_bf16(const float* __restrict__ in, unsigned short* __restrict__ out, int n4) {
  int i = blockIdx.x * blockDim.x + threadIdx.x;
  if (i >= n4) return;
  float4 v = ((const float4*)in)[i];
  ushort4 o;
  o.x = f2bf(v.x); o.y = f2bf(v.y); o.z = f2bf(v.z); o.w = f2bf(v.w);
  ((ushort4*)out)[i] = o;
}

// ---------------- weight concat + transpose + bf16: Wt[c][k] ----------------
__global__ void concat_wt(const float* __restrict__ W0, const float* __restrict__ W1,
                          const float* __restrict__ W2, const float* __restrict__ W3,
                          const float* __restrict__ b0, const float* __restrict__ b1,
                          const float* __restrict__ b2, const float* __restrict__ b3,
                          unsigned short* __restrict__ Wt, float* __restrict__ bcat,
                          int K, int segN) {
  int i = blockIdx.x * blockDim.x + threadIdx.x;
  int Ncat = 4 * segN;
  if (i < Ncat * K) {
    int c = i / K, k = i % K;
    int mi = c / segN, lc = c % segN;
    const float* W = (mi == 0) ? W0 : (mi == 1) ? W1 : (mi == 2) ? W2 : W3;
    Wt[i] = f2bf(W[(size_t)k * segN + lc]);
  }
  if (i < Ncat) {
    int mi = i / segN, lc = i % segN;
    const float* b = (mi == 0) ? b0 : (mi == 1) ? b1 : (mi == 2) ? b2 : b3;
    bcat[i] = b[lc];
  }
}

// ================= GEMMs (unchanged from R7: direct-from-L2 fragments, =================
// ================= LDS-repack epilogue, coalesced bf16 row stores)      =================

__global__ __launch_bounds__(256) void gemm_bf16(
    const unsigned short* __restrict__ Ab, const unsigned short* __restrict__ Wt,
    const float* __restrict__ bcat, unsigned short* __restrict__ outA,
    unsigned short* __restrict__ outB, int coloffB, int M) {
  __shared__ unsigned short Ls[64 * 132];
  const int coloff = blockIdx.y ? coloffB : 0;
  unsigned short* out = blockIdx.y ? outB : outA;
  const int bm = blockIdx.x * 64;
  const int tid = threadIdx.x, wave = tid >> 6, lane = tid & 63;
  const int lr = lane & 15, q = lane >> 4;

  f32x4 acc[4][2];
#pragma unroll
  for (int i = 0; i < 4; ++i)
#pragma unroll
    for (int j = 0; j < 2; ++j) acc[i][j] = (f32x4){0.f, 0.f, 0.f, 0.f};

#pragma unroll
  for (int ks = 0; ks < 4; ++ks) {
    short8 af[4], bf[2];
#pragma unroll
    for (int i = 0; i < 4; ++i) {
      int gm = bm + i * 16 + lr; if (gm >= M) gm = 0;
      af[i] = *(const short8*)(Ab + (size_t)gm * 128 + ks * 32 + q * 8);
    }
#pragma unroll
    for (int j = 0; j < 2; ++j)
      bf[j] = *(const short8*)(Wt + (size_t)(coloff + wave * 32 + j * 16 + lr) * 128 + ks * 32 + q * 8);
#pragma unroll
    for (int i = 0; i < 4; ++i)
#pragma unroll
      for (int j = 0; j < 2; ++j)
        acc[i][j] = __builtin_amdgcn_mfma_f32_16x16x32_bf16(af[i], bf[j], acc[i][j], 0, 0, 0);
  }

  float bj[2];
#pragma unroll
  for (int j = 0; j < 2; ++j) bj[j] = bcat[coloff + wave * 32 + j * 16 + lr];
#pragma unroll
  for (int i = 0; i < 4; ++i)
#pragma unroll
    for (int r = 0; r < 4; ++r) {
      int row = i * 16 + q * 4 + r;
#pragma unroll
      for (int j = 0; j < 2; ++j) {
        int c = wave * 32 + j * 16 + lr;
        Ls[row * 132 + c] = f2bf(acc[i][j][r] + bj[j]);
      }
    }
  __syncthreads();
#pragma unroll
  for (int p = 0; p < 8; ++p) {
    int idx = tid + p * 256;
    int row = idx >> 5, u = idx & 31;
    int gr = bm + row;
    if (gr < M) *(uint2*)(out + (size_t)gr * 128 + u * 4) = *(const uint2*)&Ls[row * 132 + u * 4];
  }
}

__global__ __launch_bounds__(256) void gemm_kv1(
    const unsigned short* __restrict__ Ab, const unsigned short* __restrict__ Wt,
    const float* __restrict__ bcat, unsigned short* __restrict__ KV, int M) {
  __shared__ unsigned short Ls[64 * 268];
  const int bm = blockIdx.x * 64;
  const int tid = threadIdx.x, wave = tid >> 6, lane = tid & 63;
  const int lr = lane & 15, q = lane >> 4;

  f32x4 acc[4][4];
#pragma unroll
  for (int i = 0; i < 4; ++i)
#pragma unroll
    for (int j = 0; j < 4; ++j) acc[i][j] = (f32x4){0.f, 0.f, 0.f, 0.f};

#pragma unroll
  for (int ks = 0; ks < 4; ++ks) {
    short8 af[4], bf[4];
#pragma unroll
    for (int i = 0; i < 4; ++i) {
      int gm = bm + i * 16 + lr; if (gm >= M) gm = 0;
      af[i] = *(const short8*)(Ab + (size_t)gm * 128 + ks * 32 + q * 8);
    }
#pragma unroll
    for (int j = 0; j < 4; ++j)
      bf[j] = *(const short8*)(Wt + (size_t)(128 + wave * 64 + j * 16 + lr) * 128 + ks * 32 + q * 8);
#pragma unroll
    for (int i = 0; i < 4; ++i)
#pragma unroll
      for (int j = 0; j < 4; ++j)
        acc[i][j] = __builtin_amdgcn_mfma_f32_16x16x32_bf16(af[i], bf[j], acc[i][j], 0, 0, 0);
  }

  float bj[4];
#pragma unroll
  for (int j = 0; j < 4; ++j) bj[j] = bcat[128 + wave * 64 + j * 16 + lr];
#pragma unroll
  for (int i = 0; i < 4; ++i)
#pragma unroll
    for (int r = 0; r < 4; ++r) {
      int row = i * 16 + q * 4 + r;
#pragma unroll
      for (int j = 0; j < 4; ++j) {
        int c = wave * 64 + j * 16 + lr;
        int slot = (c < 128) ? ((c >> 1) * 4 + (c & 1))
                             : (((c - 128) >> 1) * 4 + 2 + ((c - 128) & 1));
        Ls[row * 268 + slot] = f2bf(acc[i][j][r] + bj[j]);
      }
    }
  __syncthreads();
#pragma unroll
  for (int p = 0; p < 16; ++p) {
    int idx = tid + p * 256;
    int row = idx >> 6, u = idx & 63;
    int gr = bm + row;
    if (gr < M) *(uint2*)(KV + (size_t)gr * 256 + u * 4) = *(const uint2*)&Ls[row * 268 + u * 4];
  }
}

__global__ __launch_bounds__(256) void gemm2(
    const unsigned short* __restrict__ Ab, const unsigned short* __restrict__ Wt,
    const float* __restrict__ bcat, unsigned short* __restrict__ C2, int M) {
  __shared__ unsigned short Ls[64 * 132];
  const int bm = blockIdx.x * 64;
  const int tid = threadIdx.x, wave = tid >> 6, lane = tid & 63;
  const int lr = lane & 15, q = lane >> 4;

  f32x4 acc[4][2];
#pragma unroll
  for (int i = 0; i < 4; ++i)
#pragma unroll
    for (int j = 0; j < 2; ++j) acc[i][j] = (f32x4){0.f, 0.f, 0.f, 0.f};

#pragma unroll
  for (int ks = 0; ks < 4; ++ks) {
    short8 af[4], bf[2];
#pragma unroll
    for (int i = 0; i < 4; ++i) {
      int gm = bm + i * 16 + lr; if (gm >= M) gm = 0;
      af[i] = *(const short8*)(Ab + (size_t)gm * 128 + ks * 32 + q * 8);
    }
#pragma unroll
    for (int j = 0; j < 2; ++j)
      bf[j] = *(const short8*)(Wt + (size_t)(wave * 32 + j * 16 + lr) * 128 + ks * 32 + q * 8);
#pragma unroll
    for (int i = 0; i < 4; ++i)
#pragma unroll
      for (int j = 0; j < 2; ++j)
        acc[i][j] = __builtin_amdgcn_mfma_f32_16x16x32_bf16(af[i], bf[j], acc[i][j], 0, 0, 0);
  }

  float bj[2];
#pragma unroll
  for (int j = 0; j < 2; ++j) bj[j] = bcat[wave * 32 + j * 16 + lr];
#pragma unroll
  for (int i = 0; i < 4; ++i)
#pragma unroll
    for (int r = 0; r < 4; ++r) {
      int row = i * 16 + q * 4 + r;
#pragma unroll
      for (int j = 0; j < 2; ++j) {
        int c = wave * 32 + j * 16 + lr;
        int slot = (c < 32) ? c
                 : (c < 64) ? (32 + (c - 32) * 2)
                 : (c < 96) ? (33 + (c - 64) * 2)
                 : c;
        Ls[row * 132 + slot] = f2bf(acc[i][j][r] + bj[j]);
      }
    }
  __syncthreads();
#pragma unroll
  for (int p = 0; p < 8; ++p) {
    int idx = tid + p * 256;
    int row = idx >> 5, u = idx & 31;
    int gr = bm + row;
    if (gr < M) *(uint2*)(C2 + (size_t)gr * 128 + u * 4) = *(const uint2*)&Ls[row * 132 + u * 4];
  }
}

// ================= CSR build via two-level bucket sort (LDS-localized) =================
// bucket = dst >> 8 (256 nodes per bucket), NBK = 196.

// phase 0: global bucket histogram (LDS-aggregated)
__global__ void bucket_hist(const int* __restrict__ ei, int* __restrict__ bhist, int E) {
  __shared__ int h[NBK];
  for (int i = threadIdx.x; i < NBK; i += 256) h[i] = 0;
  __syncthreads();
  int e = blockIdx.x * 4096 + threadIdx.x;
#pragma unroll
  for (int p = 0; p < 16; ++p, e += 256)
    if (e < E) atomicAdd(&h[ei[E + e] >> 8], 1);
  __syncthreads();
  for (int i = threadIdx.x; i < NBK; i += 256)
    if (h[i]) atomicAdd(&bhist[i], h[i]);
}

// phase 1: scan bucket counts -> boff[0..NBK], bcur (single 256-thread block)
__global__ void bucket_scan(const int* __restrict__ bhist, int* __restrict__ boff,
                            int* __restrict__ bcur) {
  __shared__ int s[256];
  int t = threadIdx.x;
  int v = (t < NBK) ? bhist[t] : 0;
  s[t] = v;
  __syncthreads();
#pragma unroll
  for (int off = 1; off < 256; off <<= 1) {
    int u = (t >= off) ? s[t - off] : 0;
    __syncthreads();
    s[t] += u;
    __syncthreads();
  }
  if (t < NBK) {
    int excl = s[t] - v;
    boff[t] = excl;
    bcur[t] = excl;
  }
  if (t == NBK - 1) boff[NBK] = s[t];
}

// phase 2: scatter (src,dst) into bucket-grouped ebuck with contiguous per-block runs
__global__ void bucket_scatter(const int* __restrict__ ei, int* __restrict__ bcur,
                               int2* __restrict__ ebuck, int E) {
  __shared__ int lh[NBK];
  for (int i = threadIdx.x; i < NBK; i += 256) lh[i] = 0;
  __syncthreads();
  const int e0 = blockIdx.x * 4096;
  int srcs[16], dsts[16];
#pragma unroll
  for (int p = 0; p < 16; ++p) {
    int e = e0 + p * 256 + threadIdx.x;
    if (e < E) {
      srcs[p] = ei[e];
      dsts[p] = ei[E + e];
      atomicAdd(&lh[dsts[p] >> 8], 1);
    } else dsts[p] = -1;
  }
  __syncthreads();
  for (int i = threadIdx.x; i < NBK; i += 256)
    if (lh[i]) lh[i] = atomicAdd(&bcur[i], lh[i]);  // lh becomes running cursor
  __syncthreads();
#pragma unroll
  for (int p = 0; p < 16; ++p) {
    if (dsts[p] >= 0) {
      int slot = atomicAdd(&lh[dsts[p] >> 8], 1);
      ebuck[slot] = make_int2(srcs[p], dsts[p]);
    }
  }
}

// phase 3: one block per bucket: LDS per-node count + scan + placement, coalesced writes
__global__ void bucket_csr(const int2* __restrict__ ebuck, const int* __restrict__ boff,
                           int* __restrict__ rowptr, int* __restrict__ esrc, int N) {
  const int b = blockIdx.x;
  const int lo = boff[b], hi = boff[b + 1];
  const int cnt = hi - lo;
  __shared__ int hist[256];
  __shared__ int cur[256];
  __shared__ int sorted[BCAP];
  const int t = threadIdx.x;
  hist[t] = 0;
  __syncthreads();
  for (int i = t; i < cnt; i += 256) {
    int2 ed = ebuck[lo + i];
    atomicAdd(&hist[ed.y & 255], 1);
  }
  __syncthreads();
  int v = hist[t];
  sorted[t] = v;  // reuse sorted[0..255] as scan temp
  __syncthreads();
#pragma unroll
  for (int off = 1; off < 256; off <<= 1) {
    int u = (t >= off) ? sorted[t - off] : 0;
    __syncthreads();
    sorted[t] += u;
    __syncthreads();
  }
  int excl = sorted[t] - v;
  cur[t] = excl;
  int node = b * 256 + t;
  if (node <= N) rowptr[node] = lo + excl;  // node==N lands here in the last bucket -> E
  __syncthreads();
  for (int i = t; i < cnt; i += 256) {
    int2 ed = ebuck[lo + i];
    int slot = atomicAdd(&cur[ed.y & 255], 1);
    if (slot < BCAP) sorted[slot] = ed.x;
    else esrc[lo + slot] = ed.x;  // overflow fallback (statistically unreachable)
  }
  __syncthreads();
  int lim = cnt < BCAP ? cnt : BCAP;
  for (int i = t; i < lim; i += 256) esrc[lo + i] = sorted[i];
}

// ---------------- fused online-softmax aggregation (unchanged) ----------------
__global__ void node_attn1(const int* __restrict__ rowptr, const int* __restrict__ esrc,
                           const unsigned short* __restrict__ Qb,
                           const unsigned short* __restrict__ KV,
                           const unsigned short* __restrict__ SK, unsigned short* __restrict__ Hb,
                           int n) {
  int node = (blockIdx.x * blockDim.x + threadIdx.x) >> 6;
  int lane = threadIdx.x & 63;
  if (node >= n) return;
  const int r0 = rowptr[node], r1 = rowptr[node + 1];
  unsigned qu = *(const unsigned*)(Qb + (size_t)node * 128 + lane * 2);
  float2 q;
  q.x = __uint_as_float((qu & 0xFFFFu) << 16);
  q.y = __uint_as_float(qu & 0xFFFF0000u);
  float m = -INFINITY, l = 0.f;
  float2 acc = {0.f, 0.f};
  const float SCL = 0.17677669529663687f;  // 1/sqrt(32)
  int j = r0;
  for (; j + 4 <= r1; j += 4) {
    int s0 = esrc[j], s1 = esrc[j + 1], s2 = esrc[j + 2], s3 = esrc[j + 3];
    ushort4 kv0 = *(const ushort4*)(KV + (size_t)s0 * 256 + lane * 4);
    ushort4 kv1 = *(const ushort4*)(KV + (size_t)s1 * 256 + lane * 4);
    ushort4 kv2 = *(const ushort4*)(KV + (size_t)s2 * 256 + lane * 4);
    ushort4 kv3 = *(const ushort4*)(KV + (size_t)s3 * 256 + lane * 4);
    float d0 = q.x * bf2f(kv0.x) + q.y * bf2f(kv0.y);
    float d1 = q.x * bf2f(kv1.x) + q.y * bf2f(kv1.y);
    float d2 = q.x * bf2f(kv2.x) + q.y * bf2f(kv2.y);
    float d3 = q.x * bf2f(kv3.x) + q.y * bf2f(kv3.y);
#pragma unroll
    for (int msk = 1; msk <= 8; msk <<= 1) {
      d0 += __shfl_xor(d0, msk);
      d1 += __shfl_xor(d1, msk);
      d2 += __shfl_xor(d2, msk);
      d3 += __shfl_xor(d3, msk);
    }
    float lg0 = d0 * SCL, lg1 = d1 * SCL, lg2 = d2 * SCL, lg3 = d3 * SCL;
    float mnew = fmaxf(fmaxf(m, fmaxf(lg0, lg1)), fmaxf(lg2, lg3));
    float sc = __expf(m - mnew);
    float p0 = __expf(lg0 - mnew), p1 = __expf(lg1 - mnew);
    float p2 = __expf(lg2 - mnew), p3 = __expf(lg3 - mnew);
    l = l * sc + (p0 + p1) + (p2 + p3);
    acc.x = acc.x * sc + p0 * bf2f(kv0.z) + p1 * bf2f(kv1.z) + p2 * bf2f(kv2.z) + p3 * bf2f(kv3.z);
    acc.y = acc.y * sc + p0 * bf2f(kv0.w) + p1 * bf2f(kv1.w) + p2 * bf2f(kv2.w) + p3 * bf2f(kv3.w);
    m = mnew;
  }
  for (; j < r1; ++j) {
    int src = esrc[j];
    ushort4 kv = *(const ushort4*)(KV + (size_t)src * 256 + lane * 4);
    float d = q.x * bf2f(kv.x) + q.y * bf2f(kv.y);
    d += __shfl_xor(d, 1);
    d += __shfl_xor(d, 2);
    d += __shfl_xor(d, 4);
    d += __shfl_xor(d, 8);
    float lg = d * SCL;
    float mnew = fmaxf(m, lg);
    float sc = __expf(m - mnew);
    float p = __expf(lg - mnew);
    l = l * sc + p;
    acc.x = acc.x * sc + p * bf2f(kv.z);
    acc.y = acc.y * sc + p * bf2f(kv.w);
    m = mnew;
  }
  float inv = (l > 0.f) ? 1.f / l : 0.f;
  unsigned sku = *(const unsigned*)(SK + (size_t)node * 128 + lane * 2);
  float skx = __uint_as_float((sku & 0xFFFFu) << 16);
  float sky = __uint_as_float(sku & 0xFFFF0000u);
  float ox = fmaxf(skx + acc.x * inv, 0.f);
  float oy = fmaxf(sky + acc.y * inv, 0.f);
  unsigned hb = ((unsigned)f2bf(oy) << 16) | (unsigned)f2bf(ox);
  *(unsigned*)(Hb + (size_t)node * 128 + lane * 2) = hb;
}

__global__ void node_attn2(const int* __restrict__ rowptr, const int* __restrict__ esrc,
                           unsigned short* __restrict__ C2, int n) {
  int t = blockIdx.x * blockDim.x + threadIdx.x;
  int node = t >> 5;
  int lane = threadIdx.x & 31;
  if (node >= n) return;
  const int r0 = rowptr[node], r1 = rowptr[node + 1];
  const float q = bf2f(C2[(size_t)node * 128 + lane]);
  float m = -INFINITY, l = 0.f, acc = 0.f;
  const float SCL = 0.17677669529663687f;
  int j = r0;
  for (; j + 4 <= r1; j += 4) {
    int s0 = esrc[j], s1 = esrc[j + 1], s2 = esrc[j + 2], s3 = esrc[j + 3];
    unsigned u0 = *(const unsigned*)(C2 + (size_t)s0 * 128 + 32 + lane * 2);
    unsigned u1 = *(const unsigned*)(C2 + (size_t)s1 * 128 + 32 + lane * 2);
    unsigned u2 = *(const unsigned*)(C2 + (size_t)s2 * 128 + 32 + lane * 2);
    unsigned u3 = *(const unsigned*)(C2 + (size_t)s3 * 128 + 32 + lane * 2);
    float d0 = q * __uint_as_float((u0 & 0xFFFFu) << 16);
    float d1 = q * __uint_as_float((u1 & 0xFFFFu) << 16);
    float d2 = q * __uint_as_float((u2 & 0xFFFFu) << 16);
    float d3 = q * __uint_as_float((u3 & 0xFFFFu) << 16);
#pragma unroll
    for (int msk = 1; msk <= 16; msk <<= 1) {
      d0 += __shfl_xor(d0, msk);
      d1 += __shfl_xor(d1, msk);
      d2 += __shfl_xor(d2, msk);
      d3 += __shfl_xor(d3, msk);
    }
    float lg0 = d0 * SCL, lg1 = d1 * SCL, lg2 = d2 * SCL, lg3 = d3 * SCL;
    float mnew = fmaxf(fmaxf(m, fmaxf(lg0, lg1)), fmaxf(lg2, lg3));
    float sc = __expf(m - mnew);
    float p0 = __expf(lg0 - mnew), p1 = __expf(lg1 - mnew);
    float p2 = __expf(lg2 - mnew), p3 = __expf(lg3 - mnew);
    l = l * sc + (p0 + p1) + (p2 + p3);
    acc = acc * sc + p0 * __uint_as_float(u0 & 0xFFFF0000u) + p1 * __uint_as_float(u1 & 0xFFFF0000u)
                   + p2 * __uint_as_float(u2 & 0xFFFF0000u) + p3 * __uint_as_float(u3 & 0xFFFF0000u);
    m = mnew;
  }
  for (; j < r1; ++j) {
    int src = esrc[j];
    unsigned kvu = *(const unsigned*)(C2 + (size_t)src * 128 + 32 + lane * 2);
    float k = __uint_as_float((kvu & 0xFFFFu) << 16);
    float v = __uint_as_float(kvu & 0xFFFF0000u);
    float d = q * k;
    d += __shfl_xor(d, 1);
    d += __shfl_xor(d, 2);
    d += __shfl_xor(d, 4);
    d += __shfl_xor(d, 8);
    d += __shfl_xor(d, 16);
    float lg = d * SCL;
    float mnew = fmaxf(m, lg);
    float sc = __expf(m - mnew);
    float p = __expf(lg - mnew);
    l = l * sc + p;
    acc = acc * sc + p * v;
    m = mnew;
  }
  float inv = (l > 0.f) ? 1.f / l : 0.f;
  unsigned short* h = C2 + (size_t)node * 128 + 96 + lane;
  *h = f2bf(bf2f(*h) + acc * inv);
}

// ---------------- epilogue ----------------
__global__ void mean_reduce(const unsigned short* __restrict__ C2, float* __restrict__ ACC, int n) {
  __shared__ float s[256];
  float acc = 0.f;
  int stride = gridDim.x * blockDim.x;
  int total = n * 32;
  for (int i = blockIdx.x * blockDim.x + threadIdx.x; i < total; i += stride) {
    int node = i >> 5, c = i & 31;
    acc += fmaxf(bf2f(C2[(size_t)node * 128 + 96 + c]), 0.f);
  }
  s[threadIdx.x] = acc;
  __syncthreads();
  for (int off = 128; off >= 32; off >>= 1) {
    if (threadIdx.x < off) s[threadIdx.x] += s[threadIdx.x + off];
    __syncthreads();
  }
  if (threadIdx.x < 32) atomicAdd(&ACC[threadIdx.x], s[threadIdx.x]);
}

__global__ void final_out(const float* __restrict__ ACC, const float* __restrict__ Wo,
                          const float* __restrict__ bo, float* __restrict__ out, float invN) {
  int lane = threadIdx.x;
  float v = 0.f;
  if (lane < 32) v = ACC[lane] * invN * Wo[lane];
  v += __shfl_xor(v, 1);
  v += __shfl_xor(v, 2);
  v += __shfl_xor(v, 4);
  v += __shfl_xor(v, 8);
  v += __shfl_xor(v, 16);
  v += __shfl_xor(v, 32);
  if (lane == 0) out[0] = v + bo[0];
}

extern "C" void kernel_launch(void* const* d_in, const int* in_sizes, int n_in,
                              void* d_out, int out_size, void* d_ws, size_t ws_size,
                              hipStream_t stream) {
  const float* x   = (const float*)d_in[0];
  const int*   ei  = (const int*)d_in[1];  // [2, E]: row 0 = src, row 1 = dst
  const float* Wq1 = (const float*)d_in[2];  const float* bq1 = (const float*)d_in[3];
  const float* Wk1 = (const float*)d_in[4];  const float* bk1 = (const float*)d_in[5];
  const float* Wv1 = (const float*)d_in[6];  const float* bv1 = (const float*)d_in[7];
  const float* Ws1 = (const float*)d_in[8];  const float* bs1 = (const float*)d_in[9];
  const float* Wq2 = (const float*)d_in[10]; const float* bq2 = (const float*)d_in[11];
  const float* Wk2 = (const float*)d_in[12]; const float* bk2 = (const float*)d_in[13];
  const float* Wv2 = (const float*)d_in[14]; const float* bv2 = (const float*)d_in[15];
  const float* Ws2 = (const float*)d_in[16]; const float* bs2 = (const float*)d_in[17];
  const float* Wo  = (const float*)d_in[18]; const float* bo  = (const float*)d_in[19];

  char* ws = (char*)d_ws;
  const int N = N_NODES, E = N_EDGES;
  const int GB = (N + 63) / 64;
  const int EB = (E + 4095) / 4096;  // 196 edge chunks

  // buffers (all bf16 intermediates)
  unsigned short* xb  = (unsigned short*)(ws + 0);          // N*128
  unsigned short* Q1b = (unsigned short*)(ws + 12800000);   // N*128
  unsigned short* SK1 = (unsigned short*)(ws + 25600000);   // N*128
  unsigned short* KV1 = (unsigned short*)(ws + 38400000);   // N*256 interleaved
  unsigned short* H1b = (unsigned short*)(ws + 64000000);   // N*128
  unsigned short* C2  = (unsigned short*)(ws + 76800000);   // N*128 [Q|KV|H]
  // CSR + weights + misc
  int* rowptr = (int*)(ws + 102400000);                     // N+1
  int* esrc   = (int*)(ws + 102700032);                     // E
  int* bhist  = (int*)(ws + 105900032);                     // NBK
  int* boff   = (int*)(ws + 105901056);                     // NBK+1
  int* bcur   = (int*)(ws + 105902080);                     // NBK
  unsigned short* Wt1   = (unsigned short*)(ws + 105903104);  // 512x128
  unsigned short* Wt2   = (unsigned short*)(ws + 106034176);  // 128x128
  float*          bcat1 = (float*)(ws + 106066944);
  float*          bcat2 = (float*)(ws + 106068992);
  float*          ACC   = (float*)(ws + 106069504);
  int2*           ebuck = (int2*)(ws + 106070016);          // E * 8B = 6.4 MB

  float* out = (float*)d_out;

  hipMemsetAsync(bhist, 0, NBK * sizeof(int), stream);
  hipMemsetAsync(ACC, 0, 32 * sizeof(float), stream);

  dim3 blk(256);

  // ---- CSR build (two-level bucket sort) ----
  bucket_hist<<<dim3(EB), blk, 0, stream>>>(ei, bhist, E);
  bucket_scan<<<dim3(1), blk, 0, stream>>>(bhist, boff, bcur);
  bucket_scatter<<<dim3(EB), blk, 0, stream>>>(ei, bcur, ebuck, E);
  bucket_csr<<<dim3(NBK), blk, 0, stream>>>(ebuck, boff, rowptr, esrc, N);

  // ---- prep ----
  cast_bf16<<<dim3((N * 128 / 4 + 255) / 256), blk, 0, stream>>>(x, xb, N * 128 / 4);
  concat_wt<<<dim3((512 * 128 + 255) / 256), blk, 0, stream>>>(
      Wq1, Wk1, Wv1, Ws1, bq1, bk1, bv1, bs1, Wt1, bcat1, 128, 128);
  concat_wt<<<dim3((128 * 128 + 255) / 256), blk, 0, stream>>>(
      Wq2, Wk2, Wv2, Ws2, bq2, bk2, bv2, bs2, Wt2, bcat2, 128, 32);

  // ---- conv1 GEMMs ----
  gemm_bf16<<<dim3(GB, 2), blk, 0, stream>>>(xb, Wt1, bcat1, Q1b, SK1, 384, N);
  gemm_kv1<<<dim3(GB), blk, 0, stream>>>(xb, Wt1, bcat1, KV1, N);

  // ---- conv1 fused attention + skip + relu -> bf16 ----
  node_attn1<<<dim3((N * 64 + 255) / 256), blk, 0, stream>>>(rowptr, esrc, Q1b, KV1, SK1, H1b, N);

  // ---- conv2 GEMM (fused Q|KV|H rows) ----
  gemm2<<<dim3(GB), blk, 0, stream>>>(H1b, Wt2, bcat2, C2, N);

  // ---- conv2 fused attention ----
  node_attn2<<<dim3((N * 32 + 255) / 256), blk, 0, stream>>>(rowptr, esrc, C2, N);

  // ---- relu + mean + final linear ----
  mean_reduce<<<dim3(1024), blk, 0, stream>>>(C2, ACC, N);
  final_out<<<dim3(1), dim3(64), 0, stream>>>(ACC, Wo, bo, out, 1.0f / (float)N);
}

// Round 9
// 315.459 us; speedup vs baseline: 1.2233x; 1.0378x over previous
//
#include <hip/hip_runtime.h>
#include <math.h>

#define N_NODES 50000
#define N_EDGES 800000
#define NBK 196          // dst buckets of 256 nodes: bucket = dst >> 8
#define BCAP 6144        // max edges per bucket handled in LDS (mean 4082, sigma 64)

typedef short short8 __attribute__((ext_vector_type(8)));
typedef unsigned short us8 __attribute__((ext_vector_type(8)));
typedef float f32x4 __attribute__((ext_vector_type(4)));

// ---------------- bf16 helpers ----------------
__device__ inline unsigned short f2bf(float v) {
  unsigned u = __float_as_uint(v);
  u += 0x7FFFu + ((u >> 16) & 1u);  // round-to-nearest-even
  return (unsigned short)(u >> 16);
}
__device__ inline float bf2f(unsigned short b) {
  return __uint_as_float(((unsigned)b) << 16);
}
__device__ inline float bflo(unsigned u) { return __uint_as_float(u << 16); }
__device__ inline float bfhi(unsigned u) { return __uint_as_float(u & 0xFFFF0000u); }

// ---------------- fused prep: cast x->bf16, concat both weight sets, zero bhist/ACC ----------------
#define CAST_B 6250   // N*128/4 / 256
#define C1_B 256      // 512*128 / 256
#define C2_B 64       // 128*128 / 256
__global__ void prep_fused(const float* __restrict__ x,
                           const float* __restrict__ Wq1, const float* __restrict__ Wk1,
                           const float* __restrict__ Wv1, const float* __restrict__ Ws1,
                           const float* __restrict__ bq1, const float* __restrict__ bk1,
                           const float* __restrict__ bv1, const float* __restrict__ bs1,
                           const float* __restrict__ Wq2, const float* __restrict__ Wk2,
                           const float* __restrict__ Wv2, const float* __restrict__ Ws2,
                           const float* __restrict__ bq2, const float* __restrict__ bk2,
                           const float* __restrict__ bv2, const float* __restrict__ bs2,
                           unsigned short* __restrict__ xb, unsigned short* __restrict__ Wt1,
                           float* __restrict__ bcat1, unsigned short* __restrict__ Wt2,
                           float* __restrict__ bcat2, int* __restrict__ bhist,
                           float* __restrict__ ACC) {
  const int b = blockIdx.x, tid = threadIdx.x;
  if (b < CAST_B) {
    int i = b * 256 + tid;  // float4 index
    float4 v = ((const float4*)x)[i];
    ushort4 o;
    o.x = f2bf(v.x); o.y = f2bf(v.y); o.z = f2bf(v.z); o.w = f2bf(v.w);
    ((ushort4*)xb)[i] = o;
  } else if (b < CAST_B + C1_B) {
    int i = (b - CAST_B) * 256 + tid;   // over 512*128
    int c = i >> 7, k = i & 127;
    int mi = c >> 7, lc = c & 127;
    const float* W = (mi == 0) ? Wq1 : (mi == 1) ? Wk1 : (mi == 2) ? Wv1 : Ws1;
    Wt1[i] = f2bf(W[(size_t)k * 128 + lc]);
    if (i < 512) {
      int bm = i >> 7, bl = i & 127;
      const float* bb = (bm == 0) ? bq1 : (bm == 1) ? bk1 : (bm == 2) ? bv1 : bs1;
      bcat1[i] = bb[bl];
    }
  } else if (b < CAST_B + C1_B + C2_B) {
    int i = (b - CAST_B - C1_B) * 256 + tid;  // over 128*128
    int c = i >> 7, k = i & 127;
    int mi = c >> 5, lc = c & 31;
    const float* W = (mi == 0) ? Wq2 : (mi == 1) ? Wk2 : (mi == 2) ? Wv2 : Ws2;
    Wt2[i] = f2bf(W[(size_t)k * 32 + lc]);
    if (i < 128) {
      int bm = i >> 5, bl = i & 31;
      const float* bb = (bm == 0) ? bq2 : (bm == 1) ? bk2 : (bm == 2) ? bv2 : bs2;
      bcat2[i] = bb[bl];
    }
  } else {
    if (tid < NBK) bhist[tid] = 0;
    else if (tid >= 224 && tid < 256) ACC[tid - 224] = 0.f;
  }
}

// ================= conv1 GEMM, unified 3-way: y=0 Q, y=1 SK, y=2 KV-interleave =================
// A [M][128] bf16, Wt1 [512][128] bf16 pre-transposed. BM=64, 256 thr = 4 waves.
__global__ __launch_bounds__(256) void gemm_conv1(
    const unsigned short* __restrict__ Ab, const unsigned short* __restrict__ Wt,
    const float* __restrict__ bcat, unsigned short* __restrict__ Q1b,
    unsigned short* __restrict__ SK1, unsigned short* __restrict__ KV, int M) {
  __shared__ unsigned short Ls[64 * 268];
  const int bm = blockIdx.x * 64;
  const int tid = threadIdx.x, wave = tid >> 6, lane = tid & 63;
  const int lr = lane & 15, q = lane >> 4;

  if (blockIdx.y < 2) {  // ---- 128-col identity path (Q or SK) ----
    const int coloff = blockIdx.y ? 384 : 0;
    unsigned short* out = blockIdx.y ? SK1 : Q1b;
    f32x4 acc[4][2];
#pragma unroll
    for (int i = 0; i < 4; ++i)
#pragma unroll
      for (int j = 0; j < 2; ++j) acc[i][j] = (f32x4){0.f, 0.f, 0.f, 0.f};
#pragma unroll
    for (int ks = 0; ks < 4; ++ks) {
      short8 af[4], bf[2];
#pragma unroll
      for (int i = 0; i < 4; ++i) {
        int gm = bm + i * 16 + lr; if (gm >= M) gm = 0;
        af[i] = *(const short8*)(Ab + (size_t)gm * 128 + ks * 32 + q * 8);
      }
#pragma unroll
      for (int j = 0; j < 2; ++j)
        bf[j] = *(const short8*)(Wt + (size_t)(coloff + wave * 32 + j * 16 + lr) * 128 + ks * 32 + q * 8);
#pragma unroll
      for (int i = 0; i < 4; ++i)
#pragma unroll
        for (int j = 0; j < 2; ++j)
          acc[i][j] = __builtin_amdgcn_mfma_f32_16x16x32_bf16(af[i], bf[j], acc[i][j], 0, 0, 0);
    }
    float bj[2];
#pragma unroll
    for (int j = 0; j < 2; ++j) bj[j] = bcat[coloff + wave * 32 + j * 16 + lr];
#pragma unroll
    for (int i = 0; i < 4; ++i)
#pragma unroll
      for (int r = 0; r < 4; ++r) {
        int row = i * 16 + q * 4 + r;
#pragma unroll
        for (int j = 0; j < 2; ++j) {
          int c = wave * 32 + j * 16 + lr;
          Ls[row * 132 + c] = f2bf(acc[i][j][r] + bj[j]);
        }
      }
    __syncthreads();
#pragma unroll
    for (int p = 0; p < 8; ++p) {
      int idx = tid + p * 256;
      int row = idx >> 5, u = idx & 31;
      int gr = bm + row;
      if (gr < M) *(uint2*)(out + (size_t)gr * 128 + u * 4) = *(const uint2*)&Ls[row * 132 + u * 4];
    }
  } else {  // ---- 256-col KV interleave path ----
    f32x4 acc[4][4];
#pragma unroll
    for (int i = 0; i < 4; ++i)
#pragma unroll
      for (int j = 0; j < 4; ++j) acc[i][j] = (f32x4){0.f, 0.f, 0.f, 0.f};
#pragma unroll
    for (int ks = 0; ks < 4; ++ks) {
      short8 af[4], bf[4];
#pragma unroll
      for (int i = 0; i < 4; ++i) {
        int gm = bm + i * 16 + lr; if (gm >= M) gm = 0;
        af[i] = *(const short8*)(Ab + (size_t)gm * 128 + ks * 32 + q * 8);
      }
#pragma unroll
      for (int j = 0; j < 4; ++j)
        bf[j] = *(const short8*)(Wt + (size_t)(128 + wave * 64 + j * 16 + lr) * 128 + ks * 32 + q * 8);
#pragma unroll
      for (int i = 0; i < 4; ++i)
#pragma unroll
        for (int j = 0; j < 4; ++j)
          acc[i][j] = __builtin_amdgcn_mfma_f32_16x16x32_bf16(af[i], bf[j], acc[i][j], 0, 0, 0);
    }
    float bj[4];
#pragma unroll
    for (int j = 0; j < 4; ++j) bj[j] = bcat[128 + wave * 64 + j * 16 + lr];
#pragma unroll
    for (int i = 0; i < 4; ++i)
#pragma unroll
      for (int r = 0; r < 4; ++r) {
        int row = i * 16 + q * 4 + r;
#pragma unroll
        for (int j = 0; j < 4; ++j) {
          int c = wave * 64 + j * 16 + lr;
          int slot = (c < 128) ? ((c >> 1) * 4 + (c & 1))
                               : (((c - 128) >> 1) * 4 + 2 + ((c - 128) & 1));
          Ls[row * 268 + slot] = f2bf(acc[i][j][r] + bj[j]);
        }
      }
    __syncthreads();
#pragma unroll
    for (int p = 0; p < 16; ++p) {
      int idx = tid + p * 256;
      int row = idx >> 6, u = idx & 63;
      int gr = bm + row;
      if (gr < M) *(uint2*)(KV + (size_t)gr * 256 + u * 4) = *(const uint2*)&Ls[row * 268 + u * 4];
    }
  }
}

// ---- gemm2: 128 cols of Wt2 -> C2 rows [Q(32) | KVinterleave(64) | H(32)] bf16 ----
__global__ __launch_bounds__(256) void gemm2(
    const unsigned short* __restrict__ Ab, const unsigned short* __restrict__ Wt,
    const float* __restrict__ bcat, unsigned short* __restrict__ C2, int M) {
  __shared__ unsigned short Ls[64 * 132];
  const int bm = blockIdx.x * 64;
  const int tid = threadIdx.x, wave = tid >> 6, lane = tid & 63;
  const int lr = lane & 15, q = lane >> 4;

  f32x4 acc[4][2];
#pragma unroll
  for (int i = 0; i < 4; ++i)
#pragma unroll
    for (int j = 0; j < 2; ++j) acc[i][j] = (f32x4){0.f, 0.f, 0.f, 0.f};

#pragma unroll
  for (int ks = 0; ks < 4; ++ks) {
    short8 af[4], bf[2];
#pragma unroll
    for (int i = 0; i < 4; ++i) {
      int gm = bm + i * 16 + lr; if (gm >= M) gm = 0;
      af[i] = *(const short8*)(Ab + (size_t)gm * 128 + ks * 32 + q * 8);
    }
#pragma unroll
    for (int j = 0; j < 2; ++j)
      bf[j] = *(const short8*)(Wt + (size_t)(wave * 32 + j * 16 + lr) * 128 + ks * 32 + q * 8);
#pragma unroll
    for (int i = 0; i < 4; ++i)
#pragma unroll
      for (int j = 0; j < 2; ++j)
        acc[i][j] = __builtin_amdgcn_mfma_f32_16x16x32_bf16(af[i], bf[j], acc[i][j], 0, 0, 0);
  }

  float bj[2];
#pragma unroll
  for (int j = 0; j < 2; ++j) bj[j] = bcat[wave * 32 + j * 16 + lr];
#pragma unroll
  for (int i = 0; i < 4; ++i)
#pragma unroll
    for (int r = 0; r < 4; ++r) {
      int row = i * 16 + q * 4 + r;
#pragma unroll
      for (int j = 0; j < 2; ++j) {
        int c = wave * 32 + j * 16 + lr;
        int slot = (c < 32) ? c
                 : (c < 64) ? (32 + (c - 32) * 2)
                 : (c < 96) ? (33 + (c - 64) * 2)
                 : c;
        Ls[row * 132 + slot] = f2bf(acc[i][j][r] + bj[j]);
      }
    }
  __syncthreads();
#pragma unroll
  for (int p = 0; p < 8; ++p) {
    int idx = tid + p * 256;
    int row = idx >> 5, u = idx & 31;
    int gr = bm + row;
    if (gr < M) *(uint2*)(C2 + (size_t)gr * 128 + u * 4) = *(const uint2*)&Ls[row * 132 + u * 4];
  }
}

// ================= CSR build via two-level bucket sort (unchanged from R8) =================
__global__ void bucket_hist(const int* __restrict__ ei, int* __restrict__ bhist, int E) {
  __shared__ int h[NBK];
  for (int i = threadIdx.x; i < NBK; i += 256) h[i] = 0;
  __syncthreads();
  int e = blockIdx.x * 4096 + threadIdx.x;
#pragma unroll
  for (int p = 0; p < 16; ++p, e += 256)
    if (e < E) atomicAdd(&h[ei[E + e] >> 8], 1);
  __syncthreads();
  for (int i = threadIdx.x; i < NBK; i += 256)
    if (h[i]) atomicAdd(&bhist[i], h[i]);
}

__global__ void bucket_scan(const int* __restrict__ bhist, int* __restrict__ boff,
                            int* __restrict__ bcur) {
  __shared__ int s[256];
  int t = threadIdx.x;
  int v = (t < NBK) ? bhist[t] : 0;
  s[t] = v;
  __syncthreads();
#pragma unroll
  for (int off = 1; off < 256; off <<= 1) {
    int u = (t >= off) ? s[t - off] : 0;
    __syncthreads();
    s[t] += u;
    __syncthreads();
  }
  if (t < NBK) {
    int excl = s[t] - v;
    boff[t] = excl;
    bcur[t] = excl;
  }
  if (t == NBK - 1) boff[NBK] = s[t];
}

__global__ void bucket_scatter(const int* __restrict__ ei, int* __restrict__ bcur,
                               int2* __restrict__ ebuck, int E) {
  __shared__ int lh[NBK];
  for (int i = threadIdx.x; i < NBK; i += 256) lh[i] = 0;
  __syncthreads();
  const int e0 = blockIdx.x * 4096;
  int srcs[16], dsts[16];
#pragma unroll
  for (int p = 0; p < 16; ++p) {
    int e = e0 + p * 256 + threadIdx.x;
    if (e < E) {
      srcs[p] = ei[e];
      dsts[p] = ei[E + e];
      atomicAdd(&lh[dsts[p] >> 8], 1);
    } else dsts[p] = -1;
  }
  __syncthreads();
  for (int i = threadIdx.x; i < NBK; i += 256)
    if (lh[i]) lh[i] = atomicAdd(&bcur[i], lh[i]);
  __syncthreads();
#pragma unroll
  for (int p = 0; p < 16; ++p) {
    if (dsts[p] >= 0) {
      int slot = atomicAdd(&lh[dsts[p] >> 8], 1);
      ebuck[slot] = make_int2(srcs[p], dsts[p]);
    }
  }
}

__global__ void bucket_csr(const int2* __restrict__ ebuck, const int* __restrict__ boff,
                           int* __restrict__ rowptr, int* __restrict__ esrc, int N) {
  const int b = blockIdx.x;
  const int lo = boff[b], hi = boff[b + 1];
  const int cnt = hi - lo;
  __shared__ int hist[256];
  __shared__ int cur[256];
  __shared__ int sorted[BCAP];
  const int t = threadIdx.x;
  hist[t] = 0;
  __syncthreads();
  for (int i = t; i < cnt; i += 256) {
    int2 ed = ebuck[lo + i];
    atomicAdd(&hist[ed.y & 255], 1);
  }
  __syncthreads();
  int v = hist[t];
  sorted[t] = v;
  __syncthreads();
#pragma unroll
  for (int off = 1; off < 256; off <<= 1) {
    int u = (t >= off) ? sorted[t - off] : 0;
    __syncthreads();
    sorted[t] += u;
    __syncthreads();
  }
  int excl = sorted[t] - v;
  cur[t] = excl;
  int node = b * 256 + t;
  if (node <= N) rowptr[node] = lo + excl;
  __syncthreads();
  for (int i = t; i < cnt; i += 256) {
    int2 ed = ebuck[lo + i];
    int slot = atomicAdd(&cur[ed.y & 255], 1);
    if (slot < BCAP) sorted[slot] = ed.x;
    else esrc[lo + slot] = ed.x;
  }
  __syncthreads();
  int lim = cnt < BCAP ? cnt : BCAP;
  for (int i = t; i < lim; i += 256) esrc[lo + i] = sorted[i];
}

// ================= fused online-softmax aggregation, half-wave layout =================
// conv1: 32 lanes per edge (lane holds K dims 4ll..4ll+3 and V dims 4ll..4ll+3 via one
// 16B load); halves process disjoint edges; state merged once per node.
__global__ void node_attn1(const int* __restrict__ rowptr, const int* __restrict__ esrc,
                           const unsigned short* __restrict__ Qb,
                           const unsigned short* __restrict__ KV,
                           const unsigned short* __restrict__ SK, unsigned short* __restrict__ Hb,
                           int n) {
  int node = (blockIdx.x * blockDim.x + threadIdx.x) >> 6;
  int lane = threadIdx.x & 63;
  if (node >= n) return;
  const int half = lane >> 5, ll = lane & 31;
  const int r0 = rowptr[node], r1 = rowptr[node + 1];
  uint2 qq = *(const uint2*)(Qb + (size_t)node * 128 + ll * 4);
  const float q0 = bflo(qq.x), q1 = bfhi(qq.x), q2 = bflo(qq.y), q3 = bfhi(qq.y);
  float m = -INFINITY, l = 0.f, a0 = 0.f, a1 = 0.f, a2 = 0.f, a3 = 0.f;
  const float SCL = 0.17677669529663687f;  // 1/sqrt(32)
  int j = r0;
  for (; j + 4 <= r1; j += 4) {
    int eA = j + half * 2;
    int sA = esrc[eA], sB = esrc[eA + 1];
    us8 kvA = *(const us8*)(KV + (size_t)sA * 256 + ll * 8);
    us8 kvB = *(const us8*)(KV + (size_t)sB * 256 + ll * 8);
    float dA = q0 * bf2f(kvA[0]) + q1 * bf2f(kvA[1]) + q2 * bf2f(kvA[4]) + q3 * bf2f(kvA[5]);
    float dB = q0 * bf2f(kvB[0]) + q1 * bf2f(kvB[1]) + q2 * bf2f(kvB[4]) + q3 * bf2f(kvB[5]);
    dA += __shfl_xor(dA, 1); dB += __shfl_xor(dB, 1);
    dA += __shfl_xor(dA, 2); dB += __shfl_xor(dB, 2);
    dA += __shfl_xor(dA, 4); dB += __shfl_xor(dB, 4);
    float lgA = dA * SCL, lgB = dB * SCL;
    float mnew = fmaxf(m, fmaxf(lgA, lgB));
    float sc = __expf(m - mnew);           // first chunk: exp(-inf)=0
    float pA = __expf(lgA - mnew), pB = __expf(lgB - mnew);
    l = l * sc + pA + pB;
    a0 = a0 * sc + pA * bf2f(kvA[2]) + pB * bf2f(kvB[2]);
    a1 = a1 * sc + pA * bf2f(kvA[3]) + pB * bf2f(kvB[3]);
    a2 = a2 * sc + pA * bf2f(kvA[6]) + pB * bf2f(kvB[6]);
    a3 = a3 * sc + pA * bf2f(kvA[7]) + pB * bf2f(kvB[7]);
    m = mnew;
  }
  if (j < r1) {  // tail: 1..3 edges, masked
    int eA = j + half * 2, eB = eA + 1;
    bool vA = eA < r1, vB = eB < r1;
    int sA = esrc[vA ? eA : r0];
    int sB = esrc[vB ? eB : r0];
    us8 kvA = *(const us8*)(KV + (size_t)sA * 256 + ll * 8);
    us8 kvB = *(const us8*)(KV + (size_t)sB * 256 + ll * 8);
    float dA = q0 * bf2f(kvA[0]) + q1 * bf2f(kvA[1]) + q2 * bf2f(kvA[4]) + q3 * bf2f(kvA[5]);
    float dB = q0 * bf2f(kvB[0]) + q1 * bf2f(kvB[1]) + q2 * bf2f(kvB[4]) + q3 * bf2f(kvB[5]);
    dA += __shfl_xor(dA, 1); dB += __shfl_xor(dB, 1);
    dA += __shfl_xor(dA, 2); dB += __shfl_xor(dB, 2);
    dA += __shfl_xor(dA, 4); dB += __shfl_xor(dB, 4);
    float lgA = vA ? dA * SCL : -INFINITY;
    float lgB = vB ? dB * SCL : -INFINITY;
    float mnew = fmaxf(m, fmaxf(lgA, lgB));
    float sc = (mnew == -INFINITY) ? 0.f : __expf(m - mnew);
    float pA = vA ? __expf(lgA - mnew) : 0.f;
    float pB = vB ? __expf(lgB - mnew) : 0.f;
    l = l * sc + pA + pB;
    a0 = a0 * sc + pA * bf2f(kvA[2]) + pB * bf2f(kvB[2]);
    a1 = a1 * sc + pA * bf2f(kvA[3]) + pB * bf2f(kvB[3]);
    a2 = a2 * sc + pA * bf2f(kvA[6]) + pB * bf2f(kvB[6]);
    a3 = a3 * sc + pA * bf2f(kvA[7]) + pB * bf2f(kvB[7]);
    m = mnew;
  }
  // merge the two halves
  float mo = __shfl_xor(m, 32);
  float lo = __shfl_xor(l, 32);
  float b0 = __shfl_xor(a0, 32), b1 = __shfl_xor(a1, 32);
  float b2 = __shfl_xor(a2, 32), b3 = __shfl_xor(a3, 32);
  float mm = fmaxf(m, mo);
  float s1 = (m == -INFINITY) ? 0.f : __expf(m - mm);
  float s2 = (mo == -INFINITY) ? 0.f : __expf(mo - mm);
  l = l * s1 + lo * s2;
  a0 = a0 * s1 + b0 * s2;
  a1 = a1 * s1 + b1 * s2;
  a2 = a2 * s1 + b2 * s2;
  a3 = a3 * s1 + b3 * s2;
  float inv = (l > 0.f) ? 1.f / l : 0.f;
  if (half == 0) {
    uint2 sk = *(const uint2*)(SK + (size_t)node * 128 + ll * 4);
    float o0 = fmaxf(bflo(sk.x) + a0 * inv, 0.f);
    float o1 = fmaxf(bfhi(sk.x) + a1 * inv, 0.f);
    float o2 = fmaxf(bflo(sk.y) + a2 * inv, 0.f);
    float o3 = fmaxf(bfhi(sk.y) + a3 * inv, 0.f);
    uint2 hb;
    hb.x = ((unsigned)f2bf(o1) << 16) | (unsigned)f2bf(o0);
    hb.y = ((unsigned)f2bf(o3) << 16) | (unsigned)f2bf(o2);
    *(uint2*)(Hb + (size_t)node * 128 + ll * 4) = hb;
  }
}

// conv2: 16 lanes per edge (lane holds k/v dims 2gl, 2gl+1 via one 8B load);
// 4 edge-groups per wave; 2-level merge. One node per wave.
__global__ void node_attn2(const int* __restrict__ rowptr, const int* __restrict__ esrc,
                           unsigned short* __restrict__ C2, int n) {
  int node = (blockIdx.x * blockDim.x + threadIdx.x) >> 6;
  int lane = threadIdx.x & 63;
  if (node >= n) return;
  const int g = lane >> 4, gl = lane & 15;
  const int r0 = rowptr[node], r1 = rowptr[node + 1];
  unsigned qu = *(const unsigned*)(C2 + (size_t)node * 128 + gl * 2);
  const float q0 = bflo(qu), q1 = bfhi(qu);
  float m = -INFINITY, l = 0.f, a0 = 0.f, a1 = 0.f;
  const float SCL = 0.17677669529663687f;
  int j = r0;
  for (; j + 4 <= r1; j += 4) {
    int s = esrc[j + g];
    uint2 kv = *(const uint2*)(C2 + (size_t)s * 128 + 32 + gl * 4);
    float d = q0 * bflo(kv.x) + q1 * bflo(kv.y);
    d += __shfl_xor(d, 1);
    d += __shfl_xor(d, 2);
    d += __shfl_xor(d, 4);
    d += __shfl_xor(d, 8);
    float lg = d * SCL;
    float mnew = fmaxf(m, lg);
    float sc = __expf(m - mnew);
    float p = __expf(lg - mnew);
    l = l * sc + p;
    a0 = a0 * sc + p * bfhi(kv.x);
    a1 = a1 * sc + p * bfhi(kv.y);
    m = mnew;
  }
  if (j < r1) {  // tail: 1..3 edges, masked per group
    bool v = (j + g) < r1;
    int s = esrc[v ? j + g : r0];
    uint2 kv = *(const uint2*)(C2 + (size_t)s * 128 + 32 + gl * 4);
    float d = q0 * bflo(kv.x) + q1 * bflo(kv.y);
    d += __shfl_xor(d, 1);
    d += __shfl_xor(d, 2);
    d += __shfl_xor(d, 4);
    d += __shfl_xor(d, 8);
    float lg = v ? d * SCL : -INFINITY;
    float mnew = fmaxf(m, lg);
    float sc = (mnew == -INFINITY) ? 0.f : __expf(m - mnew);
    float p = v ? __expf(lg - mnew) : 0.f;
    l = l * sc + p;
    a0 = a0 * sc + p * bfhi(kv.x);
    a1 = a1 * sc + p * bfhi(kv.y);
    m = mnew;
  }
  // 2-level merge across the 4 groups
#pragma unroll
  for (int msk = 16; msk <= 32; msk <<= 1) {
    float mo = __shfl_xor(m, msk), lo = __shfl_xor(l, msk);
    float c0 = __shfl_xor(a0, msk), c1 = __shfl_xor(a1, msk);
    float mm = fmaxf(m, mo);
    float s1 = (m == -INFINITY) ? 0.f : __expf(m - mm);
    float s2 = (mo == -INFINITY) ? 0.f : __expf(mo - mm);
    l = l * s1 + lo * s2;
    a0 = a0 * s1 + c0 * s2;
    a1 = a1 * s1 + c1 * s2;
    m = mm;
  }
  float inv = (l > 0.f) ? 1.f / l : 0.f;
  if (lane < 16) {
    unsigned short* h = C2 + (size_t)node * 128 + 96 + gl * 2;
    unsigned hu = *(unsigned*)h;
    float o0 = bflo(hu) + a0 * inv;
    float o1 = bfhi(hu) + a1 * inv;
    *(unsigned*)h = ((unsigned)f2bf(o1) << 16) | (unsigned)f2bf(o0);
  }
}

// ---------------- epilogue ----------------
__global__ void mean_reduce(const unsigned short* __restrict__ C2, float* __restrict__ ACC, int n) {
  __shared__ float s[256];
  float acc = 0.f;
  int stride = gridDim.x * blockDim.x;
  int total = n * 32;
  for (int i = blockIdx.x * blockDim.x + threadIdx.x; i < total; i += stride) {
    int node = i >> 5, c = i & 31;
    acc += fmaxf(bf2f(C2[(size_t)node * 128 + 96 + c]), 0.f);
  }
  s[threadIdx.x] = acc;
  __syncthreads();
  for (int off = 128; off >= 32; off >>= 1) {
    if (threadIdx.x < off) s[threadIdx.x] += s[threadIdx.x + off];
    __syncthreads();
  }
  if (threadIdx.x < 32) atomicAdd(&ACC[threadIdx.x], s[threadIdx.x]);
}

__global__ void final_out(const float* __restrict__ ACC, const float* __restrict__ Wo,
                          const float* __restrict__ bo, float* __restrict__ out, float invN) {
  int lane = threadIdx.x;
  float v = 0.f;
  if (lane < 32) v = ACC[lane] * invN * Wo[lane];
  v += __shfl_xor(v, 1);
  v += __shfl_xor(v, 2);
  v += __shfl_xor(v, 4);
  v += __shfl_xor(v, 8);
  v += __shfl_xor(v, 16);
  v += __shfl_xor(v, 32);
  if (lane == 0) out[0] = v + bo[0];
}

extern "C" void kernel_launch(void* const* d_in, const int* in_sizes, int n_in,
                              void* d_out, int out_size, void* d_ws, size_t ws_size,
                              hipStream_t stream) {
  const float* x   = (const float*)d_in[0];
  const int*   ei  = (const int*)d_in[1];  // [2, E]: row 0 = src, row 1 = dst
  const float* Wq1 = (const float*)d_in[2];  const float* bq1 = (const float*)d_in[3];
  const float* Wk1 = (const float*)d_in[4];  const float* bk1 = (const float*)d_in[5];
  const float* Wv1 = (const float*)d_in[6];  const float* bv1 = (const float*)d_in[7];
  const float* Ws1 = (const float*)d_in[8];  const float* bs1 = (const float*)d_in[9];
  const float* Wq2 = (const float*)d_in[10]; const float* bq2 = (const float*)d_in[11];
  const float* Wk2 = (const float*)d_in[12]; const float* bk2 = (const float*)d_in[13];
  const float* Wv2 = (const float*)d_in[14]; const float* bv2 = (const float*)d_in[15];
  const float* Ws2 = (const float*)d_in[16]; const float* bs2 = (const float*)d_in[17];
  const float* Wo  = (const float*)d_in[18]; const float* bo  = (const float*)d_in[19];

  char* ws = (char*)d_ws;
  const int N = N_NODES, E = N_EDGES;
  const int GB = (N + 63) / 64;
  const int EB = (E + 4095) / 4096;

  // buffers (all bf16 intermediates)
  unsigned short* xb  = (unsigned short*)(ws + 0);          // N*128
  unsigned short* Q1b = (unsigned short*)(ws + 12800000);   // N*128
  unsigned short* SK1 = (unsigned short*)(ws + 25600000);   // N*128
  unsigned short* KV1 = (unsigned short*)(ws + 38400000);   // N*256 interleaved
  unsigned short* H1b = (unsigned short*)(ws + 64000000);   // N*128
  unsigned short* C2  = (unsigned short*)(ws + 76800000);   // N*128 [Q|KV|H]
  // CSR + weights + misc
  int* rowptr = (int*)(ws + 102400000);                     // N+1
  int* esrc   = (int*)(ws + 102700032);                     // E
  int* bhist  = (int*)(ws + 105900032);                     // NBK
  int* boff   = (int*)(ws + 105901056);                     // NBK+1
  int* bcur   = (int*)(ws + 105902080);                     // NBK
  unsigned short* Wt1   = (unsigned short*)(ws + 105903104);  // 512x128
  unsigned short* Wt2   = (unsigned short*)(ws + 106034176);  // 128x128
  float*          bcat1 = (float*)(ws + 106066944);
  float*          bcat2 = (float*)(ws + 106068992);
  float*          ACC   = (float*)(ws + 106069504);
  int2*           ebuck = (int2*)(ws + 106070016);          // E * 8B

  float* out = (float*)d_out;

  dim3 blk(256);

  // ---- fused prep (also zeroes bhist/ACC; must precede CSR build) ----
  prep_fused<<<dim3(CAST_B + C1_B + C2_B + 1), blk, 0, stream>>>(
      x, Wq1, Wk1, Wv1, Ws1, bq1, bk1, bv1, bs1,
      Wq2, Wk2, Wv2, Ws2, bq2, bk2, bv2, bs2,
      xb, Wt1, bcat1, Wt2, bcat2, bhist, ACC);

  // ---- CSR build (two-level bucket sort) ----
  bucket_hist<<<dim3(EB), blk, 0, stream>>>(ei, bhist, E);
  bucket_scan<<<dim3(1), blk, 0, stream>>>(bhist, boff, bcur);
  bucket_scatter<<<dim3(EB), blk, 0, stream>>>(ei, bcur, ebuck, E);
  bucket_csr<<<dim3(NBK), blk, 0, stream>>>(ebuck, boff, rowptr, esrc, N);

  // ---- conv1 GEMMs (one 3-way launch) ----
  gemm_conv1<<<dim3(GB, 3), blk, 0, stream>>>(xb, Wt1, bcat1, Q1b, SK1, KV1, N);

  // ---- conv1 fused attention + skip + relu -> bf16 ----
  node_attn1<<<dim3((N * 64 + 255) / 256), blk, 0, stream>>>(rowptr, esrc, Q1b, KV1, SK1, H1b, N);

  // ---- conv2 GEMM (fused Q|KV|H rows) ----
  gemm2<<<dim3(GB), blk, 0, stream>>>(H1b, Wt2, bcat2, C2, N);

  // ---- conv2 fused attention ----
  node_attn2<<<dim3((N * 64 + 255) / 256), blk, 0, stream>>>(rowptr, esrc, C2, N);

  // ---- relu + mean + final linear ----
  mean_reduce<<<dim3(1024), blk, 0, stream>>>(C2, ACC, N);
  final_out<<<dim3(1), dim3(64), 0, stream>>>(ACC, Wo, bo, out, 1.0f / (float)N);
}

// Round 11
// 302.637 us; speedup vs baseline: 1.2752x; 1.0424x over previous
//
#include <hip/hip_runtime.h>
#include <math.h>

#define N_NODES 50000
#define N_EDGES 800000
#define NBK 196          // dst buckets of 256 nodes: bucket = dst >> 8
#define BCAP 6144        // max edges per bucket handled in LDS (mean 4082, sigma 64)

typedef short short8 __attribute__((ext_vector_type(8)));
typedef float f32x4 __attribute__((ext_vector_type(4)));
typedef float f32x2 __attribute__((ext_vector_type(2)));

// ---------------- bf16 / fp8 helpers ----------------
__device__ inline unsigned short f2bf(float v) {
  unsigned u = __float_as_uint(v);
  u += 0x7FFFu + ((u >> 16) & 1u);  // round-to-nearest-even
  return (unsigned short)(u >> 16);
}
__device__ inline float bf2f(unsigned short b) {
  return __uint_as_float(((unsigned)b) << 16);
}
__device__ inline float bflo(unsigned u) { return __uint_as_float(u << 16); }
__device__ inline float bfhi(unsigned u) { return __uint_as_float(u & 0xFFFF0000u); }
// fp8 e4m3 (OCP on gfx950): HW packed converts. Selector must be an immediate ->
// template parameter.
__device__ inline unsigned char f2fp8(float v) {
  return (unsigned char)(__builtin_amdgcn_cvt_pk_fp8_f32(v, 0.f, 0, false) & 0xFF);
}
template <bool HI>
__device__ inline f32x2 fp8dec(unsigned u) {
  return __builtin_amdgcn_cvt_pk_f32_fp8(u, HI);
}

// ---------------- fused prep: cast x->bf16, concat both weight sets, zero bhist/ACC ----------------
#define CAST_B 6250   // N*128/4 / 256
#define C1_B 256      // 512*128 / 256
#define C2_B 64       // 128*128 / 256
__global__ void prep_fused(const float* __restrict__ x,
                           const float* __restrict__ Wq1, const float* __restrict__ Wk1,
                           const float* __restrict__ Wv1, const float* __restrict__ Ws1,
                           const float* __restrict__ bq1, const float* __restrict__ bk1,
                           const float* __restrict__ bv1, const float* __restrict__ bs1,
                           const float* __restrict__ Wq2, const float* __restrict__ Wk2,
                           const float* __restrict__ Wv2, const float* __restrict__ Ws2,
                           const float* __restrict__ bq2, const float* __restrict__ bk2,
                           const float* __restrict__ bv2, const float* __restrict__ bs2,
                           unsigned short* __restrict__ xb, unsigned short* __restrict__ Wt1,
                           float* __restrict__ bcat1, unsigned short* __restrict__ Wt2,
                           float* __restrict__ bcat2, int* __restrict__ bhist,
                           float* __restrict__ ACC) {
  const int b = blockIdx.x, tid = threadIdx.x;
  if (b < CAST_B) {
    int i = b * 256 + tid;  // float4 index
    float4 v = ((const float4*)x)[i];
    ushort4 o;
    o.x = f2bf(v.x); o.y = f2bf(v.y); o.z = f2bf(v.z); o.w = f2bf(v.w);
    ((ushort4*)xb)[i] = o;
  } else if (b < CAST_B + C1_B) {
    int i = (b - CAST_B) * 256 + tid;   // over 512*128
    int c = i >> 7, k = i & 127;
    int mi = c >> 7, lc = c & 127;
    const float* W = (mi == 0) ? Wq1 : (mi == 1) ? Wk1 : (mi == 2) ? Wv1 : Ws1;
    Wt1[i] = f2bf(W[(size_t)k * 128 + lc]);
    if (i < 512) {
      int bm = i >> 7, bl = i & 127;
      const float* bb = (bm == 0) ? bq1 : (bm == 1) ? bk1 : (bm == 2) ? bv1 : bs1;
      bcat1[i] = bb[bl];
    }
  } else if (b < CAST_B + C1_B + C2_B) {
    int i = (b - CAST_B - C1_B) * 256 + tid;  // over 128*128
    int c = i >> 7, k = i & 127;
    int mi = c >> 5, lc = c & 31;
    const float* W = (mi == 0) ? Wq2 : (mi == 1) ? Wk2 : (mi == 2) ? Wv2 : Ws2;
    Wt2[i] = f2bf(W[(size_t)k * 32 + lc]);
    if (i < 128) {
      int bm = i >> 5, bl = i & 31;
      const float* bb = (bm == 0) ? bq2 : (bm == 1) ? bk2 : (bm == 2) ? bv2 : bs2;
      bcat2[i] = bb[bl];
    }
  } else {
    if (tid < NBK) bhist[tid] = 0;
    else if (tid >= 224 && tid < 256) ACC[tid - 224] = 0.f;
  }
}

// ================= conv1 GEMM, unified 3-way: y=0 Q(bf16), y=1 SK(bf16), y=2 KV(fp8) =================
// A [M][128] bf16, Wt1 [512][128] bf16 pre-transposed. BM=64, 256 thr = 4 waves.
// KV fp8 row (256 B/node): byte 4t+{0,1} = K[2t,2t+1], byte 4t+{2,3} = V[2t,2t+1].
__global__ __launch_bounds__(256) void gemm_conv1(
    const unsigned short* __restrict__ Ab, const unsigned short* __restrict__ Wt,
    const float* __restrict__ bcat, unsigned short* __restrict__ Q1b,
    unsigned short* __restrict__ SK1, unsigned char* __restrict__ KV8, int M) {
  __shared__ __align__(16) unsigned char Lsb[64 * 272];
  unsigned short* Ls16 = (unsigned short*)Lsb;   // stride 136 shorts (= 272 B)
  const int bm = blockIdx.x * 64;
  const int tid = threadIdx.x, wave = tid >> 6, lane = tid & 63;
  const int lr = lane & 15, q = lane >> 4;

  if (blockIdx.y < 2) {  // ---- 128-col bf16 identity path (Q or SK) ----
    const int coloff = blockIdx.y ? 384 : 0;
    unsigned short* out = blockIdx.y ? SK1 : Q1b;
    f32x4 acc[4][2];
#pragma unroll
    for (int i = 0; i < 4; ++i)
#pragma unroll
      for (int j = 0; j < 2; ++j) acc[i][j] = (f32x4){0.f, 0.f, 0.f, 0.f};
#pragma unroll
    for (int ks = 0; ks < 4; ++ks) {
      short8 af[4], bf[2];
#pragma unroll
      for (int i = 0; i < 4; ++i) {
        int gm = bm + i * 16 + lr; if (gm >= M) gm = 0;
        af[i] = *(const short8*)(Ab + (size_t)gm * 128 + ks * 32 + q * 8);
      }
#pragma unroll
      for (int j = 0; j < 2; ++j)
        bf[j] = *(const short8*)(Wt + (size_t)(coloff + wave * 32 + j * 16 + lr) * 128 + ks * 32 + q * 8);
#pragma unroll
      for (int i = 0; i < 4; ++i)
#pragma unroll
        for (int j = 0; j < 2; ++j)
          acc[i][j] = __builtin_amdgcn_mfma_f32_16x16x32_bf16(af[i], bf[j], acc[i][j], 0, 0, 0);
    }
    float bj[2];
#pragma unroll
    for (int j = 0; j < 2; ++j) bj[j] = bcat[coloff + wave * 32 + j * 16 + lr];
#pragma unroll
    for (int i = 0; i < 4; ++i)
#pragma unroll
      for (int r = 0; r < 4; ++r) {
        int row = i * 16 + q * 4 + r;
#pragma unroll
        for (int j = 0; j < 2; ++j) {
          int c = wave * 32 + j * 16 + lr;
          Ls16[row * 136 + c] = f2bf(acc[i][j][r] + bj[j]);
        }
      }
    __syncthreads();
#pragma unroll
    for (int p = 0; p < 8; ++p) {
      int idx = tid + p * 256;
      int row = idx >> 5, u = idx & 31;
      int gr = bm + row;
      if (gr < M) *(uint2*)(out + (size_t)gr * 128 + u * 4) = *(const uint2*)&Ls16[row * 136 + u * 4];
    }
  } else {  // ---- 256-col KV fp8 interleave path ----
    f32x4 acc[4][4];
#pragma unroll
    for (int i = 0; i < 4; ++i)
#pragma unroll
      for (int j = 0; j < 4; ++j) acc[i][j] = (f32x4){0.f, 0.f, 0.f, 0.f};
#pragma unroll
    for (int ks = 0; ks < 4; ++ks) {
      short8 af[4], bf[4];
#pragma unroll
      for (int i = 0; i < 4; ++i) {
        int gm = bm + i * 16 + lr; if (gm >= M) gm = 0;
        af[i] = *(const short8*)(Ab + (size_t)gm * 128 + ks * 32 + q * 8);
      }
#pragma unroll
      for (int j = 0; j < 4; ++j)
        bf[j] = *(const short8*)(Wt + (size_t)(128 + wave * 64 + j * 16 + lr) * 128 + ks * 32 + q * 8);
#pragma unroll
      for (int i = 0; i < 4; ++i)
#pragma unroll
        for (int j = 0; j < 4; ++j)
          acc[i][j] = __builtin_amdgcn_mfma_f32_16x16x32_bf16(af[i], bf[j], acc[i][j], 0, 0, 0);
    }
    float bj[4];
#pragma unroll
    for (int j = 0; j < 4; ++j) bj[j] = bcat[128 + wave * 64 + j * 16 + lr];
#pragma unroll
    for (int i = 0; i < 4; ++i)
#pragma unroll
      for (int r = 0; r < 4; ++r) {
        int row = i * 16 + q * 4 + r;
#pragma unroll
        for (int j = 0; j < 4; ++j) {
          int c = wave * 64 + j * 16 + lr;  // 0..255 over K|V
          int bslot = (c < 128) ? (4 * (c >> 1) + (c & 1))
                                : (4 * ((c - 128) >> 1) + 2 + ((c - 128) & 1));
          Lsb[row * 272 + bslot] = f2fp8(acc[i][j][r] + bj[j]);
        }
      }
    __syncthreads();
    // readout: 64 rows x 64 uints = 4096, 16 per thread
#pragma unroll
    for (int p = 0; p < 16; ++p) {
      int idx = tid + p * 256;
      int row = idx >> 6, u = idx & 63;
      int gr = bm + row;
      if (gr < M) *(unsigned*)(KV8 + (size_t)gr * 256 + u * 4) = *(const unsigned*)&Lsb[row * 272 + u * 4];
    }
  }
}

// ---- gemm2: 128 cols of Wt2 -> C2 rows (256 B): [Q 32 bf16 | KV fp8 64 B | pad | H 32 bf16] ----
// byte layout: Q at 2c (c<32); K d -> 64+4*(d>>1)+(d&1); V d -> 64+4*(d>>1)+2+(d&1); H at 192+2*(c-96).
__global__ __launch_bounds__(256) void gemm2(
    const unsigned short* __restrict__ Ab, const unsigned short* __restrict__ Wt,
    const float* __restrict__ bcat, unsigned char* __restrict__ C2b, int M) {
  __shared__ __align__(16) unsigned char Lsb[64 * 272];
  const int bm = blockIdx.x * 64;
  const int tid = threadIdx.x, wave = tid >> 6, lane = tid & 63;
  const int lr = lane & 15, q = lane >> 4;

  f32x4 acc[4][2];
#pragma unroll
  for (int i = 0; i < 4; ++i)
#pragma unroll
    for (int j = 0; j < 2; ++j) acc[i][j] = (f32x4){0.f, 0.f, 0.f, 0.f};

#pragma unroll
  for (int ks = 0; ks < 4; ++ks) {
    short8 af[4], bf[2];
#pragma unroll
    for (int i = 0; i < 4; ++i) {
      int gm = bm + i * 16 + lr; if (gm >= M) gm = 0;
      af[i] = *(const short8*)(Ab + (size_t)gm * 128 + ks * 32 + q * 8);
    }
#pragma unroll
    for (int j = 0; j < 2; ++j)
      bf[j] = *(const short8*)(Wt + (size_t)(wave * 32 + j * 16 + lr) * 128 + ks * 32 + q * 8);
#pragma unroll
    for (int i = 0; i < 4; ++i)
#pragma unroll
      for (int j = 0; j < 2; ++j)
        acc[i][j] = __builtin_amdgcn_mfma_f32_16x16x32_bf16(af[i], bf[j], acc[i][j], 0, 0, 0);
  }

  float bj[2];
#pragma unroll
  for (int j = 0; j < 2; ++j) bj[j] = bcat[wave * 32 + j * 16 + lr];
#pragma unroll
  for (int i = 0; i < 4; ++i)
#pragma unroll
    for (int r = 0; r < 4; ++r) {
      int row = i * 16 + q * 4 + r;
#pragma unroll
      for (int j = 0; j < 2; ++j) {
        int c = wave * 32 + j * 16 + lr;
        float val = acc[i][j][r] + bj[j];
        if (c < 32) {
          *(unsigned short*)&Lsb[row * 272 + 2 * c] = f2bf(val);
        } else if (c < 64) {
          int d = c - 32;
          Lsb[row * 272 + 64 + 4 * (d >> 1) + (d & 1)] = f2fp8(val);
        } else if (c < 96) {
          int d = c - 64;
          Lsb[row * 272 + 64 + 4 * (d >> 1) + 2 + (d & 1)] = f2fp8(val);
        } else {
          *(unsigned short*)&Lsb[row * 272 + 192 + 2 * (c - 96)] = f2bf(val);
        }
      }
    }
  __syncthreads();
  // readout: 64 rows x 64 uints (bytes 0..255; 128..191 are pad/garbage but harmless)
#pragma unroll
  for (int p = 0; p < 16; ++p) {
    int idx = tid + p * 256;
    int row = idx >> 6, u = idx & 63;
    int gr = bm + row;
    if (gr < M) *(unsigned*)(C2b + (size_t)gr * 256 + u * 4) = *(const unsigned*)&Lsb[row * 272 + u * 4];
  }
}

// ================= CSR build via two-level bucket sort (unchanged) =================
__global__ void bucket_hist(const int* __restrict__ ei, int* __restrict__ bhist, int E) {
  __shared__ int h[NBK];
  for (int i = threadIdx.x; i < NBK; i += 256) h[i] = 0;
  __syncthreads();
  int e = blockIdx.x * 4096 + threadIdx.x;
#pragma unroll
  for (int p = 0; p < 16; ++p, e += 256)
    if (e < E) atomicAdd(&h[ei[E + e] >> 8], 1);
  __syncthreads();
  for (int i = threadIdx.x; i < NBK; i += 256)
    if (h[i]) atomicAdd(&bhist[i], h[i]);
}

__global__ void bucket_scan(const int* __restrict__ bhist, int* __restrict__ boff,
                            int* __restrict__ bcur) {
  __shared__ int s[256];
  int t = threadIdx.x;
  int v = (t < NBK) ? bhist[t] : 0;
  s[t] = v;
  __syncthreads();
#pragma unroll
  for (int off = 1; off < 256; off <<= 1) {
    int u = (t >= off) ? s[t - off] : 0;
    __syncthreads();
    s[t] += u;
    __syncthreads();
  }
  if (t < NBK) {
    int excl = s[t] - v;
    boff[t] = excl;
    bcur[t] = excl;
  }
  if (t == NBK - 1) boff[NBK] = s[t];
}

__global__ void bucket_scatter(const int* __restrict__ ei, int* __restrict__ bcur,
                               int2* __restrict__ ebuck, int E) {
  __shared__ int lh[NBK];
  for (int i = threadIdx.x; i < NBK; i += 256) lh[i] = 0;
  __syncthreads();
  const int e0 = blockIdx.x * 4096;
  int srcs[16], dsts[16];
#pragma unroll
  for (int p = 0; p < 16; ++p) {
    int e = e0 + p * 256 + threadIdx.x;
    if (e < E) {
      srcs[p] = ei[e];
      dsts[p] = ei[E + e];
      atomicAdd(&lh[dsts[p] >> 8], 1);
    } else dsts[p] = -1;
  }
  __syncthreads();
  for (int i = threadIdx.x; i < NBK; i += 256)
    if (lh[i]) lh[i] = atomicAdd(&bcur[i], lh[i]);
  __syncthreads();
#pragma unroll
  for (int p = 0; p < 16; ++p) {
    if (dsts[p] >= 0) {
      int slot = atomicAdd(&lh[dsts[p] >> 8], 1);
      ebuck[slot] = make_int2(srcs[p], dsts[p]);
    }
  }
}

__global__ void bucket_csr(const int2* __restrict__ ebuck, const int* __restrict__ boff,
                           int* __restrict__ rowptr, int* __restrict__ esrc, int N) {
  const int b = blockIdx.x;
  const int lo = boff[b], hi = boff[b + 1];
  const int cnt = hi - lo;
  __shared__ int hist[256];
  __shared__ int cur[256];
  __shared__ int sorted[BCAP];
  const int t = threadIdx.x;
  hist[t] = 0;
  __syncthreads();
  for (int i = t; i < cnt; i += 256) {
    int2 ed = ebuck[lo + i];
    atomicAdd(&hist[ed.y & 255], 1);
  }
  __syncthreads();
  int v = hist[t];
  sorted[t] = v;
  __syncthreads();
#pragma unroll
  for (int off = 1; off < 256; off <<= 1) {
    int u = (t >= off) ? sorted[t - off] : 0;
    __syncthreads();
    sorted[t] += u;
    __syncthreads();
  }
  int excl = sorted[t] - v;
  cur[t] = excl;
  int node = b * 256 + t;
  if (node <= N) rowptr[node] = lo + excl;
  __syncthreads();
  for (int i = t; i < cnt; i += 256) {
    int2 ed = ebuck[lo + i];
    int slot = atomicAdd(&cur[ed.y & 255], 1);
    if (slot < BCAP) sorted[slot] = ed.x;
    else esrc[lo + slot] = ed.x;
  }
  __syncthreads();
  int lim = cnt < BCAP ? cnt : BCAP;
  for (int i = t; i < lim; i += 256) esrc[lo + i] = sorted[i];
}

// ================= fused online-softmax aggregation, fp8 K/V gathers =================
// conv1: 32 lanes per edge; lane ll holds K/V dims 4ll..4ll+3 via one 8B fp8 load.
__global__ void node_attn1(const int* __restrict__ rowptr, const int* __restrict__ esrc,
                           const unsigned short* __restrict__ Qb,
                           const unsigned char* __restrict__ KV8,
                           const unsigned short* __restrict__ SK, unsigned short* __restrict__ Hb,
                           int n) {
  int node = (blockIdx.x * blockDim.x + threadIdx.x) >> 6;
  int lane = threadIdx.x & 63;
  if (node >= n) return;
  const int half = lane >> 5, ll = lane & 31;
  const int r0 = rowptr[node], r1 = rowptr[node + 1];
  uint2 qq = *(const uint2*)(Qb + (size_t)node * 128 + ll * 4);
  const float q0 = bflo(qq.x), q1 = bfhi(qq.x), q2 = bflo(qq.y), q3 = bfhi(qq.y);
  float m = -INFINITY, l = 0.f, a0 = 0.f, a1 = 0.f, a2 = 0.f, a3 = 0.f;
  const float SCL = 0.17677669529663687f;  // 1/sqrt(32)
  int j = r0;
  for (; j + 4 <= r1; j += 4) {
    int eA = j + half * 2;
    int sA = esrc[eA], sB = esrc[eA + 1];
    uint2 ua = *(const uint2*)(KV8 + (size_t)sA * 256 + ll * 8);
    uint2 ub = *(const uint2*)(KV8 + (size_t)sB * 256 + ll * 8);
    f32x2 ka1 = fp8dec<false>(ua.x), va1 = fp8dec<true>(ua.x);
    f32x2 ka2 = fp8dec<false>(ua.y), va2 = fp8dec<true>(ua.y);
    f32x2 kb1 = fp8dec<false>(ub.x), vb1 = fp8dec<true>(ub.x);
    f32x2 kb2 = fp8dec<false>(ub.y), vb2 = fp8dec<true>(ub.y);
    float dA = q0 * ka1.x + q1 * ka1.y + q2 * ka2.x + q3 * ka2.y;
    float dB = q0 * kb1.x + q1 * kb1.y + q2 * kb2.x + q3 * kb2.y;
    dA += __shfl_xor(dA, 1); dB += __shfl_xor(dB, 1);
    dA += __shfl_xor(dA, 2); dB += __shfl_xor(dB, 2);
    dA += __shfl_xor(dA, 4); dB += __shfl_xor(dB, 4);
    float lgA = dA * SCL, lgB = dB * SCL;
    float mnew = fmaxf(m, fmaxf(lgA, lgB));
    float sc = __expf(m - mnew);
    float pA = __expf(lgA - mnew), pB = __expf(lgB - mnew);
    l = l * sc + pA + pB;
    a0 = a0 * sc + pA * va1.x + pB * vb1.x;
    a1 = a1 * sc + pA * va1.y + pB * vb1.y;
    a2 = a2 * sc + pA * va2.x + pB * vb2.x;
    a3 = a3 * sc + pA * va2.y + pB * vb2.y;
    m = mnew;
  }
  if (j < r1) {  // tail: 1..3 edges, masked
    int eA = j + half * 2, eB = eA + 1;
    bool vA = eA < r1, vB = eB < r1;
    int sA = esrc[vA ? eA : r0];
    int sB = esrc[vB ? eB : r0];
    uint2 ua = *(const uint2*)(KV8 + (size_t)sA * 256 + ll * 8);
    uint2 ub = *(const uint2*)(KV8 + (size_t)sB * 256 + ll * 8);
    f32x2 ka1 = fp8dec<false>(ua.x), va1 = fp8dec<true>(ua.x);
    f32x2 ka2 = fp8dec<false>(ua.y), va2 = fp8dec<true>(ua.y);
    f32x2 kb1 = fp8dec<false>(ub.x), vb1 = fp8dec<true>(ub.x);
    f32x2 kb2 = fp8dec<false>(ub.y), vb2 = fp8dec<true>(ub.y);
    float dA = q0 * ka1.x + q1 * ka1.y + q2 * ka2.x + q3 * ka2.y;
    float dB = q0 * kb1.x + q1 * kb1.y + q2 * kb2.x + q3 * kb2.y;
    dA += __shfl_xor(dA, 1); dB += __shfl_xor(dB, 1);
    dA += __shfl_xor(dA, 2); dB += __shfl_xor(dB, 2);
    dA += __shfl_xor(dA, 4); dB += __shfl_xor(dB, 4);
    float lgA = vA ? dA * SCL : -INFINITY;
    float lgB = vB ? dB * SCL : -INFINITY;
    float mnew = fmaxf(m, fmaxf(lgA, lgB));
    float sc = (mnew == -INFINITY) ? 0.f : __expf(m - mnew);
    float pA = vA ? __expf(lgA - mnew) : 0.f;
    float pB = vB ? __expf(lgB - mnew) : 0.f;
    l = l * sc + pA + pB;
    a0 = a0 * sc + pA * va1.x + pB * vb1.x;
    a1 = a1 * sc + pA * va1.y + pB * vb1.y;
    a2 = a2 * sc + pA * va2.x + pB * vb2.x;
    a3 = a3 * sc + pA * va2.y + pB * vb2.y;
    m = mnew;
  }
  // merge the two halves
  float mo = __shfl_xor(m, 32);
  float lo = __shfl_xor(l, 32);
  float b0 = __shfl_xor(a0, 32), b1 = __shfl_xor(a1, 32);
  float b2 = __shfl_xor(a2, 32), b3 = __shfl_xor(a3, 32);
  float mm = fmaxf(m, mo);
  float s1 = (m == -INFINITY) ? 0.f : __expf(m - mm);
  float s2 = (mo == -INFINITY) ? 0.f : __expf(mo - mm);
  l = l * s1 + lo * s2;
  a0 = a0 * s1 + b0 * s2;
  a1 = a1 * s1 + b1 * s2;
  a2 = a2 * s1 + b2 * s2;
  a3 = a3 * s1 + b3 * s2;
  float inv = (l > 0.f) ? 1.f / l : 0.f;
  if (half == 0) {
    uint2 sk = *(const uint2*)(SK + (size_t)node * 128 + ll * 4);
    float o0 = fmaxf(bflo(sk.x) + a0 * inv, 0.f);
    float o1 = fmaxf(bfhi(sk.x) + a1 * inv, 0.f);
    float o2 = fmaxf(bflo(sk.y) + a2 * inv, 0.f);
    float o3 = fmaxf(bfhi(sk.y) + a3 * inv, 0.f);
    uint2 hb;
    hb.x = ((unsigned)f2bf(o1) << 16) | (unsigned)f2bf(o0);
    hb.y = ((unsigned)f2bf(o3) << 16) | (unsigned)f2bf(o2);
    *(uint2*)(Hb + (size_t)node * 128 + ll * 4) = hb;
  }
}

// conv2: 16 lanes per edge; lane gl holds k/v dims 2gl,2gl+1 via one 4B fp8 load.
// C2 row 256 B: [Q 32 bf16 @0 | KV fp8 @64 | pad | H 32 bf16 @192].
__global__ void node_attn2(const int* __restrict__ rowptr, const int* __restrict__ esrc,
                           unsigned char* __restrict__ C2b, int n) {
  int node = (blockIdx.x * blockDim.x + threadIdx.x) >> 6;
  int lane = threadIdx.x & 63;
  if (node >= n) return;
  const int g = lane >> 4, gl = lane & 15;
  const int r0 = rowptr[node], r1 = rowptr[node + 1];
  unsigned qu = *(const unsigned*)(C2b + (size_t)node * 256 + gl * 4);
  const float q0 = bflo(qu), q1 = bfhi(qu);
  float m = -INFINITY, l = 0.f, a0 = 0.f, a1 = 0.f;
  const float SCL = 0.17677669529663687f;
  int j = r0;
  for (; j + 4 <= r1; j += 4) {
    int s = esrc[j + g];
    unsigned u = *(const unsigned*)(C2b + (size_t)s * 256 + 64 + gl * 4);
    f32x2 kd = fp8dec<false>(u), vd = fp8dec<true>(u);
    float d = q0 * kd.x + q1 * kd.y;
    d += __shfl_xor(d, 1);
    d += __shfl_xor(d, 2);
    d += __shfl_xor(d, 4);
    d += __shfl_xor(d, 8);
    float lg = d * SCL;
    float mnew = fmaxf(m, lg);
    float sc = __expf(m - mnew);
    float p = __expf(lg - mnew);
    l = l * sc + p;
    a0 = a0 * sc + p * vd.x;
    a1 = a1 * sc + p * vd.y;
    m = mnew;
  }
  if (j < r1) {  // tail: 1..3 edges, masked per group
    bool v = (j + g) < r1;
    int s = esrc[v ? j + g : r0];
    unsigned u = *(const unsigned*)(C2b + (size_t)s * 256 + 64 + gl * 4);
    f32x2 kd = fp8dec<false>(u), vd = fp8dec<true>(u);
    float d = q0 * kd.x + q1 * kd.y;
    d += __shfl_xor(d, 1);
    d += __shfl_xor(d, 2);
    d += __shfl_xor(d, 4);
    d += __shfl_xor(d, 8);
    float lg = v ? d * SCL : -INFINITY;
    float mnew = fmaxf(m, lg);
    float sc = (mnew == -INFINITY) ? 0.f : __expf(m - mnew);
    float p = v ? __expf(lg - mnew) : 0.f;
    l = l * sc + p;
    a0 = a0 * sc + p * vd.x;
    a1 = a1 * sc + p * vd.y;
    m = mnew;
  }
  // 2-level merge across the 4 groups
#pragma unroll
  for (int msk = 16; msk <= 32; msk <<= 1) {
    float mo = __shfl_xor(m, msk), lo = __shfl_xor(l, msk);
    float c0 = __shfl_xor(a0, msk), c1 = __shfl_xor(a1, msk);
    float mm = fmaxf(m, mo);
    float s1 = (m == -INFINITY) ? 0.f : __expf(m - mm);
    float s2 = (mo == -INFINITY) ? 0.f : __expf(mo - mm);
    l = l * s1 + lo * s2;
    a0 = a0 * s1 + c0 * s2;
    a1 = a1 * s1 + c1 * s2;
    m = mm;
  }
  float inv = (l > 0.f) ? 1.f / l : 0.f;
  if (lane < 16) {
    unsigned* h = (unsigned*)(C2b + (size_t)node * 256 + 192 + gl * 4);
    unsigned hu = *h;
    float o0 = bflo(hu) + a0 * inv;
    float o1 = bfhi(hu) + a1 * inv;
    *h = ((unsigned)f2bf(o1) << 16) | (unsigned)f2bf(o0);
  }
}

// ---------------- epilogue ----------------
__global__ void mean_reduce(const unsigned char* __restrict__ C2b, float* __restrict__ ACC, int n) {
  __shared__ float s[256];
  float acc = 0.f;
  int stride = gridDim.x * blockDim.x;
  int total = n * 32;
  for (int i = blockIdx.x * blockDim.x + threadIdx.x; i < total; i += stride) {
    int node = i >> 5, c = i & 31;
    unsigned short h = *(const unsigned short*)(C2b + (size_t)node * 256 + 192 + c * 2);
    acc += fmaxf(bf2f(h), 0.f);
  }
  s[threadIdx.x] = acc;
  __syncthreads();
  for (int off = 128; off >= 32; off >>= 1) {
    if (threadIdx.x < off) s[threadIdx.x] += s[threadIdx.x + off];
    __syncthreads();
  }
  if (threadIdx.x < 32) atomicAdd(&ACC[threadIdx.x], s[threadIdx.x]);
}

__global__ void final_out(const float* __restrict__ ACC, const float* __restrict__ Wo,
                          const float* __restrict__ bo, float* __restrict__ out, float invN) {
  int lane = threadIdx.x;
  float v = 0.f;
  if (lane < 32) v = ACC[lane] * invN * Wo[lane];
  v += __shfl_xor(v, 1);
  v += __shfl_xor(v, 2);
  v += __shfl_xor(v, 4);
  v += __shfl_xor(v, 8);
  v += __shfl_xor(v, 16);
  v += __shfl_xor(v, 32);
  if (lane == 0) out[0] = v + bo[0];
}

extern "C" void kernel_launch(void* const* d_in, const int* in_sizes, int n_in,
                              void* d_out, int out_size, void* d_ws, size_t ws_size,
                              hipStream_t stream) {
  const float* x   = (const float*)d_in[0];
  const int*   ei  = (const int*)d_in[1];  // [2, E]: row 0 = src, row 1 = dst
  const float* Wq1 = (const float*)d_in[2];  const float* bq1 = (const float*)d_in[3];
  const float* Wk1 = (const float*)d_in[4];  const float* bk1 = (const float*)d_in[5];
  const float* Wv1 = (const float*)d_in[6];  const float* bv1 = (const float*)d_in[7];
  const float* Ws1 = (const float*)d_in[8];  const float* bs1 = (const float*)d_in[9];
  const float* Wq2 = (const float*)d_in[10]; const float* bq2 = (const float*)d_in[11];
  const float* Wk2 = (const float*)d_in[12]; const float* bk2 = (const float*)d_in[13];
  const float* Wv2 = (const float*)d_in[14]; const float* bv2 = (const float*)d_in[15];
  const float* Ws2 = (const float*)d_in[16]; const float* bs2 = (const float*)d_in[17];
  const float* Wo  = (const float*)d_in[18]; const float* bo  = (const float*)d_in[19];

  char* ws = (char*)d_ws;
  const int N = N_NODES, E = N_EDGES;
  const int GB = (N + 63) / 64;
  const int EB = (E + 4095) / 4096;

  // buffers
  unsigned short* xb  = (unsigned short*)(ws + 0);          // N*128 bf16
  unsigned short* Q1b = (unsigned short*)(ws + 12800000);   // N*128 bf16
  unsigned short* SK1 = (unsigned short*)(ws + 25600000);   // N*128 bf16
  unsigned char*  KV1 = (unsigned char*)(ws + 38400000);    // N*256 fp8 (12.8 MB)
  unsigned short* H1b = (unsigned short*)(ws + 64000000);   // N*128 bf16
  unsigned char*  C2  = (unsigned char*)(ws + 76800000);    // N*256 bytes [Q|KV8|pad|H]
  // CSR + weights + misc
  int* rowptr = (int*)(ws + 102400000);                     // N+1
  int* esrc   = (int*)(ws + 102700032);                     // E
  int* bhist  = (int*)(ws + 105900032);                     // NBK
  int* boff   = (int*)(ws + 105901056);                     // NBK+1
  int* bcur   = (int*)(ws + 105902080);                     // NBK
  unsigned short* Wt1   = (unsigned short*)(ws + 105903104);  // 512x128 bf16
  unsigned short* Wt2   = (unsigned short*)(ws + 106034176);  // 128x128 bf16
  float*          bcat1 = (float*)(ws + 106066944);
  float*          bcat2 = (float*)(ws + 106068992);
  float*          ACC   = (float*)(ws + 106069504);
  int2*           ebuck = (int2*)(ws + 106070016);          // E * 8B

  float* out = (float*)d_out;

  dim3 blk(256);

  // ---- fused prep (also zeroes bhist/ACC; must precede CSR build) ----
  prep_fused<<<dim3(CAST_B + C1_B + C2_B + 1), blk, 0, stream>>>(
      x, Wq1, Wk1, Wv1, Ws1, bq1, bk1, bv1, bs1,
      Wq2, Wk2, Wv2, Ws2, bq2, bk2, bv2, bs2,
      xb, Wt1, bcat1, Wt2, bcat2, bhist, ACC);

  // ---- CSR build (two-level bucket sort) ----
  bucket_hist<<<dim3(EB), blk, 0, stream>>>(ei, bhist, E);
  bucket_scan<<<dim3(1), blk, 0, stream>>>(bhist, boff, bcur);
  bucket_scatter<<<dim3(EB), blk, 0, stream>>>(ei, bcur, ebuck, E);
  bucket_csr<<<dim3(NBK), blk, 0, stream>>>(ebuck, boff, rowptr, esrc, N);

  // ---- conv1 GEMMs (one 3-way launch; KV emitted fp8) ----
  gemm_conv1<<<dim3(GB, 3), blk, 0, stream>>>(xb, Wt1, bcat1, Q1b, SK1, KV1, N);

  // ---- conv1 fused attention + skip + relu -> bf16 ----
  node_attn1<<<dim3((N * 64 + 255) / 256), blk, 0, stream>>>(rowptr, esrc, Q1b, KV1, SK1, H1b, N);

  // ---- conv2 GEMM (fused Q|KV8|H rows) ----
  gemm2<<<dim3(GB), blk, 0, stream>>>(H1b, Wt2, bcat2, C2, N);

  // ---- conv2 fused attention ----
  node_attn2<<<dim3((N * 64 + 255) / 256), blk, 0, stream>>>(rowptr, esrc, C2, N);

  // ---- relu + mean + final linear ----
  mean_reduce<<<dim3(1024), blk, 0, stream>>>(C2, ACC, N);
  final_out<<<dim3(1), dim3(64), 0, stream>>>(ACC, Wo, bo, out, 1.0f / (float)N);
}

// Round 12
// 284.321 us; speedup vs baseline: 1.3573x; 1.0644x over previous
//
#include <hip/hip_runtime.h>
#include <math.h>

#define N_NODES 50000
#define N_EDGES 800000
#define NBK 196          // dst buckets of 256 nodes: bucket = dst >> 8
#define BCAP 6144        // max edges per bucket handled in LDS (mean 4082, sigma 64)

typedef short short8 __attribute__((ext_vector_type(8)));
typedef float f32x4 __attribute__((ext_vector_type(4)));
typedef float f32x2 __attribute__((ext_vector_type(2)));

// ---------------- bf16 / fp8 helpers ----------------
__device__ inline unsigned short f2bf(float v) {
  unsigned u = __float_as_uint(v);
  u += 0x7FFFu + ((u >> 16) & 1u);  // round-to-nearest-even
  return (unsigned short)(u >> 16);
}
__device__ inline float bf2f(unsigned short b) {
  return __uint_as_float(((unsigned)b) << 16);
}
__device__ inline float bflo(unsigned u) { return __uint_as_float(u << 16); }
__device__ inline float bfhi(unsigned u) { return __uint_as_float(u & 0xFFFF0000u); }
// fp8 e4m3 (OCP on gfx950): HW packed converts; selector is an immediate.
__device__ inline unsigned char f2fp8(float v) {
  return (unsigned char)(__builtin_amdgcn_cvt_pk_fp8_f32(v, 0.f, 0, false) & 0xFF);
}
template <bool HI>
__device__ inline f32x2 fp8dec(unsigned u) {
  return __builtin_amdgcn_cvt_pk_f32_fp8(u, HI);
}

#define SCL 0.17677669529663687f   // 1/sqrt(32), folded into Wq/bq at prep

// ---------------- fused prep: cast x->bf16, concat both weight sets, zero bhist/ACC ----------------
#define CAST_B 6250   // N*128/4 / 256
#define C1_B 256      // 512*128 / 256
#define C2_B 64       // 128*128 / 256
__global__ void prep_fused(const float* __restrict__ x,
                           const float* __restrict__ Wq1, const float* __restrict__ Wk1,
                           const float* __restrict__ Wv1, const float* __restrict__ Ws1,
                           const float* __restrict__ bq1, const float* __restrict__ bk1,
                           const float* __restrict__ bv1, const float* __restrict__ bs1,
                           const float* __restrict__ Wq2, const float* __restrict__ Wk2,
                           const float* __restrict__ Wv2, const float* __restrict__ Ws2,
                           const float* __restrict__ bq2, const float* __restrict__ bk2,
                           const float* __restrict__ bv2, const float* __restrict__ bs2,
                           unsigned short* __restrict__ xb, unsigned short* __restrict__ Wt1,
                           float* __restrict__ bcat1, unsigned short* __restrict__ Wt2,
                           float* __restrict__ bcat2, int* __restrict__ bhist,
                           float* __restrict__ ACC) {
  const int b = blockIdx.x, tid = threadIdx.x;
  if (b < CAST_B) {
    int i = b * 256 + tid;  // float4 index
    float4 v = ((const float4*)x)[i];
    ushort4 o;
    o.x = f2bf(v.x); o.y = f2bf(v.y); o.z = f2bf(v.z); o.w = f2bf(v.w);
    ((ushort4*)xb)[i] = o;
  } else if (b < CAST_B + C1_B) {
    int i = (b - CAST_B) * 256 + tid;   // over 512*128
    int c = i >> 7, k = i & 127;
    int mi = c >> 7, lc = c & 127;
    const float* W = (mi == 0) ? Wq1 : (mi == 1) ? Wk1 : (mi == 2) ? Wv1 : Ws1;
    float scl = (mi == 0) ? SCL : 1.f;   // fold 1/sqrt(32) into Q
    Wt1[i] = f2bf(W[(size_t)k * 128 + lc] * scl);
    if (i < 512) {
      int bm = i >> 7, bl = i & 127;
      const float* bb = (bm == 0) ? bq1 : (bm == 1) ? bk1 : (bm == 2) ? bv1 : bs1;
      bcat1[i] = bb[bl] * ((bm == 0) ? SCL : 1.f);
    }
  } else if (b < CAST_B + C1_B + C2_B) {
    int i = (b - CAST_B - C1_B) * 256 + tid;  // over 128*128
    int c = i >> 7, k = i & 127;
    int mi = c >> 5, lc = c & 31;
    const float* W = (mi == 0) ? Wq2 : (mi == 1) ? Wk2 : (mi == 2) ? Wv2 : Ws2;
    float scl = (mi == 0) ? SCL : 1.f;
    Wt2[i] = f2bf(W[(size_t)k * 32 + lc] * scl);
    if (i < 128) {
      int bm = i >> 5, bl = i & 31;
      const float* bb = (bm == 0) ? bq2 : (bm == 1) ? bk2 : (bm == 2) ? bv2 : bs2;
      bcat2[i] = bb[bl] * ((bm == 0) ? SCL : 1.f);
    }
  } else {
    if (tid < NBK) bhist[tid] = 0;
    else if (tid >= 224 && tid < 256) ACC[tid - 224] = 0.f;
  }
}

// ================= conv1 GEMM, unified 3-way: y=0 Q(bf16), y=1 SK(bf16), y=2 KV(fp8) =================
__global__ __launch_bounds__(256) void gemm_conv1(
    const unsigned short* __restrict__ Ab, const unsigned short* __restrict__ Wt,
    const float* __restrict__ bcat, unsigned short* __restrict__ Q1b,
    unsigned short* __restrict__ SK1, unsigned char* __restrict__ KV8, int M) {
  __shared__ __align__(16) unsigned char Lsb[64 * 272];
  unsigned short* Ls16 = (unsigned short*)Lsb;   // stride 136 shorts (= 272 B)
  const int bm = blockIdx.x * 64;
  const int tid = threadIdx.x, wave = tid >> 6, lane = tid & 63;
  const int lr = lane & 15, q = lane >> 4;

  if (blockIdx.y < 2) {  // ---- 128-col bf16 identity path (Q or SK) ----
    const int coloff = blockIdx.y ? 384 : 0;
    unsigned short* out = blockIdx.y ? SK1 : Q1b;
    f32x4 acc[4][2];
#pragma unroll
    for (int i = 0; i < 4; ++i)
#pragma unroll
      for (int j = 0; j < 2; ++j) acc[i][j] = (f32x4){0.f, 0.f, 0.f, 0.f};
#pragma unroll
    for (int ks = 0; ks < 4; ++ks) {
      short8 af[4], bf[2];
#pragma unroll
      for (int i = 0; i < 4; ++i) {
        int gm = bm + i * 16 + lr; if (gm >= M) gm = 0;
        af[i] = *(const short8*)(Ab + (size_t)gm * 128 + ks * 32 + q * 8);
      }
#pragma unroll
      for (int j = 0; j < 2; ++j)
        bf[j] = *(const short8*)(Wt + (size_t)(coloff + wave * 32 + j * 16 + lr) * 128 + ks * 32 + q * 8);
#pragma unroll
      for (int i = 0; i < 4; ++i)
#pragma unroll
        for (int j = 0; j < 2; ++j)
          acc[i][j] = __builtin_amdgcn_mfma_f32_16x16x32_bf16(af[i], bf[j], acc[i][j], 0, 0, 0);
    }
    float bj[2];
#pragma unroll
    for (int j = 0; j < 2; ++j) bj[j] = bcat[coloff + wave * 32 + j * 16 + lr];
#pragma unroll
    for (int i = 0; i < 4; ++i)
#pragma unroll
      for (int r = 0; r < 4; ++r) {
        int row = i * 16 + q * 4 + r;
#pragma unroll
        for (int j = 0; j < 2; ++j) {
          int c = wave * 32 + j * 16 + lr;
          Ls16[row * 136 + c] = f2bf(acc[i][j][r] + bj[j]);
        }
      }
    __syncthreads();
#pragma unroll
    for (int p = 0; p < 8; ++p) {
      int idx = tid + p * 256;
      int row = idx >> 5, u = idx & 31;
      int gr = bm + row;
      if (gr < M) *(uint2*)(out + (size_t)gr * 128 + u * 4) = *(const uint2*)&Ls16[row * 136 + u * 4];
    }
  } else {  // ---- 256-col KV fp8 interleave path ----
    f32x4 acc[4][4];
#pragma unroll
    for (int i = 0; i < 4; ++i)
#pragma unroll
      for (int j = 0; j < 4; ++j) acc[i][j] = (f32x4){0.f, 0.f, 0.f, 0.f};
#pragma unroll
    for (int ks = 0; ks < 4; ++ks) {
      short8 af[4], bf[4];
#pragma unroll
      for (int i = 0; i < 4; ++i) {
        int gm = bm + i * 16 + lr; if (gm >= M) gm = 0;
        af[i] = *(const short8*)(Ab + (size_t)gm * 128 + ks * 32 + q * 8);
      }
#pragma unroll
      for (int j = 0; j < 4; ++j)
        bf[j] = *(const short8*)(Wt + (size_t)(128 + wave * 64 + j * 16 + lr) * 128 + ks * 32 + q * 8);
#pragma unroll
      for (int i = 0; i < 4; ++i)
#pragma unroll
        for (int j = 0; j < 4; ++j)
          acc[i][j] = __builtin_amdgcn_mfma_f32_16x16x32_bf16(af[i], bf[j], acc[i][j], 0, 0, 0);
    }
    float bj[4];
#pragma unroll
    for (int j = 0; j < 4; ++j) bj[j] = bcat[128 + wave * 64 + j * 16 + lr];
#pragma unroll
    for (int i = 0; i < 4; ++i)
#pragma unroll
      for (int r = 0; r < 4; ++r) {
        int row = i * 16 + q * 4 + r;
#pragma unroll
        for (int j = 0; j < 4; ++j) {
          int c = wave * 64 + j * 16 + lr;  // 0..255 over K|V
          int bslot = (c < 128) ? (4 * (c >> 1) + (c & 1))
                                : (4 * ((c - 128) >> 1) + 2 + ((c - 128) & 1));
          Lsb[row * 272 + bslot] = f2fp8(acc[i][j][r] + bj[j]);
        }
      }
    __syncthreads();
#pragma unroll
    for (int p = 0; p < 16; ++p) {
      int idx = tid + p * 256;
      int row = idx >> 6, u = idx & 63;
      int gr = bm + row;
      if (gr < M) *(unsigned*)(KV8 + (size_t)gr * 256 + u * 4) = *(const unsigned*)&Lsb[row * 272 + u * 4];
    }
  }
}

// ---- gemm2: 128 cols of Wt2 -> C2 rows (256 B): [Q 32 bf16 | KV fp8 64 B | pad | H 32 bf16] ----
__global__ __launch_bounds__(256) void gemm2(
    const unsigned short* __restrict__ Ab, const unsigned short* __restrict__ Wt,
    const float* __restrict__ bcat, unsigned char* __restrict__ C2b, int M) {
  __shared__ __align__(16) unsigned char Lsb[64 * 272];
  const int bm = blockIdx.x * 64;
  const int tid = threadIdx.x, wave = tid >> 6, lane = tid & 63;
  const int lr = lane & 15, q = lane >> 4;

  f32x4 acc[4][2];
#pragma unroll
  for (int i = 0; i < 4; ++i)
#pragma unroll
    for (int j = 0; j < 2; ++j) acc[i][j] = (f32x4){0.f, 0.f, 0.f, 0.f};

#pragma unroll
  for (int ks = 0; ks < 4; ++ks) {
    short8 af[4], bf[2];
#pragma unroll
    for (int i = 0; i < 4; ++i) {
      int gm = bm + i * 16 + lr; if (gm >= M) gm = 0;
      af[i] = *(const short8*)(Ab + (size_t)gm * 128 + ks * 32 + q * 8);
    }
#pragma unroll
    for (int j = 0; j < 2; ++j)
      bf[j] = *(const short8*)(Wt + (size_t)(wave * 32 + j * 16 + lr) * 128 + ks * 32 + q * 8);
#pragma unroll
    for (int i = 0; i < 4; ++i)
#pragma unroll
      for (int j = 0; j < 2; ++j)
        acc[i][j] = __builtin_amdgcn_mfma_f32_16x16x32_bf16(af[i], bf[j], acc[i][j], 0, 0, 0);
  }

  float bj[2];
#pragma unroll
  for (int j = 0; j < 2; ++j) bj[j] = bcat[wave * 32 + j * 16 + lr];
#pragma unroll
  for (int i = 0; i < 4; ++i)
#pragma unroll
    for (int r = 0; r < 4; ++r) {
      int row = i * 16 + q * 4 + r;
#pragma unroll
      for (int j = 0; j < 2; ++j) {
        int c = wave * 32 + j * 16 + lr;
        float val = acc[i][j][r] + bj[j];
        if (c < 32) {
          *(unsigned short*)&Lsb[row * 272 + 2 * c] = f2bf(val);
        } else if (c < 64) {
          int d = c - 32;
          Lsb[row * 272 + 64 + 4 * (d >> 1) + (d & 1)] = f2fp8(val);
        } else if (c < 96) {
          int d = c - 64;
          Lsb[row * 272 + 64 + 4 * (d >> 1) + 2 + (d & 1)] = f2fp8(val);
        } else {
          *(unsigned short*)&Lsb[row * 272 + 192 + 2 * (c - 96)] = f2bf(val);
        }
      }
    }
  __syncthreads();
#pragma unroll
  for (int p = 0; p < 16; ++p) {
    int idx = tid + p * 256;
    int row = idx >> 6, u = idx & 63;
    int gr = bm + row;
    if (gr < M) *(unsigned*)(C2b + (size_t)gr * 256 + u * 4) = *(const unsigned*)&Lsb[row * 272 + u * 4];
  }
}

// ================= CSR build via two-level bucket sort =================
__global__ void bucket_hist(const int* __restrict__ ei, int* __restrict__ bhist, int E) {
  __shared__ int h[NBK];
  for (int i = threadIdx.x; i < NBK; i += 256) h[i] = 0;
  __syncthreads();
  int e = blockIdx.x * 4096 + threadIdx.x;
#pragma unroll
  for (int p = 0; p < 16; ++p, e += 256)
    if (e < E) atomicAdd(&h[ei[E + e] >> 8], 1);
  __syncthreads();
  for (int i = threadIdx.x; i < NBK; i += 256)
    if (h[i]) atomicAdd(&bhist[i], h[i]);
}

__global__ void bucket_scan(const int* __restrict__ bhist, int* __restrict__ boff,
                            int* __restrict__ bcur) {
  __shared__ int s[256];
  int t = threadIdx.x;
  int v = (t < NBK) ? bhist[t] : 0;
  s[t] = v;
  __syncthreads();
#pragma unroll
  for (int off = 1; off < 256; off <<= 1) {
    int u = (t >= off) ? s[t - off] : 0;
    __syncthreads();
    s[t] += u;
    __syncthreads();
  }
  if (t < NBK) {
    int excl = s[t] - v;
    boff[t] = excl;
    bcur[t] = excl;
  }
  if (t == NBK - 1) boff[NBK] = s[t];
}

__global__ void bucket_scatter(const int* __restrict__ ei, int* __restrict__ bcur,
                               int2* __restrict__ ebuck, int E) {
  __shared__ int lh[NBK];
  for (int i = threadIdx.x; i < NBK; i += 256) lh[i] = 0;
  __syncthreads();
  const int e0 = blockIdx.x * 4096;
  int srcs[16], dsts[16];
#pragma unroll
  for (int p = 0; p < 16; ++p) {
    int e = e0 + p * 256 + threadIdx.x;
    if (e < E) {
      srcs[p] = ei[e];
      dsts[p] = ei[E + e];
      atomicAdd(&lh[dsts[p] >> 8], 1);
    } else dsts[p] = -1;
  }
  __syncthreads();
  for (int i = threadIdx.x; i < NBK; i += 256)
    if (lh[i]) lh[i] = atomicAdd(&bcur[i], lh[i]);
  __syncthreads();
#pragma unroll
  for (int p = 0; p < 16; ++p) {
    if (dsts[p] >= 0) {
      int slot = atomicAdd(&lh[dsts[p] >> 8], 1);
      ebuck[slot] = make_int2(srcs[p], dsts[p]);
    }
  }
}

// esrc entries are stored pre-shifted (src<<8 = byte offset into the 256B/node tables)
__global__ void bucket_csr(const int2* __restrict__ ebuck, const int* __restrict__ boff,
                           int* __restrict__ rowptr, int* __restrict__ esrc, int N) {
  const int b = blockIdx.x;
  const int lo = boff[b], hi = boff[b + 1];
  const int cnt = hi - lo;
  __shared__ int hist[256];
  __shared__ int cur[256];
  __shared__ int sorted[BCAP];
  const int t = threadIdx.x;
  hist[t] = 0;
  __syncthreads();
  for (int i = t; i < cnt; i += 256) {
    int2 ed = ebuck[lo + i];
    atomicAdd(&hist[ed.y & 255], 1);
  }
  __syncthreads();
  int v = hist[t];
  sorted[t] = v;
  __syncthreads();
#pragma unroll
  for (int off = 1; off < 256; off <<= 1) {
    int u = (t >= off) ? sorted[t - off] : 0;
    __syncthreads();
    sorted[t] += u;
    __syncthreads();
  }
  int excl = sorted[t] - v;
  cur[t] = excl;
  int node = b * 256 + t;
  if (node <= N) rowptr[node] = lo + excl;
  __syncthreads();
  for (int i = t; i < cnt; i += 256) {
    int2 ed = ebuck[lo + i];
    int slot = atomicAdd(&cur[ed.y & 255], 1);
    if (slot < BCAP) sorted[slot] = ed.x;
    else esrc[lo + slot] = ed.x << 8;  // overflow fallback
  }
  __syncthreads();
  int lim = cnt < BCAP ? cnt : BCAP;
  for (int i = t; i < lim; i += 256) esrc[lo + i] = sorted[i] << 8;
}

// ================= fused aggregation: plain-exp softmax (no online max), fp8 K/V =================
// Safe: logits = q·k/sqrt(32) with q,k ~ O(1) -> |lg| << 88 (fp32 exp overflow).
// conv1: 32 lanes per edge; halves process disjoint edges; x8 main loop (4 edges/half).
__global__ void node_attn1(const int* __restrict__ rowptr, const int* __restrict__ esrc,
                           const unsigned short* __restrict__ Qb,
                           const unsigned char* __restrict__ KV8,
                           const unsigned short* __restrict__ SK, unsigned short* __restrict__ Hb,
                           int n) {
  int node = (blockIdx.x * blockDim.x + threadIdx.x) >> 6;
  int lane = threadIdx.x & 63;
  if (node >= n) return;
  const int half = lane >> 5, ll = lane & 31;
  const int r0 = rowptr[node], r1 = rowptr[node + 1];
  uint2 qq = *(const uint2*)(Qb + (size_t)node * 128 + ll * 4);
  const float q0 = bflo(qq.x), q1 = bfhi(qq.x), q2 = bflo(qq.y), q3 = bfhi(qq.y);
  float l = 0.f, a0 = 0.f, a1 = 0.f, a2 = 0.f, a3 = 0.f;
  const unsigned char* kvb = KV8 + ll * 8;   // lane-invariant part folded once
  int j = r0;
  for (; j + 8 <= r1; j += 8) {
    int e = j + half * 4;
    int s0 = esrc[e], s1 = esrc[e + 1], s2 = esrc[e + 2], s3 = esrc[e + 3];
    uint2 u0 = *(const uint2*)(kvb + s0);
    uint2 u1 = *(const uint2*)(kvb + s1);
    uint2 u2 = *(const uint2*)(kvb + s2);
    uint2 u3 = *(const uint2*)(kvb + s3);
    f32x2 k0a = fp8dec<false>(u0.x), k0b = fp8dec<false>(u0.y);
    f32x2 k1a = fp8dec<false>(u1.x), k1b = fp8dec<false>(u1.y);
    f32x2 k2a = fp8dec<false>(u2.x), k2b = fp8dec<false>(u2.y);
    f32x2 k3a = fp8dec<false>(u3.x), k3b = fp8dec<false>(u3.y);
    float d0 = q0 * k0a.x + q1 * k0a.y + q2 * k0b.x + q3 * k0b.y;
    float d1 = q0 * k1a.x + q1 * k1a.y + q2 * k1b.x + q3 * k1b.y;
    float d2 = q0 * k2a.x + q1 * k2a.y + q2 * k2b.x + q3 * k2b.y;
    float d3 = q0 * k3a.x + q1 * k3a.y + q2 * k3b.x + q3 * k3b.y;
#pragma unroll
    for (int msk = 1; msk <= 4; msk <<= 1) {
      d0 += __shfl_xor(d0, msk);
      d1 += __shfl_xor(d1, msk);
      d2 += __shfl_xor(d2, msk);
      d3 += __shfl_xor(d3, msk);
    }
    float p0 = __expf(d0), p1 = __expf(d1), p2 = __expf(d2), p3 = __expf(d3);
    l += (p0 + p1) + (p2 + p3);
    f32x2 v0a = fp8dec<true>(u0.x), v0b = fp8dec<true>(u0.y);
    f32x2 v1a = fp8dec<true>(u1.x), v1b = fp8dec<true>(u1.y);
    f32x2 v2a = fp8dec<true>(u2.x), v2b = fp8dec<true>(u2.y);
    f32x2 v3a = fp8dec<true>(u3.x), v3b = fp8dec<true>(u3.y);
    a0 += p0 * v0a.x + p1 * v1a.x + p2 * v2a.x + p3 * v3a.x;
    a1 += p0 * v0a.y + p1 * v1a.y + p2 * v2a.y + p3 * v3a.y;
    a2 += p0 * v0b.x + p1 * v1b.x + p2 * v2b.x + p3 * v3b.x;
    a3 += p0 * v0b.y + p1 * v1b.y + p2 * v2b.y + p3 * v3b.y;
  }
  for (; j < r1; j += 4) {  // masked tail, 2 edges/half per pass
    int eA = j + half * 2, eB = eA + 1;
    bool vA = eA < r1, vB = eB < r1;
    int sA = esrc[vA ? eA : r0];
    int sB = esrc[vB ? eB : r0];
    uint2 ua = *(const uint2*)(kvb + sA);
    uint2 ub = *(const uint2*)(kvb + sB);
    f32x2 ka1 = fp8dec<false>(ua.x), ka2 = fp8dec<false>(ua.y);
    f32x2 kb1 = fp8dec<false>(ub.x), kb2 = fp8dec<false>(ub.y);
    float dA = q0 * ka1.x + q1 * ka1.y + q2 * ka2.x + q3 * ka2.y;
    float dB = q0 * kb1.x + q1 * kb1.y + q2 * kb2.x + q3 * kb2.y;
#pragma unroll
    for (int msk = 1; msk <= 4; msk <<= 1) {
      dA += __shfl_xor(dA, msk);
      dB += __shfl_xor(dB, msk);
    }
    float pA = vA ? __expf(dA) : 0.f;
    float pB = vB ? __expf(dB) : 0.f;
    l += pA + pB;
    f32x2 va1 = fp8dec<true>(ua.x), va2 = fp8dec<true>(ua.y);
    f32x2 vb1 = fp8dec<true>(ub.x), vb2 = fp8dec<true>(ub.y);
    a0 += pA * va1.x + pB * vb1.x;
    a1 += pA * va1.y + pB * vb1.y;
    a2 += pA * va2.x + pB * vb2.x;
    a3 += pA * va2.y + pB * vb2.y;
  }
  // merge halves (pure sums)
  l  += __shfl_xor(l, 32);
  a0 += __shfl_xor(a0, 32);
  a1 += __shfl_xor(a1, 32);
  a2 += __shfl_xor(a2, 32);
  a3 += __shfl_xor(a3, 32);
  float inv = (l > 0.f) ? 1.f / l : 0.f;
  if (half == 0) {
    uint2 sk = *(const uint2*)(SK + (size_t)node * 128 + ll * 4);
    float o0 = fmaxf(bflo(sk.x) + a0 * inv, 0.f);
    float o1 = fmaxf(bfhi(sk.x) + a1 * inv, 0.f);
    float o2 = fmaxf(bflo(sk.y) + a2 * inv, 0.f);
    float o3 = fmaxf(bfhi(sk.y) + a3 * inv, 0.f);
    uint2 hb;
    hb.x = ((unsigned)f2bf(o1) << 16) | (unsigned)f2bf(o0);
    hb.y = ((unsigned)f2bf(o3) << 16) | (unsigned)f2bf(o2);
    *(uint2*)(Hb + (size_t)node * 128 + ll * 4) = hb;
  }
}

// conv2: 16 lanes per edge (4 groups); x8 main loop (2 edges/group); plain exp.
__global__ void node_attn2(const int* __restrict__ rowptr, const int* __restrict__ esrc,
                           unsigned char* __restrict__ C2b, int n) {
  int node = (blockIdx.x * blockDim.x + threadIdx.x) >> 6;
  int lane = threadIdx.x & 63;
  if (node >= n) return;
  const int g = lane >> 4, gl = lane & 15;
  const int r0 = rowptr[node], r1 = rowptr[node + 1];
  unsigned qu = *(const unsigned*)(C2b + (size_t)node * 256 + gl * 4);
  const float q0 = bflo(qu), q1 = bfhi(qu);
  float l = 0.f, a0 = 0.f, a1 = 0.f;
  const unsigned char* kvb = C2b + 64 + gl * 4;
  int j = r0;
  for (; j + 8 <= r1; j += 8) {
    int e = j + g * 2;
    int s0 = esrc[e], s1 = esrc[e + 1];
    unsigned u0 = *(const unsigned*)(kvb + s0);
    unsigned u1 = *(const unsigned*)(kvb + s1);
    f32x2 k0 = fp8dec<false>(u0), k1 = fp8dec<false>(u1);
    float d0 = q0 * k0.x + q1 * k0.y;
    float d1 = q0 * k1.x + q1 * k1.y;
#pragma unroll
    for (int msk = 1; msk <= 8; msk <<= 1) {
      d0 += __shfl_xor(d0, msk);
      d1 += __shfl_xor(d1, msk);
    }
    float p0 = __expf(d0), p1 = __expf(d1);
    l += p0 + p1;
    f32x2 v0 = fp8dec<true>(u0), v1 = fp8dec<true>(u1);
    a0 += p0 * v0.x + p1 * v1.x;
    a1 += p0 * v0.y + p1 * v1.y;
  }
  for (; j < r1; j += 4) {  // masked tail, 1 edge/group per pass
    bool v = (j + g) < r1;
    int s = esrc[v ? j + g : r0];
    unsigned u = *(const unsigned*)(kvb + s);
    f32x2 kd = fp8dec<false>(u);
    float d = q0 * kd.x + q1 * kd.y;
#pragma unroll
    for (int msk = 1; msk <= 8; msk <<= 1) d += __shfl_xor(d, msk);
    float p = v ? __expf(d) : 0.f;
    l += p;
    f32x2 vd = fp8dec<true>(u);
    a0 += p * vd.x;
    a1 += p * vd.y;
  }
  // merge across 4 groups (pure sums)
#pragma unroll
  for (int msk = 16; msk <= 32; msk <<= 1) {
    l  += __shfl_xor(l, msk);
    a0 += __shfl_xor(a0, msk);
    a1 += __shfl_xor(a1, msk);
  }
  float inv = (l > 0.f) ? 1.f / l : 0.f;
  if (lane < 16) {
    unsigned* h = (unsigned*)(C2b + (size_t)node * 256 + 192 + gl * 4);
    unsigned hu = *h;
    float o0 = bflo(hu) + a0 * inv;
    float o1 = bfhi(hu) + a1 * inv;
    *h = ((unsigned)f2bf(o1) << 16) | (unsigned)f2bf(o0);
  }
}

// ---------------- epilogue ----------------
__global__ void mean_reduce(const unsigned char* __restrict__ C2b, float* __restrict__ ACC, int n) {
  __shared__ float s[256];
  float acc = 0.f;
  int stride = gridDim.x * blockDim.x;
  int total = n * 32;
  for (int i = blockIdx.x * blockDim.x + threadIdx.x; i < total; i += stride) {
    int node = i >> 5, c = i & 31;
    unsigned short h = *(const unsigned short*)(C2b + (size_t)node * 256 + 192 + c * 2);
    acc += fmaxf(bf2f(h), 0.f);
  }
  s[threadIdx.x] = acc;
  __syncthreads();
  for (int off = 128; off >= 32; off >>= 1) {
    if (threadIdx.x < off) s[threadIdx.x] += s[threadIdx.x + off];
    __syncthreads();
  }
  if (threadIdx.x < 32) atomicAdd(&ACC[threadIdx.x], s[threadIdx.x]);
}

__global__ void final_out(const float* __restrict__ ACC, const float* __restrict__ Wo,
                          const float* __restrict__ bo, float* __restrict__ out, float invN) {
  int lane = threadIdx.x;
  float v = 0.f;
  if (lane < 32) v = ACC[lane] * invN * Wo[lane];
  v += __shfl_xor(v, 1);
  v += __shfl_xor(v, 2);
  v += __shfl_xor(v, 4);
  v += __shfl_xor(v, 8);
  v += __shfl_xor(v, 16);
  v += __shfl_xor(v, 32);
  if (lane == 0) out[0] = v + bo[0];
}

extern "C" void kernel_launch(void* const* d_in, const int* in_sizes, int n_in,
                              void* d_out, int out_size, void* d_ws, size_t ws_size,
                              hipStream_t stream) {
  const float* x   = (const float*)d_in[0];
  const int*   ei  = (const int*)d_in[1];  // [2, E]: row 0 = src, row 1 = dst
  const float* Wq1 = (const float*)d_in[2];  const float* bq1 = (const float*)d_in[3];
  const float* Wk1 = (const float*)d_in[4];  const float* bk1 = (const float*)d_in[5];
  const float* Wv1 = (const float*)d_in[6];  const float* bv1 = (const float*)d_in[7];
  const float* Ws1 = (const float*)d_in[8];  const float* bs1 = (const float*)d_in[9];
  const float* Wq2 = (const float*)d_in[10]; const float* bq2 = (const float*)d_in[11];
  const float* Wk2 = (const float*)d_in[12]; const float* bk2 = (const float*)d_in[13];
  const float* Wv2 = (const float*)d_in[14]; const float* bv2 = (const float*)d_in[15];
  const float* Ws2 = (const float*)d_in[16]; const float* bs2 = (const float*)d_in[17];
  const float* Wo  = (const float*)d_in[18]; const float* bo  = (const float*)d_in[19];

  char* ws = (char*)d_ws;
  const int N = N_NODES, E = N_EDGES;
  const int GB = (N + 63) / 64;
  const int EB = (E + 4095) / 4096;

  // buffers
  unsigned short* xb  = (unsigned short*)(ws + 0);          // N*128 bf16
  unsigned short* Q1b = (unsigned short*)(ws + 12800000);   // N*128 bf16 (pre-scaled by 1/sqrt32)
  unsigned short* SK1 = (unsigned short*)(ws + 25600000);   // N*128 bf16
  unsigned char*  KV1 = (unsigned char*)(ws + 38400000);    // N*256 fp8
  unsigned short* H1b = (unsigned short*)(ws + 64000000);   // N*128 bf16
  unsigned char*  C2  = (unsigned char*)(ws + 76800000);    // N*256 bytes [Q|KV8|pad|H]
  // CSR + weights + misc
  int* rowptr = (int*)(ws + 102400000);                     // N+1
  int* esrc   = (int*)(ws + 102700032);                     // E (byte offsets, src<<8)
  int* bhist  = (int*)(ws + 105900032);                     // NBK
  int* boff   = (int*)(ws + 105901056);                     // NBK+1
  int* bcur   = (int*)(ws + 105902080);                     // NBK
  unsigned short* Wt1   = (unsigned short*)(ws + 105903104);  // 512x128 bf16
  unsigned short* Wt2   = (unsigned short*)(ws + 106034176);  // 128x128 bf16
  float*          bcat1 = (float*)(ws + 106066944);
  float*          bcat2 = (float*)(ws + 106068992);
  float*          ACC   = (float*)(ws + 106069504);
  int2*           ebuck = (int2*)(ws + 106070016);          // E * 8B

  float* out = (float*)d_out;

  dim3 blk(256);

  // ---- fused prep (zeroes bhist/ACC; folds 1/sqrt32 into Wq/bq) ----
  prep_fused<<<dim3(CAST_B + C1_B + C2_B + 1), blk, 0, stream>>>(
      x, Wq1, Wk1, Wv1, Ws1, bq1, bk1, bv1, bs1,
      Wq2, Wk2, Wv2, Ws2, bq2, bk2, bv2, bs2,
      xb, Wt1, bcat1, Wt2, bcat2, bhist, ACC);

  // ---- CSR build (two-level bucket sort; esrc stored as byte offsets) ----
  bucket_hist<<<dim3(EB), blk, 0, stream>>>(ei, bhist, E);
  bucket_scan<<<dim3(1), blk, 0, stream>>>(bhist, boff, bcur);
  bucket_scatter<<<dim3(EB), blk, 0, stream>>>(ei, bcur, ebuck, E);
  bucket_csr<<<dim3(NBK), blk, 0, stream>>>(ebuck, boff, rowptr, esrc, N);

  // ---- conv1 GEMMs (one 3-way launch; KV emitted fp8) ----
  gemm_conv1<<<dim3(GB, 3), blk, 0, stream>>>(xb, Wt1, bcat1, Q1b, SK1, KV1, N);

  // ---- conv1 fused attention + skip + relu -> bf16 ----
  node_attn1<<<dim3((N * 64 + 255) / 256), blk, 0, stream>>>(rowptr, esrc, Q1b, KV1, SK1, H1b, N);

  // ---- conv2 GEMM (fused Q|KV8|H rows) ----
  gemm2<<<dim3(GB), blk, 0, stream>>>(H1b, Wt2, bcat2, C2, N);

  // ---- conv2 fused attention ----
  node_attn2<<<dim3((N * 64 + 255) / 256), blk, 0, stream>>>(rowptr, esrc, C2, N);

  // ---- relu + mean + final linear ----
  mean_reduce<<<dim3(1024), blk, 0, stream>>>(C2, ACC, N);
  final_out<<<dim3(1), dim3(64), 0, stream>>>(ACC, Wo, bo, out, 1.0f / (float)N);
}

// Round 13
// 270.427 us; speedup vs baseline: 1.4270x; 1.0514x over previous
//
#include <hip/hip_runtime.h>
#include <math.h>

#define N_NODES 50000
#define N_EDGES 800000
#define NBK 196          // dst buckets of 256 nodes: bucket = dst >> 8
#define BCAP 6144        // max edges per bucket handled in LDS (mean 4082, sigma 64)

typedef short short8 __attribute__((ext_vector_type(8)));
typedef float f32x4 __attribute__((ext_vector_type(4)));
typedef float f32x2 __attribute__((ext_vector_type(2)));

// ---------------- bf16 / fp8 helpers ----------------
__device__ inline unsigned short f2bf(float v) {
  unsigned u = __float_as_uint(v);
  u += 0x7FFFu + ((u >> 16) & 1u);  // round-to-nearest-even
  return (unsigned short)(u >> 16);
}
__device__ inline float bf2f(unsigned short b) {
  return __uint_as_float(((unsigned)b) << 16);
}
__device__ inline float bflo(unsigned u) { return __uint_as_float(u << 16); }
__device__ inline float bfhi(unsigned u) { return __uint_as_float(u & 0xFFFF0000u); }
// fp8 e4m3 (OCP on gfx950); decode selector must be an immediate -> template param.
__device__ inline unsigned char f2fp8(float v) {
  return (unsigned char)(__builtin_amdgcn_cvt_pk_fp8_f32(v, 0.f, 0, false) & 0xFF);
}
template <bool HI>
__device__ inline f32x2 fp8dec(unsigned u) {
  return __builtin_amdgcn_cvt_pk_f32_fp8(u, HI);
}

#define SCL 0.17677669529663687f   // 1/sqrt(32), folded into Wq/bq at prep

// ---------------- fused prep: cast x->bf16, concat both weight sets, zero bhist/ACC ----------------
#define CAST_B 6250   // N*128/4 / 256
#define C1_B 256      // 512*128 / 256
#define C2_B 64       // 128*128 / 256
__global__ void prep_fused(const float* __restrict__ x,
                           const float* __restrict__ Wq1, const float* __restrict__ Wk1,
                           const float* __restrict__ Wv1, const float* __restrict__ Ws1,
                           const float* __restrict__ bq1, const float* __restrict__ bk1,
                           const float* __restrict__ bv1, const float* __restrict__ bs1,
                           const float* __restrict__ Wq2, const float* __restrict__ Wk2,
                           const float* __restrict__ Wv2, const float* __restrict__ Ws2,
                           const float* __restrict__ bq2, const float* __restrict__ bk2,
                           const float* __restrict__ bv2, const float* __restrict__ bs2,
                           unsigned short* __restrict__ xb, unsigned short* __restrict__ Wt1,
                           float* __restrict__ bcat1, unsigned short* __restrict__ Wt2,
                           float* __restrict__ bcat2, int* __restrict__ bhist,
                           float* __restrict__ ACC) {
  const int b = blockIdx.x, tid = threadIdx.x;
  if (b < CAST_B) {
    int i = b * 256 + tid;  // float4 index
    float4 v = ((const float4*)x)[i];
    ushort4 o;
    o.x = f2bf(v.x); o.y = f2bf(v.y); o.z = f2bf(v.z); o.w = f2bf(v.w);
    ((ushort4*)xb)[i] = o;
  } else if (b < CAST_B + C1_B) {
    int i = (b - CAST_B) * 256 + tid;   // over 512*128
    int c = i >> 7, k = i & 127;
    int mi = c >> 7, lc = c & 127;
    const float* W = (mi == 0) ? Wq1 : (mi == 1) ? Wk1 : (mi == 2) ? Wv1 : Ws1;
    float scl = (mi == 0) ? SCL : 1.f;   // fold 1/sqrt(32) into Q
    Wt1[i] = f2bf(W[(size_t)k * 128 + lc] * scl);
    if (i < 512) {
      int bm = i >> 7, bl = i & 127;
      const float* bb = (bm == 0) ? bq1 : (bm == 1) ? bk1 : (bm == 2) ? bv1 : bs1;
      bcat1[i] = bb[bl] * ((bm == 0) ? SCL : 1.f);
    }
  } else if (b < CAST_B + C1_B + C2_B) {
    int i = (b - CAST_B - C1_B) * 256 + tid;  // over 128*128
    int c = i >> 7, k = i & 127;
    int mi = c >> 5, lc = c & 31;
    const float* W = (mi == 0) ? Wq2 : (mi == 1) ? Wk2 : (mi == 2) ? Wv2 : Ws2;
    float scl = (mi == 0) ? SCL : 1.f;
    Wt2[i] = f2bf(W[(size_t)k * 32 + lc] * scl);
    if (i < 128) {
      int bm = i >> 5, bl = i & 31;
      const float* bb = (bm == 0) ? bq2 : (bm == 1) ? bk2 : (bm == 2) ? bv2 : bs2;
      bcat2[i] = bb[bl] * ((bm == 0) ? SCL : 1.f);
    }
  } else {
    if (tid < NBK) bhist[tid] = 0;
    else if (tid >= 224 && tid < 256) ACC[tid - 224] = 0.f;
  }
}

// ================= conv1 GEMM v2: one block = 64 rows x ALL 512 cols =================
// A staged in LDS once (stride 136 shorts); wave w owns cols [128w,128w+128):
// wave0 -> Q (bf16), wave1 -> K (fp8), wave2 -> V (fp8), wave3 -> SK (bf16).
// KV fp8 row (256 B/node): byte 4t+{0,1} = K[2t,2t+1], byte 4t+{2,3} = V[2t,2t+1].
__global__ __launch_bounds__(256) void gemm_conv1(
    const unsigned short* __restrict__ Ab, const unsigned short* __restrict__ Wt,
    const float* __restrict__ bcat, unsigned short* __restrict__ Q1b,
    unsigned short* __restrict__ SK1, unsigned char* __restrict__ KV8, int M) {
  __shared__ __align__(16) unsigned char L[3][64 * 272];  // 52.2 KB
  unsigned short* As = (unsigned short*)L[0];             // stride 136 shorts
  const int bm = blockIdx.x * 64;
  const int tid = threadIdx.x, wave = tid >> 6, lane = tid & 63;
  const int lr = lane & 15, q = lane >> 4;

  // ---- stage A tile: 64 rows x 128 k (16 KB), coalesced 16B chunks ----
#pragma unroll
  for (int p = 0; p < 4; ++p) {
    int f = tid + p * 256;          // 0..1023
    int row = f >> 4, chunk = f & 15;
    int gm = bm + row; if (gm >= M) gm = 0;
    uint4 v = *(const uint4*)(Ab + (size_t)gm * 128 + chunk * 8);
    *(uint4*)&As[row * 136 + chunk * 8] = v;
  }
  __syncthreads();

  const int colbase = wave * 128;
  f32x4 acc[4][8];
#pragma unroll
  for (int i = 0; i < 4; ++i)
#pragma unroll
    for (int j = 0; j < 8; ++j) acc[i][j] = (f32x4){0.f, 0.f, 0.f, 0.f};

#pragma unroll
  for (int ks = 0; ks < 4; ++ks) {
    short8 af[4];
#pragma unroll
    for (int i = 0; i < 4; ++i)
      af[i] = *(short8*)&As[(i * 16 + lr) * 136 + ks * 32 + q * 8];
#pragma unroll
    for (int j = 0; j < 8; ++j) {
      short8 bf = *(const short8*)(Wt + (size_t)(colbase + j * 16 + lr) * 128 + ks * 32 + q * 8);
#pragma unroll
      for (int i = 0; i < 4; ++i)
        acc[i][j] = __builtin_amdgcn_mfma_f32_16x16x32_bf16(af[i], bf, acc[i][j], 0, 0, 0);
    }
  }
  __syncthreads();   // As dead; regions reused for staging

  float bj[8];
#pragma unroll
  for (int j = 0; j < 8; ++j) bj[j] = bcat[colbase + j * 16 + lr];

  // ---- per-wave epilogue into LDS: L[1]=Q(shorts), L[2]=KV(bytes), L[0]=SK(shorts) ----
  if (wave == 0 || wave == 3) {
    unsigned short* Ls16 = (unsigned short*)((wave == 0) ? L[1] : L[0]);
#pragma unroll
    for (int i = 0; i < 4; ++i)
#pragma unroll
      for (int r = 0; r < 4; ++r) {
        int row = i * 16 + q * 4 + r;
#pragma unroll
        for (int j = 0; j < 8; ++j)
          Ls16[row * 136 + j * 16 + lr] = f2bf(acc[i][j][r] + bj[j]);
      }
  } else {
    unsigned char* KLs = L[2];
    const int voff = (wave == 2) ? 2 : 0;
#pragma unroll
    for (int i = 0; i < 4; ++i)
#pragma unroll
      for (int r = 0; r < 4; ++r) {
        int row = i * 16 + q * 4 + r;
#pragma unroll
        for (int j = 0; j < 8; ++j) {
          int d = j * 16 + lr;
          KLs[row * 272 + 4 * (d >> 1) + voff + (d & 1)] = f2fp8(acc[i][j][r] + bj[j]);
        }
      }
  }
  __syncthreads();

  // ---- cooperative coalesced copy-out (16B per thread per pass) ----
#pragma unroll
  for (int p = 0; p < 4; ++p) {
    int f = tid + p * 256;
    int row = f >> 4, u = f & 15;
    int gr = bm + row;
    if (gr < M) {
      *(uint4*)(Q1b + (size_t)gr * 128 + u * 8) = *(uint4*)&((unsigned short*)L[1])[row * 136 + u * 8];
      *(uint4*)(KV8 + (size_t)gr * 256 + u * 16) = *(uint4*)&L[2][row * 272 + u * 16];
      *(uint4*)(SK1 + (size_t)gr * 128 + u * 8) = *(uint4*)&((unsigned short*)L[0])[row * 136 + u * 8];
    }
  }
}

// ---- gemm2 v2: LDS-staged A; 128 cols of Wt2 -> C2 rows (256 B): [Q bf16 | KV fp8 | pad | H bf16] ----
__global__ __launch_bounds__(256) void gemm2(
    const unsigned short* __restrict__ Ab, const unsigned short* __restrict__ Wt,
    const float* __restrict__ bcat, unsigned char* __restrict__ C2b, int M) {
  __shared__ __align__(16) unsigned short As[64 * 136];   // 17.4 KB
  __shared__ __align__(16) unsigned char Lsb[64 * 272];   // 17.4 KB
  const int bm = blockIdx.x * 64;
  const int tid = threadIdx.x, wave = tid >> 6, lane = tid & 63;
  const int lr = lane & 15, q = lane >> 4;

#pragma unroll
  for (int p = 0; p < 4; ++p) {
    int f = tid + p * 256;
    int row = f >> 4, chunk = f & 15;
    int gm = bm + row; if (gm >= M) gm = 0;
    uint4 v = *(const uint4*)(Ab + (size_t)gm * 128 + chunk * 8);
    *(uint4*)&As[row * 136 + chunk * 8] = v;
  }
  __syncthreads();

  f32x4 acc[4][2];
#pragma unroll
  for (int i = 0; i < 4; ++i)
#pragma unroll
    for (int j = 0; j < 2; ++j) acc[i][j] = (f32x4){0.f, 0.f, 0.f, 0.f};

#pragma unroll
  for (int ks = 0; ks < 4; ++ks) {
    short8 af[4];
#pragma unroll
    for (int i = 0; i < 4; ++i)
      af[i] = *(short8*)&As[(i * 16 + lr) * 136 + ks * 32 + q * 8];
#pragma unroll
    for (int j = 0; j < 2; ++j) {
      short8 bf = *(const short8*)(Wt + (size_t)(wave * 32 + j * 16 + lr) * 128 + ks * 32 + q * 8);
#pragma unroll
      for (int i = 0; i < 4; ++i)
        acc[i][j] = __builtin_amdgcn_mfma_f32_16x16x32_bf16(af[i], bf, acc[i][j], 0, 0, 0);
    }
  }

  float bj[2];
#pragma unroll
  for (int j = 0; j < 2; ++j) bj[j] = bcat[wave * 32 + j * 16 + lr];
#pragma unroll
  for (int i = 0; i < 4; ++i)
#pragma unroll
    for (int r = 0; r < 4; ++r) {
      int row = i * 16 + q * 4 + r;
#pragma unroll
      for (int j = 0; j < 2; ++j) {
        int c = wave * 32 + j * 16 + lr;
        float val = acc[i][j][r] + bj[j];
        if (c < 32) {
          *(unsigned short*)&Lsb[row * 272 + 2 * c] = f2bf(val);
        } else if (c < 64) {
          int d = c - 32;
          Lsb[row * 272 + 64 + 4 * (d >> 1) + (d & 1)] = f2fp8(val);
        } else if (c < 96) {
          int d = c - 64;
          Lsb[row * 272 + 64 + 4 * (d >> 1) + 2 + (d & 1)] = f2fp8(val);
        } else {
          *(unsigned short*)&Lsb[row * 272 + 192 + 2 * (c - 96)] = f2bf(val);
        }
      }
    }
  __syncthreads();
#pragma unroll
  for (int p = 0; p < 16; ++p) {
    int idx = tid + p * 256;
    int row = idx >> 6, u = idx & 63;
    int gr = bm + row;
    if (gr < M) *(unsigned*)(C2b + (size_t)gr * 256 + u * 4) = *(const unsigned*)&Lsb[row * 272 + u * 4];
  }
}

// ================= CSR build via two-level bucket sort =================
__global__ void bucket_hist(const int* __restrict__ ei, int* __restrict__ bhist, int E) {
  __shared__ int h[NBK];
  for (int i = threadIdx.x; i < NBK; i += 256) h[i] = 0;
  __syncthreads();
  int e = blockIdx.x * 4096 + threadIdx.x;
#pragma unroll
  for (int p = 0; p < 16; ++p, e += 256)
    if (e < E) atomicAdd(&h[ei[E + e] >> 8], 1);
  __syncthreads();
  for (int i = threadIdx.x; i < NBK; i += 256)
    if (h[i]) atomicAdd(&bhist[i], h[i]);
}

__global__ void bucket_scan(const int* __restrict__ bhist, int* __restrict__ boff,
                            int* __restrict__ bcur) {
  __shared__ int s[256];
  int t = threadIdx.x;
  int v = (t < NBK) ? bhist[t] : 0;
  s[t] = v;
  __syncthreads();
#pragma unroll
  for (int off = 1; off < 256; off <<= 1) {
    int u = (t >= off) ? s[t - off] : 0;
    __syncthreads();
    s[t] += u;
    __syncthreads();
  }
  if (t < NBK) {
    int excl = s[t] - v;
    boff[t] = excl;
    bcur[t] = excl;
  }
  if (t == NBK - 1) boff[NBK] = s[t];
}

__global__ void bucket_scatter(const int* __restrict__ ei, int* __restrict__ bcur,
                               int2* __restrict__ ebuck, int E) {
  __shared__ int lh[NBK];
  for (int i = threadIdx.x; i < NBK; i += 256) lh[i] = 0;
  __syncthreads();
  const int e0 = blockIdx.x * 4096;
  int srcs[16], dsts[16];
#pragma unroll
  for (int p = 0; p < 16; ++p) {
    int e = e0 + p * 256 + threadIdx.x;
    if (e < E) {
      srcs[p] = ei[e];
      dsts[p] = ei[E + e];
      atomicAdd(&lh[dsts[p] >> 8], 1);
    } else dsts[p] = -1;
  }
  __syncthreads();
  for (int i = threadIdx.x; i < NBK; i += 256)
    if (lh[i]) lh[i] = atomicAdd(&bcur[i], lh[i]);
  __syncthreads();
#pragma unroll
  for (int p = 0; p < 16; ++p) {
    if (dsts[p] >= 0) {
      int slot = atomicAdd(&lh[dsts[p] >> 8], 1);
      ebuck[slot] = make_int2(srcs[p], dsts[p]);
    }
  }
}

// esrc entries are stored pre-shifted (src<<8 = byte offset into the 256B/node tables)
__global__ void bucket_csr(const int2* __restrict__ ebuck, const int* __restrict__ boff,
                           int* __restrict__ rowptr, int* __restrict__ esrc, int N) {
  const int b = blockIdx.x;
  const int lo = boff[b], hi = boff[b + 1];
  const int cnt = hi - lo;
  __shared__ int hist[256];
  __shared__ int cur[256];
  __shared__ int sorted[BCAP];
  const int t = threadIdx.x;
  hist[t] = 0;
  __syncthreads();
  for (int i = t; i < cnt; i += 256) {
    int2 ed = ebuck[lo + i];
    atomicAdd(&hist[ed.y & 255], 1);
  }
  __syncthreads();
  int v = hist[t];
  sorted[t] = v;
  __syncthreads();
#pragma unroll
  for (int off = 1; off < 256; off <<= 1) {
    int u = (t >= off) ? sorted[t - off] : 0;
    __syncthreads();
    sorted[t] += u;
    __syncthreads();
  }
  int excl = sorted[t] - v;
  cur[t] = excl;
  int node = b * 256 + t;
  if (node <= N) rowptr[node] = lo + excl;
  __syncthreads();
  for (int i = t; i < cnt; i += 256) {
    int2 ed = ebuck[lo + i];
    int slot = atomicAdd(&cur[ed.y & 255], 1);
    if (slot < BCAP) sorted[slot] = ed.x;
    else esrc[lo + slot] = ed.x << 8;  // overflow fallback
  }
  __syncthreads();
  int lim = cnt < BCAP ? cnt : BCAP;
  for (int i = t; i < lim; i += 256) esrc[lo + i] = sorted[i] << 8;
}

// ================= fused aggregation: plain-exp softmax, fp8 K/V =================
// conv1: 32 lanes per edge; halves process disjoint edges; x8 main loop (4 edges/half).
__global__ void node_attn1(const int* __restrict__ rowptr, const int* __restrict__ esrc,
                           const unsigned short* __restrict__ Qb,
                           const unsigned char* __restrict__ KV8,
                           const unsigned short* __restrict__ SK, unsigned short* __restrict__ Hb,
                           int n) {
  int node = (blockIdx.x * blockDim.x + threadIdx.x) >> 6;
  int lane = threadIdx.x & 63;
  if (node >= n) return;
  const int half = lane >> 5, ll = lane & 31;
  const int r0 = rowptr[node], r1 = rowptr[node + 1];
  uint2 qq = *(const uint2*)(Qb + (size_t)node * 128 + ll * 4);
  const float q0 = bflo(qq.x), q1 = bfhi(qq.x), q2 = bflo(qq.y), q3 = bfhi(qq.y);
  float l = 0.f, a0 = 0.f, a1 = 0.f, a2 = 0.f, a3 = 0.f;
  const unsigned char* kvb = KV8 + ll * 8;
  int j = r0;
  for (; j + 8 <= r1; j += 8) {
    int e = j + half * 4;
    int s0 = esrc[e], s1 = esrc[e + 1], s2 = esrc[e + 2], s3 = esrc[e + 3];
    uint2 u0 = *(const uint2*)(kvb + s0);
    uint2 u1 = *(const uint2*)(kvb + s1);
    uint2 u2 = *(const uint2*)(kvb + s2);
    uint2 u3 = *(const uint2*)(kvb + s3);
    f32x2 k0a = fp8dec<false>(u0.x), k0b = fp8dec<false>(u0.y);
    f32x2 k1a = fp8dec<false>(u1.x), k1b = fp8dec<false>(u1.y);
    f32x2 k2a = fp8dec<false>(u2.x), k2b = fp8dec<false>(u2.y);
    f32x2 k3a = fp8dec<false>(u3.x), k3b = fp8dec<false>(u3.y);
    float d0 = q0 * k0a.x + q1 * k0a.y + q2 * k0b.x + q3 * k0b.y;
    float d1 = q0 * k1a.x + q1 * k1a.y + q2 * k1b.x + q3 * k1b.y;
    float d2 = q0 * k2a.x + q1 * k2a.y + q2 * k2b.x + q3 * k2b.y;
    float d3 = q0 * k3a.x + q1 * k3a.y + q2 * k3b.x + q3 * k3b.y;
#pragma unroll
    for (int msk = 1; msk <= 4; msk <<= 1) {
      d0 += __shfl_xor(d0, msk);
      d1 += __shfl_xor(d1, msk);
      d2 += __shfl_xor(d2, msk);
      d3 += __shfl_xor(d3, msk);
    }
    float p0 = __expf(d0), p1 = __expf(d1), p2 = __expf(d2), p3 = __expf(d3);
    l += (p0 + p1) + (p2 + p3);
    f32x2 v0a = fp8dec<true>(u0.x), v0b = fp8dec<true>(u0.y);
    f32x2 v1a = fp8dec<true>(u1.x), v1b = fp8dec<true>(u1.y);
    f32x2 v2a = fp8dec<true>(u2.x), v2b = fp8dec<true>(u2.y);
    f32x2 v3a = fp8dec<true>(u3.x), v3b = fp8dec<true>(u3.y);
    a0 += p0 * v0a.x + p1 * v1a.x + p2 * v2a.x + p3 * v3a.x;
    a1 += p0 * v0a.y + p1 * v1a.y + p2 * v2a.y + p3 * v3a.y;
    a2 += p0 * v0b.x + p1 * v1b.x + p2 * v2b.x + p3 * v3b.x;
    a3 += p0 * v0b.y + p1 * v1b.y + p2 * v2b.y + p3 * v3b.y;
  }
  for (; j < r1; j += 4) {  // masked tail, 2 edges/half per pass
    int eA = j + half * 2, eB = eA + 1;
    bool vA = eA < r1, vB = eB < r1;
    int sA = esrc[vA ? eA : r0];
    int sB = esrc[vB ? eB : r0];
    uint2 ua = *(const uint2*)(kvb + sA);
    uint2 ub = *(const uint2*)(kvb + sB);
    f32x2 ka1 = fp8dec<false>(ua.x), ka2 = fp8dec<false>(ua.y);
    f32x2 kb1 = fp8dec<false>(ub.x), kb2 = fp8dec<false>(ub.y);
    float dA = q0 * ka1.x + q1 * ka1.y + q2 * ka2.x + q3 * ka2.y;
    float dB = q0 * kb1.x + q1 * kb1.y + q2 * kb2.x + q3 * kb2.y;
#pragma unroll
    for (int msk = 1; msk <= 4; msk <<= 1) {
      dA += __shfl_xor(dA, msk);
      dB += __shfl_xor(dB, msk);
    }
    float pA = vA ? __expf(dA) : 0.f;
    float pB = vB ? __expf(dB) : 0.f;
    l += pA + pB;
    f32x2 va1 = fp8dec<true>(ua.x), va2 = fp8dec<true>(ua.y);
    f32x2 vb1 = fp8dec<true>(ub.x), vb2 = fp8dec<true>(ub.y);
    a0 += pA * va1.x + pB * vb1.x;
    a1 += pA * va1.y + pB * vb1.y;
    a2 += pA * va2.x + pB * vb2.x;
    a3 += pA * va2.y + pB * vb2.y;
  }
  l  += __shfl_xor(l, 32);
  a0 += __shfl_xor(a0, 32);
  a1 += __shfl_xor(a1, 32);
  a2 += __shfl_xor(a2, 32);
  a3 += __shfl_xor(a3, 32);
  float inv = (l > 0.f) ? 1.f / l : 0.f;
  if (half == 0) {
    uint2 sk = *(const uint2*)(SK + (size_t)node * 128 + ll * 4);
    float o0 = fmaxf(bflo(sk.x) + a0 * inv, 0.f);
    float o1 = fmaxf(bfhi(sk.x) + a1 * inv, 0.f);
    float o2 = fmaxf(bflo(sk.y) + a2 * inv, 0.f);
    float o3 = fmaxf(bfhi(sk.y) + a3 * inv, 0.f);
    uint2 hb;
    hb.x = ((unsigned)f2bf(o1) << 16) | (unsigned)f2bf(o0);
    hb.y = ((unsigned)f2bf(o3) << 16) | (unsigned)f2bf(o2);
    *(uint2*)(Hb + (size_t)node * 128 + ll * 4) = hb;
  }
}

// conv2: 16 lanes per edge (4 groups); x8 main loop (2 edges/group); plain exp.
__global__ void node_attn2(const int* __restrict__ rowptr, const int* __restrict__ esrc,
                           unsigned char* __restrict__ C2b, int n) {
  int node = (blockIdx.x * blockDim.x + threadIdx.x) >> 6;
  int lane = threadIdx.x & 63;
  if (node >= n) return;
  const int g = lane >> 4, gl = lane & 15;
  const int r0 = rowptr[node], r1 = rowptr[node + 1];
  unsigned qu = *(const unsigned*)(C2b + (size_t)node * 256 + gl * 4);
  const float q0 = bflo(qu), q1 = bfhi(qu);
  float l = 0.f, a0 = 0.f, a1 = 0.f;
  const unsigned char* kvb = C2b + 64 + gl * 4;
  int j = r0;
  for (; j + 8 <= r1; j += 8) {
    int e = j + g * 2;
    int s0 = esrc[e], s1 = esrc[e + 1];
    unsigned u0 = *(const unsigned*)(kvb + s0);
    unsigned u1 = *(const unsigned*)(kvb + s1);
    f32x2 k0 = fp8dec<false>(u0), k1 = fp8dec<false>(u1);
    float d0 = q0 * k0.x + q1 * k0.y;
    float d1 = q0 * k1.x + q1 * k1.y;
#pragma unroll
    for (int msk = 1; msk <= 8; msk <<= 1) {
      d0 += __shfl_xor(d0, msk);
      d1 += __shfl_xor(d1, msk);
    }
    float p0 = __expf(d0), p1 = __expf(d1);
    l += p0 + p1;
    f32x2 v0 = fp8dec<true>(u0), v1 = fp8dec<true>(u1);
    a0 += p0 * v0.x + p1 * v1.x;
    a1 += p0 * v0.y + p1 * v1.y;
  }
  for (; j < r1; j += 4) {  // masked tail, 1 edge/group per pass
    bool v = (j + g) < r1;
    int s = esrc[v ? j + g : r0];
    unsigned u = *(const unsigned*)(kvb + s);
    f32x2 kd = fp8dec<false>(u);
    float d = q0 * kd.x + q1 * kd.y;
#pragma unroll
    for (int msk = 1; msk <= 8; msk <<= 1) d += __shfl_xor(d, msk);
    float p = v ? __expf(d) : 0.f;
    l += p;
    f32x2 vd = fp8dec<true>(u);
    a0 += p * vd.x;
    a1 += p * vd.y;
  }
#pragma unroll
  for (int msk = 16; msk <= 32; msk <<= 1) {
    l  += __shfl_xor(l, msk);
    a0 += __shfl_xor(a0, msk);
    a1 += __shfl_xor(a1, msk);
  }
  float inv = (l > 0.f) ? 1.f / l : 0.f;
  if (lane < 16) {
    unsigned* h = (unsigned*)(C2b + (size_t)node * 256 + 192 + gl * 4);
    unsigned hu = *h;
    float o0 = bflo(hu) + a0 * inv;
    float o1 = bfhi(hu) + a1 * inv;
    *h = ((unsigned)f2bf(o1) << 16) | (unsigned)f2bf(o0);
  }
}

// ---------------- epilogue ----------------
__global__ void mean_reduce(const unsigned char* __restrict__ C2b, float* __restrict__ ACC, int n) {
  __shared__ float s[256];
  float acc = 0.f;
  int stride = gridDim.x * blockDim.x;
  int total = n * 32;
  for (int i = blockIdx.x * blockDim.x + threadIdx.x; i < total; i += stride) {
    int node = i >> 5, c = i & 31;
    unsigned short h = *(const unsigned short*)(C2b + (size_t)node * 256 + 192 + c * 2);
    acc += fmaxf(bf2f(h), 0.f);
  }
  s[threadIdx.x] = acc;
  __syncthreads();
  for (int off = 128; off >= 32; off >>= 1) {
    if (threadIdx.x < off) s[threadIdx.x] += s[threadIdx.x + off];
    __syncthreads();
  }
  if (threadIdx.x < 32) atomicAdd(&ACC[threadIdx.x], s[threadIdx.x]);
}

__global__ void final_out(const float* __restrict__ ACC, const float* __restrict__ Wo,
                          const float* __restrict__ bo, float* __restrict__ out, float invN) {
  int lane = threadIdx.x;
  float v = 0.f;
  if (lane < 32) v = ACC[lane] * invN * Wo[lane];
  v += __shfl_xor(v, 1);
  v += __shfl_xor(v, 2);
  v += __shfl_xor(v, 4);
  v += __shfl_xor(v, 8);
  v += __shfl_xor(v, 16);
  v += __shfl_xor(v, 32);
  if (lane == 0) out[0] = v + bo[0];
}

extern "C" void kernel_launch(void* const* d_in, const int* in_sizes, int n_in,
                              void* d_out, int out_size, void* d_ws, size_t ws_size,
                              hipStream_t stream) {
  const float* x   = (const float*)d_in[0];
  const int*   ei  = (const int*)d_in[1];  // [2, E]: row 0 = src, row 1 = dst
  const float* Wq1 = (const float*)d_in[2];  const float* bq1 = (const float*)d_in[3];
  const float* Wk1 = (const float*)d_in[4];  const float* bk1 = (const float*)d_in[5];
  const float* Wv1 = (const float*)d_in[6];  const float* bv1 = (const float*)d_in[7];
  const float* Ws1 = (const float*)d_in[8];  const float* bs1 = (const float*)d_in[9];
  const float* Wq2 = (const float*)d_in[10]; const float* bq2 = (const float*)d_in[11];
  const float* Wk2 = (const float*)d_in[12]; const float* bk2 = (const float*)d_in[13];
  const float* Wv2 = (const float*)d_in[14]; const float* bv2 = (const float*)d_in[15];
  const float* Ws2 = (const float*)d_in[16]; const float* bs2 = (const float*)d_in[17];
  const float* Wo  = (const float*)d_in[18]; const float* bo  = (const float*)d_in[19];

  char* ws = (char*)d_ws;
  const int N = N_NODES, E = N_EDGES;
  const int GB = (N + 63) / 64;
  const int EB = (E + 4095) / 4096;

  // buffers
  unsigned short* xb  = (unsigned short*)(ws + 0);          // N*128 bf16
  unsigned short* Q1b = (unsigned short*)(ws + 12800000);   // N*128 bf16 (pre-scaled)
  unsigned short* SK1 = (unsigned short*)(ws + 25600000);   // N*128 bf16
  unsigned char*  KV1 = (unsigned char*)(ws + 38400000);    // N*256 fp8
  unsigned short* H1b = (unsigned short*)(ws + 64000000);   // N*128 bf16
  unsigned char*  C2  = (unsigned char*)(ws + 76800000);    // N*256 bytes [Q|KV8|pad|H]
  // CSR + weights + misc
  int* rowptr = (int*)(ws + 102400000);                     // N+1
  int* esrc   = (int*)(ws + 102700032);                     // E (byte offsets, src<<8)
  int* bhist  = (int*)(ws + 105900032);                     // NBK
  int* boff   = (int*)(ws + 105901056);                     // NBK+1
  int* bcur   = (int*)(ws + 105902080);                     // NBK
  unsigned short* Wt1   = (unsigned short*)(ws + 105903104);  // 512x128 bf16
  unsigned short* Wt2   = (unsigned short*)(ws + 106034176);  // 128x128 bf16
  float*          bcat1 = (float*)(ws + 106066944);
  float*          bcat2 = (float*)(ws + 106068992);
  float*          ACC   = (float*)(ws + 106069504);
  int2*           ebuck = (int2*)(ws + 106070016);          // E * 8B

  float* out = (float*)d_out;

  dim3 blk(256);

  // ---- fused prep (zeroes bhist/ACC; folds 1/sqrt32 into Wq/bq) ----
  prep_fused<<<dim3(CAST_B + C1_B + C2_B + 1), blk, 0, stream>>>(
      x, Wq1, Wk1, Wv1, Ws1, bq1, bk1, bv1, bs1,
      Wq2, Wk2, Wv2, Ws2, bq2, bk2, bv2, bs2,
      xb, Wt1, bcat1, Wt2, bcat2, bhist, ACC);

  // ---- CSR build (two-level bucket sort; esrc stored as byte offsets) ----
  bucket_hist<<<dim3(EB), blk, 0, stream>>>(ei, bhist, E);
  bucket_scan<<<dim3(1), blk, 0, stream>>>(bhist, boff, bcur);
  bucket_scatter<<<dim3(EB), blk, 0, stream>>>(ei, bcur, ebuck, E);
  bucket_csr<<<dim3(NBK), blk, 0, stream>>>(ebuck, boff, rowptr, esrc, N);

  // ---- conv1 GEMM (single launch: 64 rows x 512 cols per block) ----
  gemm_conv1<<<dim3(GB), blk, 0, stream>>>(xb, Wt1, bcat1, Q1b, SK1, KV1, N);

  // ---- conv1 fused attention + skip + relu -> bf16 ----
  node_attn1<<<dim3((N * 64 + 255) / 256), blk, 0, stream>>>(rowptr, esrc, Q1b, KV1, SK1, H1b, N);

  // ---- conv2 GEMM (fused Q|KV8|H rows) ----
  gemm2<<<dim3(GB), blk, 0, stream>>>(H1b, Wt2, bcat2, C2, N);

  // ---- conv2 fused attention ----
  node_attn2<<<dim3((N * 64 + 255) / 256), blk, 0, stream>>>(rowptr, esrc, C2, N);

  // ---- relu + mean + final linear ----
  mean_reduce<<<dim3(1024), blk, 0, stream>>>(C2, ACC, N);
  final_out<<<dim3(1), dim3(64), 0, stream>>>(ACC, Wo, bo, out, 1.0f / (float)N);
}

// Round 14
// 269.969 us; speedup vs baseline: 1.4295x; 1.0017x over previous
//
#include <hip/hip_runtime.h>
#include <math.h>

#define N_NODES 50000
#define N_EDGES 800000
#define NBK 196          // dst buckets of 256 nodes: bucket = dst >> 8
#define BCAP 6144        // max edges per bucket handled in LDS (mean 4082, sigma 64)

typedef short short8 __attribute__((ext_vector_type(8)));
typedef float f32x4 __attribute__((ext_vector_type(4)));
typedef float f32x2 __attribute__((ext_vector_type(2)));

// ---------------- bf16 / fp8 helpers ----------------
__device__ inline unsigned short f2bf(float v) {
  unsigned u = __float_as_uint(v);
  u += 0x7FFFu + ((u >> 16) & 1u);  // round-to-nearest-even
  return (unsigned short)(u >> 16);
}
__device__ inline float bf2f(unsigned short b) {
  return __uint_as_float(((unsigned)b) << 16);
}
__device__ inline float bflo(unsigned u) { return __uint_as_float(u << 16); }
__device__ inline float bfhi(unsigned u) { return __uint_as_float(u & 0xFFFF0000u); }
// fp8 e4m3 (OCP on gfx950); decode selector must be an immediate -> template param.
__device__ inline unsigned char f2fp8(float v) {
  return (unsigned char)(__builtin_amdgcn_cvt_pk_fp8_f32(v, 0.f, 0, false) & 0xFF);
}
template <bool HI>
__device__ inline f32x2 fp8dec(unsigned u) {
  return __builtin_amdgcn_cvt_pk_f32_fp8(u, HI);
}

#define SCL 0.17677669529663687f   // 1/sqrt(32), folded into Wq/bq at prep

// ---------------- fused prep: weight concat/transpose + bucket histogram ----------------
// blocks [0,256): Wt1; [256,320): Wt2; [320,320+EB): edge-bucket histogram.
#define W1_B 256      // 512*128 / 256
#define W2_B 64       // 128*128 / 256
__global__ void prep_fused(const float* __restrict__ Wq1, const float* __restrict__ Wk1,
                           const float* __restrict__ Wv1, const float* __restrict__ Ws1,
                           const float* __restrict__ bq1, const float* __restrict__ bk1,
                           const float* __restrict__ bv1, const float* __restrict__ bs1,
                           const float* __restrict__ Wq2, const float* __restrict__ Wk2,
                           const float* __restrict__ Wv2, const float* __restrict__ Ws2,
                           const float* __restrict__ bq2, const float* __restrict__ bk2,
                           const float* __restrict__ bv2, const float* __restrict__ bs2,
                           unsigned short* __restrict__ Wt1, float* __restrict__ bcat1,
                           unsigned short* __restrict__ Wt2, float* __restrict__ bcat2,
                           const int* __restrict__ ei, int* __restrict__ bhist, int E) {
  const int b = blockIdx.x, tid = threadIdx.x;
  if (b < W1_B) {
    int i = b * 256 + tid;   // over 512*128
    int c = i >> 7, k = i & 127;
    int mi = c >> 7, lc = c & 127;
    const float* W = (mi == 0) ? Wq1 : (mi == 1) ? Wk1 : (mi == 2) ? Wv1 : Ws1;
    float scl = (mi == 0) ? SCL : 1.f;   // fold 1/sqrt(32) into Q
    Wt1[i] = f2bf(W[(size_t)k * 128 + lc] * scl);
    if (i < 512) {
      int bm = i >> 7, bl = i & 127;
      const float* bb = (bm == 0) ? bq1 : (bm == 1) ? bk1 : (bm == 2) ? bv1 : bs1;
      bcat1[i] = bb[bl] * ((bm == 0) ? SCL : 1.f);
    }
  } else if (b < W1_B + W2_B) {
    int i = (b - W1_B) * 256 + tid;  // over 128*128
    int c = i >> 7, k = i & 127;
    int mi = c >> 5, lc = c & 31;
    const float* W = (mi == 0) ? Wq2 : (mi == 1) ? Wk2 : (mi == 2) ? Wv2 : Ws2;
    float scl = (mi == 0) ? SCL : 1.f;
    Wt2[i] = f2bf(W[(size_t)k * 32 + lc] * scl);
    if (i < 128) {
      int bm = i >> 5, bl = i & 31;
      const float* bb = (bm == 0) ? bq2 : (bm == 1) ? bk2 : (bm == 2) ? bv2 : bs2;
      bcat2[i] = bb[bl] * ((bm == 0) ? SCL : 1.f);
    }
  } else {
    // bucket histogram chunk (bhist pre-zeroed via memset)
    __shared__ int h[NBK];
    for (int i = tid; i < NBK; i += 256) h[i] = 0;
    __syncthreads();
    int e = (b - W1_B - W2_B) * 4096 + tid;
#pragma unroll
    for (int p = 0; p < 16; ++p, e += 256)
      if (e < E) atomicAdd(&h[ei[E + e] >> 8], 1);
    __syncthreads();
    for (int i = tid; i < NBK; i += 256)
      if (h[i]) atomicAdd(&bhist[i], h[i]);
  }
}

// ================= conv1 GEMM: one block = 64 rows x ALL 512 cols =================
// A staged in LDS straight from fp32 x (bf16 convert in-flight); wave w owns cols
// [128w,128w+128): wave0->Q(bf16), wave1->K(fp8), wave2->V(fp8), wave3->SK(bf16).
// KV fp8 row (256 B/node): byte 4t+{0,1} = K[2t,2t+1], byte 4t+{2,3} = V[2t,2t+1].
__global__ __launch_bounds__(256) void gemm_conv1(
    const float* __restrict__ X, const unsigned short* __restrict__ Wt,
    const float* __restrict__ bcat, unsigned short* __restrict__ Q1b,
    unsigned short* __restrict__ SK1, unsigned char* __restrict__ KV8, int M) {
  __shared__ __align__(16) unsigned char L[3][64 * 272];  // 52.2 KB
  unsigned short* As = (unsigned short*)L[0];             // stride 136 shorts
  const int bm = blockIdx.x * 64;
  const int tid = threadIdx.x, wave = tid >> 6, lane = tid & 63;
  const int lr = lane & 15, q = lane >> 4;

  // ---- stage A tile from fp32: 64 rows x 128 k, convert to bf16 ----
#pragma unroll
  for (int p = 0; p < 8; ++p) {
    int f = tid + p * 256;          // 0..2047 float4s
    int row = f >> 5, c4 = f & 31;
    int gm = bm + row; if (gm >= M) gm = 0;
    float4 v = *(const float4*)(X + (size_t)gm * 128 + c4 * 4);
    ushort4 o;
    o.x = f2bf(v.x); o.y = f2bf(v.y); o.z = f2bf(v.z); o.w = f2bf(v.w);
    *(ushort4*)&As[row * 136 + c4 * 4] = o;
  }
  __syncthreads();

  const int colbase = wave * 128;
  f32x4 acc[4][8];
#pragma unroll
  for (int i = 0; i < 4; ++i)
#pragma unroll
    for (int j = 0; j < 8; ++j) acc[i][j] = (f32x4){0.f, 0.f, 0.f, 0.f};

#pragma unroll
  for (int ks = 0; ks < 4; ++ks) {
    short8 af[4];
#pragma unroll
    for (int i = 0; i < 4; ++i)
      af[i] = *(short8*)&As[(i * 16 + lr) * 136 + ks * 32 + q * 8];
#pragma unroll
    for (int j = 0; j < 8; ++j) {
      short8 bf = *(const short8*)(Wt + (size_t)(colbase + j * 16 + lr) * 128 + ks * 32 + q * 8);
#pragma unroll
      for (int i = 0; i < 4; ++i)
        acc[i][j] = __builtin_amdgcn_mfma_f32_16x16x32_bf16(af[i], bf, acc[i][j], 0, 0, 0);
    }
  }
  __syncthreads();   // As dead; regions reused

  float bj[8];
#pragma unroll
  for (int j = 0; j < 8; ++j) bj[j] = bcat[colbase + j * 16 + lr];

  // ---- per-wave epilogue into LDS: L[1]=Q(shorts), L[2]=KV(bytes), L[0]=SK(shorts) ----
  if (wave == 0 || wave == 3) {
    unsigned short* Ls16 = (unsigned short*)((wave == 0) ? L[1] : L[0]);
#pragma unroll
    for (int i = 0; i < 4; ++i)
#pragma unroll
      for (int r = 0; r < 4; ++r) {
        int row = i * 16 + q * 4 + r;
#pragma unroll
        for (int j = 0; j < 8; ++j)
          Ls16[row * 136 + j * 16 + lr] = f2bf(acc[i][j][r] + bj[j]);
      }
  } else {
    unsigned char* KLs = L[2];
    const int voff = (wave == 2) ? 2 : 0;
#pragma unroll
    for (int i = 0; i < 4; ++i)
#pragma unroll
      for (int r = 0; r < 4; ++r) {
        int row = i * 16 + q * 4 + r;
#pragma unroll
        for (int j = 0; j < 8; ++j) {
          int d = j * 16 + lr;
          KLs[row * 272 + 4 * (d >> 1) + voff + (d & 1)] = f2fp8(acc[i][j][r] + bj[j]);
        }
      }
  }
  __syncthreads();

  // ---- cooperative coalesced copy-out (16B per thread per pass) ----
#pragma unroll
  for (int p = 0; p < 4; ++p) {
    int f = tid + p * 256;
    int row = f >> 4, u = f & 15;
    int gr = bm + row;
    if (gr < M) {
      *(uint4*)(Q1b + (size_t)gr * 128 + u * 8) = *(uint4*)&((unsigned short*)L[1])[row * 136 + u * 8];
      *(uint4*)(KV8 + (size_t)gr * 256 + u * 16) = *(uint4*)&L[2][row * 272 + u * 16];
      *(uint4*)(SK1 + (size_t)gr * 128 + u * 8) = *(uint4*)&((unsigned short*)L[0])[row * 136 + u * 8];
    }
  }
}

// ---- gemm2: LDS-staged A (bf16); 128 cols -> C2 rows (256 B): [Q bf16 | KV fp8 | pad | H bf16] ----
__global__ __launch_bounds__(256) void gemm2(
    const unsigned short* __restrict__ Ab, const unsigned short* __restrict__ Wt,
    const float* __restrict__ bcat, unsigned char* __restrict__ C2b, int M) {
  __shared__ __align__(16) unsigned short As[64 * 136];   // 17.4 KB
  __shared__ __align__(16) unsigned char Lsb[64 * 272];   // 17.4 KB
  const int bm = blockIdx.x * 64;
  const int tid = threadIdx.x, wave = tid >> 6, lane = tid & 63;
  const int lr = lane & 15, q = lane >> 4;

#pragma unroll
  for (int p = 0; p < 4; ++p) {
    int f = tid + p * 256;
    int row = f >> 4, chunk = f & 15;
    int gm = bm + row; if (gm >= M) gm = 0;
    uint4 v = *(const uint4*)(Ab + (size_t)gm * 128 + chunk * 8);
    *(uint4*)&As[row * 136 + chunk * 8] = v;
  }
  __syncthreads();

  f32x4 acc[4][2];
#pragma unroll
  for (int i = 0; i < 4; ++i)
#pragma unroll
    for (int j = 0; j < 2; ++j) acc[i][j] = (f32x4){0.f, 0.f, 0.f, 0.f};

#pragma unroll
  for (int ks = 0; ks < 4; ++ks) {
    short8 af[4];
#pragma unroll
    for (int i = 0; i < 4; ++i)
      af[i] = *(short8*)&As[(i * 16 + lr) * 136 + ks * 32 + q * 8];
#pragma unroll
    for (int j = 0; j < 2; ++j) {
      short8 bf = *(const short8*)(Wt + (size_t)(wave * 32 + j * 16 + lr) * 128 + ks * 32 + q * 8);
#pragma unroll
      for (int i = 0; i < 4; ++i)
        acc[i][j] = __builtin_amdgcn_mfma_f32_16x16x32_bf16(af[i], bf, acc[i][j], 0, 0, 0);
    }
  }

  float bj[2];
#pragma unroll
  for (int j = 0; j < 2; ++j) bj[j] = bcat[wave * 32 + j * 16 + lr];
#pragma unroll
  for (int i = 0; i < 4; ++i)
#pragma unroll
    for (int r = 0; r < 4; ++r) {
      int row = i * 16 + q * 4 + r;
#pragma unroll
      for (int j = 0; j < 2; ++j) {
        int c = wave * 32 + j * 16 + lr;
        float val = acc[i][j][r] + bj[j];
        if (c < 32) {
          *(unsigned short*)&Lsb[row * 272 + 2 * c] = f2bf(val);
        } else if (c < 64) {
          int d = c - 32;
          Lsb[row * 272 + 64 + 4 * (d >> 1) + (d & 1)] = f2fp8(val);
        } else if (c < 96) {
          int d = c - 64;
          Lsb[row * 272 + 64 + 4 * (d >> 1) + 2 + (d & 1)] = f2fp8(val);
        } else {
          *(unsigned short*)&Lsb[row * 272 + 192 + 2 * (c - 96)] = f2bf(val);
        }
      }
    }
  __syncthreads();
#pragma unroll
  for (int p = 0; p < 16; ++p) {
    int idx = tid + p * 256;
    int row = idx >> 6, u = idx & 63;
    int gr = bm + row;
    if (gr < M) *(unsigned*)(C2b + (size_t)gr * 256 + u * 4) = *(const unsigned*)&Lsb[row * 272 + u * 4];
  }
}

// ================= CSR build: scan + packed scatter + per-bucket CSR =================
__global__ void bucket_scan(const int* __restrict__ bhist, int* __restrict__ boff,
                            int* __restrict__ bcur) {
  __shared__ int s[256];
  int t = threadIdx.x;
  int v = (t < NBK) ? bhist[t] : 0;
  s[t] = v;
  __syncthreads();
#pragma unroll
  for (int off = 1; off < 256; off <<= 1) {
    int u = (t >= off) ? s[t - off] : 0;
    __syncthreads();
    s[t] += u;
    __syncthreads();
  }
  if (t < NBK) {
    int excl = s[t] - v;
    boff[t] = excl;
    bcur[t] = excl;
  }
  if (t == NBK - 1) boff[NBK] = s[t];
}

// ebuck entries packed: (src<<8) | (dst & 255)  — 4 B/edge
__global__ void bucket_scatter(const int* __restrict__ ei, int* __restrict__ bcur,
                               int* __restrict__ ebuck, int E) {
  __shared__ int lh[NBK];
  for (int i = threadIdx.x; i < NBK; i += 256) lh[i] = 0;
  __syncthreads();
  const int e0 = blockIdx.x * 4096;
  int pks[16], bks[16];
#pragma unroll
  for (int p = 0; p < 16; ++p) {
    int e = e0 + p * 256 + threadIdx.x;
    if (e < E) {
      int src = ei[e], dst = ei[E + e];
      pks[p] = (src << 8) | (dst & 255);
      bks[p] = dst >> 8;
      atomicAdd(&lh[bks[p]], 1);
    } else bks[p] = -1;
  }
  __syncthreads();
  for (int i = threadIdx.x; i < NBK; i += 256)
    if (lh[i]) lh[i] = atomicAdd(&bcur[i], lh[i]);
  __syncthreads();
#pragma unroll
  for (int p = 0; p < 16; ++p) {
    if (bks[p] >= 0) {
      int slot = atomicAdd(&lh[bks[p]], 1);
      ebuck[slot] = pks[p];
    }
  }
}

// esrc stores src<<8 (byte offset into the 256B/node tables)
__global__ void bucket_csr(const int* __restrict__ ebuck, const int* __restrict__ boff,
                           int* __restrict__ rowptr, int* __restrict__ esrc, int N) {
  const int b = blockIdx.x;
  const int lo = boff[b], hi = boff[b + 1];
  const int cnt = hi - lo;
  __shared__ int hist[256];
  __shared__ int cur[256];
  __shared__ int sorted[BCAP];
  const int t = threadIdx.x;
  hist[t] = 0;
  __syncthreads();
  for (int i = t; i < cnt; i += 256) atomicAdd(&hist[ebuck[lo + i] & 255], 1);
  __syncthreads();
  int v = hist[t];
  sorted[t] = v;
  __syncthreads();
#pragma unroll
  for (int off = 1; off < 256; off <<= 1) {
    int u = (t >= off) ? sorted[t - off] : 0;
    __syncthreads();
    sorted[t] += u;
    __syncthreads();
  }
  int excl = sorted[t] - v;
  cur[t] = excl;
  int node = b * 256 + t;
  if (node <= N) rowptr[node] = lo + excl;
  __syncthreads();
  for (int i = t; i < cnt; i += 256) {
    int pk = ebuck[lo + i];
    int slot = atomicAdd(&cur[pk & 255], 1);
    if (slot < BCAP) sorted[slot] = pk;
    else esrc[lo + slot] = pk & 0xFFFFFF00;  // overflow fallback
  }
  __syncthreads();
  int lim = cnt < BCAP ? cnt : BCAP;
  for (int i = t; i < lim; i += 256) esrc[lo + i] = sorted[i] & 0xFFFFFF00;
}

// ================= fused aggregation: plain-exp softmax, fp8 K/V =================
// conv1: 32 lanes per edge; halves process disjoint edges; x8 main loop (4 edges/half).
__global__ void node_attn1(const int* __restrict__ rowptr, const int* __restrict__ esrc,
                           const unsigned short* __restrict__ Qb,
                           const unsigned char* __restrict__ KV8,
                           const unsigned short* __restrict__ SK, unsigned short* __restrict__ Hb,
                           int n) {
  int node = (blockIdx.x * blockDim.x + threadIdx.x) >> 6;
  int lane = threadIdx.x & 63;
  if (node >= n) return;
  const int half = lane >> 5, ll = lane & 31;
  const int r0 = rowptr[node], r1 = rowptr[node + 1];
  uint2 qq = *(const uint2*)(Qb + (size_t)node * 128 + ll * 4);
  const float q0 = bflo(qq.x), q1 = bfhi(qq.x), q2 = bflo(qq.y), q3 = bfhi(qq.y);
  float l = 0.f, a0 = 0.f, a1 = 0.f, a2 = 0.f, a3 = 0.f;
  const unsigned char* kvb = KV8 + ll * 8;
  int j = r0;
  for (; j + 8 <= r1; j += 8) {
    int e = j + half * 4;
    int s0 = esrc[e], s1 = esrc[e + 1], s2 = esrc[e + 2], s3 = esrc[e + 3];
    uint2 u0 = *(const uint2*)(kvb + s0);
    uint2 u1 = *(const uint2*)(kvb + s1);
    uint2 u2 = *(const uint2*)(kvb + s2);
    uint2 u3 = *(const uint2*)(kvb + s3);
    f32x2 k0a = fp8dec<false>(u0.x), k0b = fp8dec<false>(u0.y);
    f32x2 k1a = fp8dec<false>(u1.x), k1b = fp8dec<false>(u1.y);
    f32x2 k2a = fp8dec<false>(u2.x), k2b = fp8dec<false>(u2.y);
    f32x2 k3a = fp8dec<false>(u3.x), k3b = fp8dec<false>(u3.y);
    float d0 = q0 * k0a.x + q1 * k0a.y + q2 * k0b.x + q3 * k0b.y;
    float d1 = q0 * k1a.x + q1 * k1a.y + q2 * k1b.x + q3 * k1b.y;
    float d2 = q0 * k2a.x + q1 * k2a.y + q2 * k2b.x + q3 * k2b.y;
    float d3 = q0 * k3a.x + q1 * k3a.y + q2 * k3b.x + q3 * k3b.y;
#pragma unroll
    for (int msk = 1; msk <= 4; msk <<= 1) {
      d0 += __shfl_xor(d0, msk);
      d1 += __shfl_xor(d1, msk);
      d2 += __shfl_xor(d2, msk);
      d3 += __shfl_xor(d3, msk);
    }
    float p0 = __expf(d0), p1 = __expf(d1), p2 = __expf(d2), p3 = __expf(d3);
    l += (p0 + p1) + (p2 + p3);
    f32x2 v0a = fp8dec<true>(u0.x), v0b = fp8dec<true>(u0.y);
    f32x2 v1a = fp8dec<true>(u1.x), v1b = fp8dec<true>(u1.y);
    f32x2 v2a = fp8dec<true>(u2.x), v2b = fp8dec<true>(u2.y);
    f32x2 v3a = fp8dec<true>(u3.x), v3b = fp8dec<true>(u3.y);
    a0 += p0 * v0a.x + p1 * v1a.x + p2 * v2a.x + p3 * v3a.x;
    a1 += p0 * v0a.y + p1 * v1a.y + p2 * v2a.y + p3 * v3a.y;
    a2 += p0 * v0b.x + p1 * v1b.x + p2 * v2b.x + p3 * v3b.x;
    a3 += p0 * v0b.y + p1 * v1b.y + p2 * v2b.y + p3 * v3b.y;
  }
  for (; j < r1; j += 4) {  // masked tail, 2 edges/half per pass
    int eA = j + half * 2, eB = eA + 1;
    bool vA = eA < r1, vB = eB < r1;
    int sA = esrc[vA ? eA : r0];
    int sB = esrc[vB ? eB : r0];
    uint2 ua = *(const uint2*)(kvb + sA);
    uint2 ub = *(const uint2*)(kvb + sB);
    f32x2 ka1 = fp8dec<false>(ua.x), ka2 = fp8dec<false>(ua.y);
    f32x2 kb1 = fp8dec<false>(ub.x), kb2 = fp8dec<false>(ub.y);
    float dA = q0 * ka1.x + q1 * ka1.y + q2 * ka2.x + q3 * ka2.y;
    float dB = q0 * kb1.x + q1 * kb1.y + q2 * kb2.x + q3 * kb2.y;
#pragma unroll
    for (int msk = 1; msk <= 4; msk <<= 1) {
      dA += __shfl_xor(dA, msk);
      dB += __shfl_xor(dB, msk);
    }
    float pA = vA ? __expf(dA) : 0.f;
    float pB = vB ? __expf(dB) : 0.f;
    l += pA + pB;
    f32x2 va1 = fp8dec<true>(ua.x), va2 = fp8dec<true>(ua.y);
    f32x2 vb1 = fp8dec<true>(ub.x), vb2 = fp8dec<true>(ub.y);
    a0 += pA * va1.x + pB * vb1.x;
    a1 += pA * va1.y + pB * vb1.y;
    a2 += pA * va2.x + pB * vb2.x;
    a3 += pA * va2.y + pB * vb2.y;
  }
  l  += __shfl_xor(l, 32);
  a0 += __shfl_xor(a0, 32);
  a1 += __shfl_xor(a1, 32);
  a2 += __shfl_xor(a2, 32);
  a3 += __shfl_xor(a3, 32);
  float inv = (l > 0.f) ? 1.f / l : 0.f;
  if (half == 0) {
    uint2 sk = *(const uint2*)(SK + (size_t)node * 128 + ll * 4);
    float o0 = fmaxf(bflo(sk.x) + a0 * inv, 0.f);
    float o1 = fmaxf(bfhi(sk.x) + a1 * inv, 0.f);
    float o2 = fmaxf(bflo(sk.y) + a2 * inv, 0.f);
    float o3 = fmaxf(bfhi(sk.y) + a3 * inv, 0.f);
    uint2 hb;
    hb.x = ((unsigned)f2bf(o1) << 16) | (unsigned)f2bf(o0);
    hb.y = ((unsigned)f2bf(o3) << 16) | (unsigned)f2bf(o2);
    *(uint2*)(Hb + (size_t)node * 128 + ll * 4) = hb;
  }
}

// conv2: 16 lanes per edge (4 groups); x8 main loop (2 edges/group); plain exp.
__global__ void node_attn2(const int* __restrict__ rowptr, const int* __restrict__ esrc,
                           unsigned char* __restrict__ C2b, int n) {
  int node = (blockIdx.x * blockDim.x + threadIdx.x) >> 6;
  int lane = threadIdx.x & 63;
  if (node >= n) return;
  const int g = lane >> 4, gl = lane & 15;
  const int r0 = rowptr[node], r1 = rowptr[node + 1];
  unsigned qu = *(const unsigned*)(C2b + (size_t)node * 256 + gl * 4);
  const float q0 = bflo(qu), q1 = bfhi(qu);
  float l = 0.f, a0 = 0.f, a1 = 0.f;
  const unsigned char* kvb = C2b + 64 + gl * 4;
  int j = r0;
  for (; j + 8 <= r1; j += 8) {
    int e = j + g * 2;
    int s0 = esrc[e], s1 = esrc[e + 1];
    unsigned u0 = *(const unsigned*)(kvb + s0);
    unsigned u1 = *(const unsigned*)(kvb + s1);
    f32x2 k0 = fp8dec<false>(u0), k1 = fp8dec<false>(u1);
    float d0 = q0 * k0.x + q1 * k0.y;
    float d1 = q0 * k1.x + q1 * k1.y;
#pragma unroll
    for (int msk = 1; msk <= 8; msk <<= 1) {
      d0 += __shfl_xor(d0, msk);
      d1 += __shfl_xor(d1, msk);
    }
    float p0 = __expf(d0), p1 = __expf(d1);
    l += p0 + p1;
    f32x2 v0 = fp8dec<true>(u0), v1 = fp8dec<true>(u1);
    a0 += p0 * v0.x + p1 * v1.x;
    a1 += p0 * v0.y + p1 * v1.y;
  }
  for (; j < r1; j += 4) {  // masked tail, 1 edge/group per pass
    bool v = (j + g) < r1;
    int s = esrc[v ? j + g : r0];
    unsigned u = *(const unsigned*)(kvb + s);
    f32x2 kd = fp8dec<false>(u);
    float d = q0 * kd.x + q1 * kd.y;
#pragma unroll
    for (int msk = 1; msk <= 8; msk <<= 1) d += __shfl_xor(d, msk);
    float p = v ? __expf(d) : 0.f;
    l += p;
    f32x2 vd = fp8dec<true>(u);
    a0 += p * vd.x;
    a1 += p * vd.y;
  }
#pragma unroll
  for (int msk = 16; msk <= 32; msk <<= 1) {
    l  += __shfl_xor(l, msk);
    a0 += __shfl_xor(a0, msk);
    a1 += __shfl_xor(a1, msk);
  }
  float inv = (l > 0.f) ? 1.f / l : 0.f;
  if (lane < 16) {
    unsigned* h = (unsigned*)(C2b + (size_t)node * 256 + 192 + gl * 4);
    unsigned hu = *h;
    float o0 = bflo(hu) + a0 * inv;
    float o1 = bfhi(hu) + a1 * inv;
    *h = ((unsigned)f2bf(o1) << 16) | (unsigned)f2bf(o0);
  }
}

// ---------------- epilogue ----------------
__global__ void mean_reduce(const unsigned char* __restrict__ C2b, float* __restrict__ ACC, int n) {
  __shared__ float s[256];
  float acc = 0.f;
  int stride = gridDim.x * blockDim.x;
  int total = n * 32;
  for (int i = blockIdx.x * blockDim.x + threadIdx.x; i < total; i += stride) {
    int node = i >> 5, c = i & 31;
    unsigned short h = *(const unsigned short*)(C2b + (size_t)node * 256 + 192 + c * 2);
    acc += fmaxf(bf2f(h), 0.f);
  }
  s[threadIdx.x] = acc;
  __syncthreads();
  for (int off = 128; off >= 32; off >>= 1) {
    if (threadIdx.x < off) s[threadIdx.x] += s[threadIdx.x + off];
    __syncthreads();
  }
  if (threadIdx.x < 32) atomicAdd(&ACC[threadIdx.x], s[threadIdx.x]);
}

__global__ void final_out(const float* __restrict__ ACC, const float* __restrict__ Wo,
                          const float* __restrict__ bo, float* __restrict__ out, float invN) {
  int lane = threadIdx.x;
  float v = 0.f;
  if (lane < 32) v = ACC[lane] * invN * Wo[lane];
  v += __shfl_xor(v, 1);
  v += __shfl_xor(v, 2);
  v += __shfl_xor(v, 4);
  v += __shfl_xor(v, 8);
  v += __shfl_xor(v, 16);
  v += __shfl_xor(v, 32);
  if (lane == 0) out[0] = v + bo[0];
}

extern "C" void kernel_launch(void* const* d_in, const int* in_sizes, int n_in,
                              void* d_out, int out_size, void* d_ws, size_t ws_size,
                              hipStream_t stream) {
  const float* x   = (const float*)d_in[0];
  const int*   ei  = (const int*)d_in[1];  // [2, E]: row 0 = src, row 1 = dst
  const float* Wq1 = (const float*)d_in[2];  const float* bq1 = (const float*)d_in[3];
  const float* Wk1 = (const float*)d_in[4];  const float* bk1 = (const float*)d_in[5];
  const float* Wv1 = (const float*)d_in[6];  const float* bv1 = (const float*)d_in[7];
  const float* Ws1 = (const float*)d_in[8];  const float* bs1 = (const float*)d_in[9];
  const float* Wq2 = (const float*)d_in[10]; const float* bq2 = (const float*)d_in[11];
  const float* Wk2 = (const float*)d_in[12]; const float* bk2 = (const float*)d_in[13];
  const float* Wv2 = (const float*)d_in[14]; const float* bv2 = (const float*)d_in[15];
  const float* Ws2 = (const float*)d_in[16]; const float* bs2 = (const float*)d_in[17];
  const float* Wo  = (const float*)d_in[18]; const float* bo  = (const float*)d_in[19];

  char* ws = (char*)d_ws;
  const int N = N_NODES, E = N_EDGES;
  const int GB = (N + 63) / 64;
  const int EB = (E + 4095) / 4096;

  // buffers
  unsigned short* Q1b = (unsigned short*)(ws + 0);          // N*128 bf16 (pre-scaled)
  unsigned short* SK1 = (unsigned short*)(ws + 12800000);   // N*128 bf16
  unsigned char*  KV1 = (unsigned char*)(ws + 25600000);    // N*256 fp8
  unsigned short* H1b = (unsigned short*)(ws + 51200000);   // N*128 bf16
  unsigned char*  C2  = (unsigned char*)(ws + 64000000);    // N*256 bytes [Q|KV8|pad|H]
  // CSR + weights + misc
  int* rowptr = (int*)(ws + 89600000);                      // N+1
  int* esrc   = (int*)(ws + 89900032);                      // E (byte offsets, src<<8)
  int* bhist  = (int*)(ws + 93100032);                      // NBK
  int* boff   = (int*)(ws + 93101056);                      // NBK+1
  int* bcur   = (int*)(ws + 93102080);                      // NBK
  unsigned short* Wt1   = (unsigned short*)(ws + 93103104);   // 512x128 bf16
  unsigned short* Wt2   = (unsigned short*)(ws + 93234176);   // 128x128 bf16
  float*          bcat1 = (float*)(ws + 93266944);
  float*          bcat2 = (float*)(ws + 93268992);
  float*          ACC   = (float*)(ws + 93269504);
  int*            ebuck = (int*)(ws + 93270016);            // E * 4B packed

  float* out = (float*)d_out;

  dim3 blk(256);

  hipMemsetAsync(bhist, 0, NBK * sizeof(int), stream);
  hipMemsetAsync(ACC, 0, 32 * sizeof(float), stream);

  // ---- fused prep: weights + bucket histogram in one launch ----
  prep_fused<<<dim3(W1_B + W2_B + EB), blk, 0, stream>>>(
      Wq1, Wk1, Wv1, Ws1, bq1, bk1, bv1, bs1,
      Wq2, Wk2, Wv2, Ws2, bq2, bk2, bv2, bs2,
      Wt1, bcat1, Wt2, bcat2, ei, bhist, E);

  // ---- CSR build ----
  bucket_scan<<<dim3(1), blk, 0, stream>>>(bhist, boff, bcur);
  bucket_scatter<<<dim3(EB), blk, 0, stream>>>(ei, bcur, ebuck, E);
  bucket_csr<<<dim3(NBK), blk, 0, stream>>>(ebuck, boff, rowptr, esrc, N);

  // ---- conv1 GEMM (stages fp32 x directly; 64 rows x 512 cols per block) ----
  gemm_conv1<<<dim3(GB), blk, 0, stream>>>(x, Wt1, bcat1, Q1b, SK1, KV1, N);

  // ---- conv1 fused attention + skip + relu -> bf16 ----
  node_attn1<<<dim3((N * 64 + 255) / 256), blk, 0, stream>>>(rowptr, esrc, Q1b, KV1, SK1, H1b, N);

  // ---- conv2 GEMM (fused Q|KV8|H rows) ----
  gemm2<<<dim3(GB), blk, 0, stream>>>(H1b, Wt2, bcat2, C2, N);

  // ---- conv2 fused attention ----
  node_attn2<<<dim3((N * 64 + 255) / 256), blk, 0, stream>>>(rowptr, esrc, C2, N);

  // ---- relu + mean + final linear ----
  mean_reduce<<<dim3(1024), blk, 0, stream>>>(C2, ACC, N);
  final_out<<<dim3(1), dim3(64), 0, stream>>>(ACC, Wo, bo, out, 1.0f / (float)N);
}

// Round 15
// 249.168 us; speedup vs baseline: 1.5488x; 1.0835x over previous
//
#include <hip/hip_runtime.h>
#include <math.h>

#define N_NODES 50000
#define N_EDGES 800000
#define NBK 196          // dst buckets of 256 nodes: bucket = dst >> 8
#define BCAP 6144        // max edges per bucket handled in LDS (mean 4082, sigma 64)

typedef short short8 __attribute__((ext_vector_type(8)));
typedef float f32x4 __attribute__((ext_vector_type(4)));
typedef float f32x2 __attribute__((ext_vector_type(2)));

// ---------------- bf16 / fp8 helpers ----------------
__device__ inline unsigned short f2bf(float v) {
  unsigned u = __float_as_uint(v);
  u += 0x7FFFu + ((u >> 16) & 1u);  // round-to-nearest-even
  return (unsigned short)(u >> 16);
}
__device__ inline float bf2f(unsigned short b) {
  return __uint_as_float(((unsigned)b) << 16);
}
__device__ inline float bflo(unsigned u) { return __uint_as_float(u << 16); }
__device__ inline float bfhi(unsigned u) { return __uint_as_float(u & 0xFFFF0000u); }
// fp8 e4m3 (OCP on gfx950); decode selector must be an immediate -> template param.
__device__ inline unsigned char f2fp8(float v) {
  return (unsigned char)(__builtin_amdgcn_cvt_pk_fp8_f32(v, 0.f, 0, false) & 0xFF);
}
template <bool HI>
__device__ inline f32x2 fp8dec(unsigned u) {
  return __builtin_amdgcn_cvt_pk_f32_fp8(u, HI);
}

#define SCL 0.17677669529663687f   // 1/sqrt(32), folded into Wq/bq at prep

// ---------------- fused prep: weight concat/transpose + bucket histogram ----------------
#define W1_B 256      // 512*128 / 256
#define W2_B 64       // 128*128 / 256
__global__ void prep_fused(const float* __restrict__ Wq1, const float* __restrict__ Wk1,
                           const float* __restrict__ Wv1, const float* __restrict__ Ws1,
                           const float* __restrict__ bq1, const float* __restrict__ bk1,
                           const float* __restrict__ bv1, const float* __restrict__ bs1,
                           const float* __restrict__ Wq2, const float* __restrict__ Wk2,
                           const float* __restrict__ Wv2, const float* __restrict__ Ws2,
                           const float* __restrict__ bq2, const float* __restrict__ bk2,
                           const float* __restrict__ bv2, const float* __restrict__ bs2,
                           unsigned short* __restrict__ Wt1, float* __restrict__ bcat1,
                           unsigned short* __restrict__ Wt2, float* __restrict__ bcat2,
                           const int* __restrict__ ei, int* __restrict__ bhist, int E) {
  const int b = blockIdx.x, tid = threadIdx.x;
  if (b < W1_B) {
    int i = b * 256 + tid;   // over 512*128
    int c = i >> 7, k = i & 127;
    int mi = c >> 7, lc = c & 127;
    const float* W = (mi == 0) ? Wq1 : (mi == 1) ? Wk1 : (mi == 2) ? Wv1 : Ws1;
    float scl = (mi == 0) ? SCL : 1.f;
    Wt1[i] = f2bf(W[(size_t)k * 128 + lc] * scl);
    if (i < 512) {
      int bm = i >> 7, bl = i & 127;
      const float* bb = (bm == 0) ? bq1 : (bm == 1) ? bk1 : (bm == 2) ? bv1 : bs1;
      bcat1[i] = bb[bl] * ((bm == 0) ? SCL : 1.f);
    }
  } else if (b < W1_B + W2_B) {
    int i = (b - W1_B) * 256 + tid;  // over 128*128
    int c = i >> 7, k = i & 127;
    int mi = c >> 5, lc = c & 31;
    const float* W = (mi == 0) ? Wq2 : (mi == 1) ? Wk2 : (mi == 2) ? Wv2 : Ws2;
    float scl = (mi == 0) ? SCL : 1.f;
    Wt2[i] = f2bf(W[(size_t)k * 32 + lc] * scl);
    if (i < 128) {
      int bm = i >> 5, bl = i & 31;
      const float* bb = (bm == 0) ? bq2 : (bm == 1) ? bk2 : (bm == 2) ? bv2 : bs2;
      bcat2[i] = bb[bl] * ((bm == 0) ? SCL : 1.f);
    }
  } else {
    __shared__ int h[NBK];
    for (int i = tid; i < NBK; i += 256) h[i] = 0;
    __syncthreads();
    int e = (b - W1_B - W2_B) * 4096 + tid;
#pragma unroll
    for (int p = 0; p < 16; ++p, e += 256)
      if (e < E) atomicAdd(&h[ei[E + e] >> 8], 1);
    __syncthreads();
    for (int i = tid; i < NBK; i += 256)
      if (h[i]) atomicAdd(&bhist[i], h[i]);
  }
}

// ================= bucket scan =================
__global__ void bucket_scan(const int* __restrict__ bhist, int* __restrict__ boff,
                            int* __restrict__ bcur) {
  __shared__ int s[256];
  int t = threadIdx.x;
  int v = (t < NBK) ? bhist[t] : 0;
  s[t] = v;
  __syncthreads();
#pragma unroll
  for (int off = 1; off < 256; off <<= 1) {
    int u = (t >= off) ? s[t - off] : 0;
    __syncthreads();
    s[t] += u;
    __syncthreads();
  }
  if (t < NBK) {
    int excl = s[t] - v;
    boff[t] = excl;
    bcur[t] = excl;
  }
  if (t == NBK - 1) boff[NBK] = s[t];
}

// ================= FUSED: bucket_scatter (blocks [0,EB)) + conv1 GEMM (blocks [EB,EB+GB)) ====
// Independent work items run concurrently in one launch.
// GEMM: one block = 64 rows x ALL 512 cols; A staged from fp32 x (bf16 in-flight);
// wave0->Q(bf16), wave1->K(fp8), wave2->V(fp8), wave3->SK(bf16).
// KV fp8 row (256 B/node): byte 4t+{0,1} = K[2t,2t+1], byte 4t+{2,3} = V[2t,2t+1].
// ebuck packed: (src<<8) | (dst & 255).
__global__ __launch_bounds__(256) void scatter_gemm1(
    const int* __restrict__ ei, int* __restrict__ bcur, int* __restrict__ ebuck, int E, int EB,
    const float* __restrict__ X, const unsigned short* __restrict__ Wt,
    const float* __restrict__ bcat, unsigned short* __restrict__ Q1b,
    unsigned short* __restrict__ SK1, unsigned char* __restrict__ KV8, int M) {
  __shared__ __align__(16) unsigned char L[3][64 * 272];  // 52.2 KB
  const int tid = threadIdx.x;

  if ((int)blockIdx.x < EB) {
    // ---------- scatter path ----------
    int* lh = (int*)L[0];
    for (int i = tid; i < NBK; i += 256) lh[i] = 0;
    __syncthreads();
    const int e0 = blockIdx.x * 4096;
    int pks[16], bks[16];
#pragma unroll
    for (int p = 0; p < 16; ++p) {
      int e = e0 + p * 256 + tid;
      if (e < E) {
        int src = ei[e], dst = ei[E + e];
        pks[p] = (src << 8) | (dst & 255);
        bks[p] = dst >> 8;
        atomicAdd(&lh[bks[p]], 1);
      } else bks[p] = -1;
    }
    __syncthreads();
    for (int i = tid; i < NBK; i += 256)
      if (lh[i]) lh[i] = atomicAdd(&bcur[i], lh[i]);
    __syncthreads();
#pragma unroll
    for (int p = 0; p < 16; ++p) {
      if (bks[p] >= 0) {
        int slot = atomicAdd(&lh[bks[p]], 1);
        ebuck[slot] = pks[p];
      }
    }
    return;
  }

  // ---------- GEMM path ----------
  unsigned short* As = (unsigned short*)L[0];             // stride 136 shorts
  const int bm = (blockIdx.x - EB) * 64;
  const int wave = tid >> 6, lane = tid & 63;
  const int lr = lane & 15, q = lane >> 4;

#pragma unroll
  for (int p = 0; p < 8; ++p) {
    int f = tid + p * 256;          // 0..2047 float4s
    int row = f >> 5, c4 = f & 31;
    int gm = bm + row; if (gm >= M) gm = 0;
    float4 v = *(const float4*)(X + (size_t)gm * 128 + c4 * 4);
    ushort4 o;
    o.x = f2bf(v.x); o.y = f2bf(v.y); o.z = f2bf(v.z); o.w = f2bf(v.w);
    *(ushort4*)&As[row * 136 + c4 * 4] = o;
  }
  __syncthreads();

  const int colbase = wave * 128;
  f32x4 acc[4][8];
#pragma unroll
  for (int i = 0; i < 4; ++i)
#pragma unroll
    for (int j = 0; j < 8; ++j) acc[i][j] = (f32x4){0.f, 0.f, 0.f, 0.f};

#pragma unroll
  for (int ks = 0; ks < 4; ++ks) {
    short8 af[4];
#pragma unroll
    for (int i = 0; i < 4; ++i)
      af[i] = *(short8*)&As[(i * 16 + lr) * 136 + ks * 32 + q * 8];
#pragma unroll
    for (int j = 0; j < 8; ++j) {
      short8 bf = *(const short8*)(Wt + (size_t)(colbase + j * 16 + lr) * 128 + ks * 32 + q * 8);
#pragma unroll
      for (int i = 0; i < 4; ++i)
        acc[i][j] = __builtin_amdgcn_mfma_f32_16x16x32_bf16(af[i], bf, acc[i][j], 0, 0, 0);
    }
  }
  __syncthreads();

  float bj[8];
#pragma unroll
  for (int j = 0; j < 8; ++j) bj[j] = bcat[colbase + j * 16 + lr];

  if (wave == 0 || wave == 3) {
    unsigned short* Ls16 = (unsigned short*)((wave == 0) ? L[1] : L[0]);
#pragma unroll
    for (int i = 0; i < 4; ++i)
#pragma unroll
      for (int r = 0; r < 4; ++r) {
        int row = i * 16 + q * 4 + r;
#pragma unroll
        for (int j = 0; j < 8; ++j)
          Ls16[row * 136 + j * 16 + lr] = f2bf(acc[i][j][r] + bj[j]);
      }
  } else {
    unsigned char* KLs = L[2];
    const int voff = (wave == 2) ? 2 : 0;
#pragma unroll
    for (int i = 0; i < 4; ++i)
#pragma unroll
      for (int r = 0; r < 4; ++r) {
        int row = i * 16 + q * 4 + r;
#pragma unroll
        for (int j = 0; j < 8; ++j) {
          int d = j * 16 + lr;
          KLs[row * 272 + 4 * (d >> 1) + voff + (d & 1)] = f2fp8(acc[i][j][r] + bj[j]);
        }
      }
  }
  __syncthreads();

#pragma unroll
  for (int p = 0; p < 4; ++p) {
    int f = tid + p * 256;
    int row = f >> 4, u = f & 15;
    int gr = bm + row;
    if (gr < M) {
      *(uint4*)(Q1b + (size_t)gr * 128 + u * 8) = *(uint4*)&((unsigned short*)L[1])[row * 136 + u * 8];
      *(uint4*)(KV8 + (size_t)gr * 256 + u * 16) = *(uint4*)&L[2][row * 272 + u * 16];
      *(uint4*)(SK1 + (size_t)gr * 128 + u * 8) = *(uint4*)&((unsigned short*)L[0])[row * 136 + u * 8];
    }
  }
}

// esrc stores src<<8 (byte offset into the 256B/node tables)
__global__ void bucket_csr(const int* __restrict__ ebuck, const int* __restrict__ boff,
                           int* __restrict__ rowptr, int* __restrict__ esrc, int N) {
  const int b = blockIdx.x;
  const int lo = boff[b], hi = boff[b + 1];
  const int cnt = hi - lo;
  __shared__ int hist[256];
  __shared__ int cur[256];
  __shared__ int sorted[BCAP];
  const int t = threadIdx.x;
  hist[t] = 0;
  __syncthreads();
  for (int i = t; i < cnt; i += 256) atomicAdd(&hist[ebuck[lo + i] & 255], 1);
  __syncthreads();
  int v = hist[t];
  sorted[t] = v;
  __syncthreads();
#pragma unroll
  for (int off = 1; off < 256; off <<= 1) {
    int u = (t >= off) ? sorted[t - off] : 0;
    __syncthreads();
    sorted[t] += u;
    __syncthreads();
  }
  int excl = sorted[t] - v;
  cur[t] = excl;
  int node = b * 256 + t;
  if (node <= N) rowptr[node] = lo + excl;
  __syncthreads();
  for (int i = t; i < cnt; i += 256) {
    int pk = ebuck[lo + i];
    int slot = atomicAdd(&cur[pk & 255], 1);
    if (slot < BCAP) sorted[slot] = pk;
    else esrc[lo + slot] = pk & 0xFFFFFF00;
  }
  __syncthreads();
  int lim = cnt < BCAP ? cnt : BCAP;
  for (int i = t; i < lim; i += 256) esrc[lo + i] = sorted[i] & 0xFFFFFF00;
}

// ---- gemm2: LDS-staged A (bf16); 128 cols -> C2 rows (256 B): [Q bf16 | KV fp8 | pad | H bf16] ----
__global__ __launch_bounds__(256) void gemm2(
    const unsigned short* __restrict__ Ab, const unsigned short* __restrict__ Wt,
    const float* __restrict__ bcat, unsigned char* __restrict__ C2b, int M) {
  __shared__ __align__(16) unsigned short As[64 * 136];
  __shared__ __align__(16) unsigned char Lsb[64 * 272];
  const int bm = blockIdx.x * 64;
  const int tid = threadIdx.x, wave = tid >> 6, lane = tid & 63;
  const int lr = lane & 15, q = lane >> 4;

#pragma unroll
  for (int p = 0; p < 4; ++p) {
    int f = tid + p * 256;
    int row = f >> 4, chunk = f & 15;
    int gm = bm + row; if (gm >= M) gm = 0;
    uint4 v = *(const uint4*)(Ab + (size_t)gm * 128 + chunk * 8);
    *(uint4*)&As[row * 136 + chunk * 8] = v;
  }
  __syncthreads();

  f32x4 acc[4][2];
#pragma unroll
  for (int i = 0; i < 4; ++i)
#pragma unroll
    for (int j = 0; j < 2; ++j) acc[i][j] = (f32x4){0.f, 0.f, 0.f, 0.f};

#pragma unroll
  for (int ks = 0; ks < 4; ++ks) {
    short8 af[4];
#pragma unroll
    for (int i = 0; i < 4; ++i)
      af[i] = *(short8*)&As[(i * 16 + lr) * 136 + ks * 32 + q * 8];
#pragma unroll
    for (int j = 0; j < 2; ++j) {
      short8 bf = *(const short8*)(Wt + (size_t)(wave * 32 + j * 16 + lr) * 128 + ks * 32 + q * 8);
#pragma unroll
      for (int i = 0; i < 4; ++i)
        acc[i][j] = __builtin_amdgcn_mfma_f32_16x16x32_bf16(af[i], bf, acc[i][j], 0, 0, 0);
    }
  }

  float bj[2];
#pragma unroll
  for (int j = 0; j < 2; ++j) bj[j] = bcat[wave * 32 + j * 16 + lr];
#pragma unroll
  for (int i = 0; i < 4; ++i)
#pragma unroll
    for (int r = 0; r < 4; ++r) {
      int row = i * 16 + q * 4 + r;
#pragma unroll
      for (int j = 0; j < 2; ++j) {
        int c = wave * 32 + j * 16 + lr;
        float val = acc[i][j][r] + bj[j];
        if (c < 32) {
          *(unsigned short*)&Lsb[row * 272 + 2 * c] = f2bf(val);
        } else if (c < 64) {
          int d = c - 32;
          Lsb[row * 272 + 64 + 4 * (d >> 1) + (d & 1)] = f2fp8(val);
        } else if (c < 96) {
          int d = c - 64;
          Lsb[row * 272 + 64 + 4 * (d >> 1) + 2 + (d & 1)] = f2fp8(val);
        } else {
          *(unsigned short*)&Lsb[row * 272 + 192 + 2 * (c - 96)] = f2bf(val);
        }
      }
    }
  __syncthreads();
#pragma unroll
  for (int p = 0; p < 16; ++p) {
    int idx = tid + p * 256;
    int row = idx >> 6, u = idx & 63;
    int gr = bm + row;
    if (gr < M) *(unsigned*)(C2b + (size_t)gr * 256 + u * 4) = *(const unsigned*)&Lsb[row * 272 + u * 4];
  }
}

// ================= fused aggregation: plain-exp softmax, fp8 K/V =================
// conv1: 32 lanes per edge; halves process disjoint edges; x8 main loop (4 edges/half).
__global__ void node_attn1(const int* __restrict__ rowptr, const int* __restrict__ esrc,
                           const unsigned short* __restrict__ Qb,
                           const unsigned char* __restrict__ KV8,
                           const unsigned short* __restrict__ SK, unsigned short* __restrict__ Hb,
                           int n) {
  int node = (blockIdx.x * blockDim.x + threadIdx.x) >> 6;
  int lane = threadIdx.x & 63;
  if (node >= n) return;
  const int half = lane >> 5, ll = lane & 31;
  const int r0 = rowptr[node], r1 = rowptr[node + 1];
  uint2 qq = *(const uint2*)(Qb + (size_t)node * 128 + ll * 4);
  const float q0 = bflo(qq.x), q1 = bfhi(qq.x), q2 = bflo(qq.y), q3 = bfhi(qq.y);
  float l = 0.f, a0 = 0.f, a1 = 0.f, a2 = 0.f, a3 = 0.f;
  const unsigned char* kvb = KV8 + ll * 8;
  int j = r0;
  for (; j + 8 <= r1; j += 8) {
    int e = j + half * 4;
    int s0 = esrc[e], s1 = esrc[e + 1], s2 = esrc[e + 2], s3 = esrc[e + 3];
    uint2 u0 = *(const uint2*)(kvb + s0);
    uint2 u1 = *(const uint2*)(kvb + s1);
    uint2 u2 = *(const uint2*)(kvb + s2);
    uint2 u3 = *(const uint2*)(kvb + s3);
    f32x2 k0a = fp8dec<false>(u0.x), k0b = fp8dec<false>(u0.y);
    f32x2 k1a = fp8dec<false>(u1.x), k1b = fp8dec<false>(u1.y);
    f32x2 k2a = fp8dec<false>(u2.x), k2b = fp8dec<false>(u2.y);
    f32x2 k3a = fp8dec<false>(u3.x), k3b = fp8dec<false>(u3.y);
    float d0 = q0 * k0a.x + q1 * k0a.y + q2 * k0b.x + q3 * k0b.y;
    float d1 = q0 * k1a.x + q1 * k1a.y + q2 * k1b.x + q3 * k1b.y;
    float d2 = q0 * k2a.x + q1 * k2a.y + q2 * k2b.x + q3 * k2b.y;
    float d3 = q0 * k3a.x + q1 * k3a.y + q2 * k3b.x + q3 * k3b.y;
#pragma unroll
    for (int msk = 1; msk <= 4; msk <<= 1) {
      d0 += __shfl_xor(d0, msk);
      d1 += __shfl_xor(d1, msk);
      d2 += __shfl_xor(d2, msk);
      d3 += __shfl_xor(d3, msk);
    }
    float p0 = __expf(d0), p1 = __expf(d1), p2 = __expf(d2), p3 = __expf(d3);
    l += (p0 + p1) + (p2 + p3);
    f32x2 v0a = fp8dec<true>(u0.x), v0b = fp8dec<true>(u0.y);
    f32x2 v1a = fp8dec<true>(u1.x), v1b = fp8dec<true>(u1.y);
    f32x2 v2a = fp8dec<true>(u2.x), v2b = fp8dec<true>(u2.y);
    f32x2 v3a = fp8dec<true>(u3.x), v3b = fp8dec<true>(u3.y);
    a0 += p0 * v0a.x + p1 * v1a.x + p2 * v2a.x + p3 * v3a.x;
    a1 += p0 * v0a.y + p1 * v1a.y + p2 * v2a.y + p3 * v3a.y;
    a2 += p0 * v0b.x + p1 * v1b.x + p2 * v2b.x + p3 * v3b.x;
    a3 += p0 * v0b.y + p1 * v1b.y + p2 * v2b.y + p3 * v3b.y;
  }
  for (; j < r1; j += 4) {  // masked tail, 2 edges/half per pass
    int eA = j + half * 2, eB = eA + 1;
    bool vA = eA < r1, vB = eB < r1;
    int sA = esrc[vA ? eA : r0];
    int sB = esrc[vB ? eB : r0];
    uint2 ua = *(const uint2*)(kvb + sA);
    uint2 ub = *(const uint2*)(kvb + sB);
    f32x2 ka1 = fp8dec<false>(ua.x), ka2 = fp8dec<false>(ua.y);
    f32x2 kb1 = fp8dec<false>(ub.x), kb2 = fp8dec<false>(ub.y);
    float dA = q0 * ka1.x + q1 * ka1.y + q2 * ka2.x + q3 * ka2.y;
    float dB = q0 * kb1.x + q1 * kb1.y + q2 * kb2.x + q3 * kb2.y;
#pragma unroll
    for (int msk = 1; msk <= 4; msk <<= 1) {
      dA += __shfl_xor(dA, msk);
      dB += __shfl_xor(dB, msk);
    }
    float pA = vA ? __expf(dA) : 0.f;
    float pB = vB ? __expf(dB) : 0.f;
    l += pA + pB;
    f32x2 va1 = fp8dec<true>(ua.x), va2 = fp8dec<true>(ua.y);
    f32x2 vb1 = fp8dec<true>(ub.x), vb2 = fp8dec<true>(ub.y);
    a0 += pA * va1.x + pB * vb1.x;
    a1 += pA * va1.y + pB * vb1.y;
    a2 += pA * va2.x + pB * vb2.x;
    a3 += pA * va2.y + pB * vb2.y;
  }
  l  += __shfl_xor(l, 32);
  a0 += __shfl_xor(a0, 32);
  a1 += __shfl_xor(a1, 32);
  a2 += __shfl_xor(a2, 32);
  a3 += __shfl_xor(a3, 32);
  float inv = (l > 0.f) ? 1.f / l : 0.f;
  if (half == 0) {
    uint2 sk = *(const uint2*)(SK + (size_t)node * 128 + ll * 4);
    float o0 = fmaxf(bflo(sk.x) + a0 * inv, 0.f);
    float o1 = fmaxf(bfhi(sk.x) + a1 * inv, 0.f);
    float o2 = fmaxf(bflo(sk.y) + a2 * inv, 0.f);
    float o3 = fmaxf(bfhi(sk.y) + a3 * inv, 0.f);
    uint2 hb;
    hb.x = ((unsigned)f2bf(o1) << 16) | (unsigned)f2bf(o0);
    hb.y = ((unsigned)f2bf(o3) << 16) | (unsigned)f2bf(o2);
    *(uint2*)(Hb + (size_t)node * 128 + ll * 4) = hb;
  }
}

// conv2 + fused relu/mean/Wo-dot: 16 lanes per edge (4 groups); x8 main loop; plain exp.
// Per node: t = dot(relu(skip + attn), Wo); block writes sum of its 4 nodes to pblock.
__global__ void node_attn2(const int* __restrict__ rowptr, const int* __restrict__ esrc,
                           const unsigned char* __restrict__ C2b, const float* __restrict__ Wo,
                           float* __restrict__ pblock, int n) {
  __shared__ float ps[4];
  int node = (blockIdx.x * blockDim.x + threadIdx.x) >> 6;
  int lane = threadIdx.x & 63;
  int wave = threadIdx.x >> 6;
  const int g = lane >> 4, gl = lane & 15;
  float t = 0.f;
  if (node < n) {
    const int r0 = rowptr[node], r1 = rowptr[node + 1];
    unsigned qu = *(const unsigned*)(C2b + (size_t)node * 256 + gl * 4);
    const float q0 = bflo(qu), q1 = bfhi(qu);
    float l = 0.f, a0 = 0.f, a1 = 0.f;
    const unsigned char* kvb = C2b + 64 + gl * 4;
    int j = r0;
    for (; j + 8 <= r1; j += 8) {
      int e = j + g * 2;
      int s0 = esrc[e], s1 = esrc[e + 1];
      unsigned u0 = *(const unsigned*)(kvb + s0);
      unsigned u1 = *(const unsigned*)(kvb + s1);
      f32x2 k0 = fp8dec<false>(u0), k1 = fp8dec<false>(u1);
      float d0 = q0 * k0.x + q1 * k0.y;
      float d1 = q0 * k1.x + q1 * k1.y;
#pragma unroll
      for (int msk = 1; msk <= 8; msk <<= 1) {
        d0 += __shfl_xor(d0, msk);
        d1 += __shfl_xor(d1, msk);
      }
      float p0 = __expf(d0), p1 = __expf(d1);
      l += p0 + p1;
      f32x2 v0 = fp8dec<true>(u0), v1 = fp8dec<true>(u1);
      a0 += p0 * v0.x + p1 * v1.x;
      a1 += p0 * v0.y + p1 * v1.y;
    }
    for (; j < r1; j += 4) {
      bool v = (j + g) < r1;
      int s = esrc[v ? j + g : r0];
      unsigned u = *(const unsigned*)(kvb + s);
      f32x2 kd = fp8dec<false>(u);
      float d = q0 * kd.x + q1 * kd.y;
#pragma unroll
      for (int msk = 1; msk <= 8; msk <<= 1) d += __shfl_xor(d, msk);
      float p = v ? __expf(d) : 0.f;
      l += p;
      f32x2 vd = fp8dec<true>(u);
      a0 += p * vd.x;
      a1 += p * vd.y;
    }
#pragma unroll
    for (int msk = 16; msk <= 32; msk <<= 1) {
      l  += __shfl_xor(l, msk);
      a0 += __shfl_xor(a0, msk);
      a1 += __shfl_xor(a1, msk);
    }
    float inv = (l > 0.f) ? 1.f / l : 0.f;
    unsigned hu = *(const unsigned*)(C2b + (size_t)node * 256 + 192 + gl * 4);
    float o0 = fmaxf(bflo(hu) + a0 * inv, 0.f);
    float o1 = fmaxf(bfhi(hu) + a1 * inv, 0.f);
    t = o0 * Wo[2 * gl] + o1 * Wo[2 * gl + 1];
    // reduce over 16 gl-lanes (all 64 lanes hold per-gl copies; masks stay within groups)
#pragma unroll
    for (int msk = 1; msk <= 8; msk <<= 1) t += __shfl_xor(t, msk);
  }
  if (lane == 0) ps[wave] = t;
  __syncthreads();
  if (threadIdx.x == 0) pblock[blockIdx.x] = ps[0] + ps[1] + ps[2] + ps[3];
}

// ---------------- final: sum per-block partials, scale, bias ----------------
__global__ void final_out(const float* __restrict__ pblock, const float* __restrict__ bo,
                          float* __restrict__ out, int nb, float invN) {
  __shared__ float s[256];
  float acc = 0.f;
  for (int i = threadIdx.x; i < nb; i += 256) acc += pblock[i];
  s[threadIdx.x] = acc;
  __syncthreads();
  for (int off = 128; off >= 1; off >>= 1) {
    if (threadIdx.x < off) s[threadIdx.x] += s[threadIdx.x + off];
    __syncthreads();
  }
  if (threadIdx.x == 0) out[0] = s[0] * invN + bo[0];
}

extern "C" void kernel_launch(void* const* d_in, const int* in_sizes, int n_in,
                              void* d_out, int out_size, void* d_ws, size_t ws_size,
                              hipStream_t stream) {
  const float* x   = (const float*)d_in[0];
  const int*   ei  = (const int*)d_in[1];  // [2, E]: row 0 = src, row 1 = dst
  const float* Wq1 = (const float*)d_in[2];  const float* bq1 = (const float*)d_in[3];
  const float* Wk1 = (const float*)d_in[4];  const float* bk1 = (const float*)d_in[5];
  const float* Wv1 = (const float*)d_in[6];  const float* bv1 = (const float*)d_in[7];
  const float* Ws1 = (const float*)d_in[8];  const float* bs1 = (const float*)d_in[9];
  const float* Wq2 = (const float*)d_in[10]; const float* bq2 = (const float*)d_in[11];
  const float* Wk2 = (const float*)d_in[12]; const float* bk2 = (const float*)d_in[13];
  const float* Wv2 = (const float*)d_in[14]; const float* bv2 = (const float*)d_in[15];
  const float* Ws2 = (const float*)d_in[16]; const float* bs2 = (const float*)d_in[17];
  const float* Wo  = (const float*)d_in[18]; const float* bo  = (const float*)d_in[19];

  char* ws = (char*)d_ws;
  const int N = N_NODES, E = N_EDGES;
  const int GB = (N + 63) / 64;
  const int EB = (E + 4095) / 4096;
  const int AB = (N * 64) / 256;   // 12500 attn blocks

  // buffers
  unsigned short* Q1b = (unsigned short*)(ws + 0);          // N*128 bf16 (pre-scaled)
  unsigned short* SK1 = (unsigned short*)(ws + 12800000);   // N*128 bf16
  unsigned char*  KV1 = (unsigned char*)(ws + 25600000);    // N*256 fp8
  unsigned short* H1b = (unsigned short*)(ws + 51200000);   // N*128 bf16
  unsigned char*  C2  = (unsigned char*)(ws + 64000000);    // N*256 bytes [Q|KV8|pad|H]
  // CSR + weights + misc
  int* rowptr = (int*)(ws + 89600000);                      // N+1
  int* esrc   = (int*)(ws + 89900032);                      // E (byte offsets, src<<8)
  int* bhist  = (int*)(ws + 93100032);                      // NBK
  int* boff   = (int*)(ws + 93101056);                      // NBK+1
  int* bcur   = (int*)(ws + 93102080);                      // NBK
  unsigned short* Wt1   = (unsigned short*)(ws + 93103104);   // 512x128 bf16
  unsigned short* Wt2   = (unsigned short*)(ws + 93234176);   // 128x128 bf16
  float*          bcat1 = (float*)(ws + 93266944);
  float*          bcat2 = (float*)(ws + 93268992);
  float*          pblock = (float*)(ws + 93269504);         // 12500 floats
  int*            ebuck = (int*)(ws + 93319552);            // E * 4B packed

  float* out = (float*)d_out;

  dim3 blk(256);

  hipMemsetAsync(bhist, 0, NBK * sizeof(int), stream);

  // ---- fused prep: weights + bucket histogram ----
  prep_fused<<<dim3(W1_B + W2_B + EB), blk, 0, stream>>>(
      Wq1, Wk1, Wv1, Ws1, bq1, bk1, bv1, bs1,
      Wq2, Wk2, Wv2, Ws2, bq2, bk2, bv2, bs2,
      Wt1, bcat1, Wt2, bcat2, ei, bhist, E);

  // ---- bucket scan ----
  bucket_scan<<<dim3(1), blk, 0, stream>>>(bhist, boff, bcur);

  // ---- FUSED: edge scatter + conv1 GEMM (independent; run concurrently) ----
  scatter_gemm1<<<dim3(EB + GB), blk, 0, stream>>>(
      ei, bcur, ebuck, E, EB, x, Wt1, bcat1, Q1b, SK1, KV1, N);

  // ---- per-bucket CSR finalize ----
  bucket_csr<<<dim3(NBK), blk, 0, stream>>>(ebuck, boff, rowptr, esrc, N);

  // ---- conv1 fused attention + skip + relu -> bf16 ----
  node_attn1<<<dim3(AB), blk, 0, stream>>>(rowptr, esrc, Q1b, KV1, SK1, H1b, N);

  // ---- conv2 GEMM (fused Q|KV8|H rows) ----
  gemm2<<<dim3(GB), blk, 0, stream>>>(H1b, Wt2, bcat2, C2, N);

  // ---- conv2 attention + fused relu/mean/Wo-dot -> per-block partials ----
  node_attn2<<<dim3(AB), blk, 0, stream>>>(rowptr, esrc, C2, Wo, pblock, N);

  // ---- final reduce ----
  final_out<<<dim3(1), blk, 0, stream>>>(pblock, bo, out, AB, 1.0f / (float)N);
}